// Round 13
// baseline (5190.723 us; speedup 1.0000x reference)
//
#include <hip/hip_runtime.h>
#include <hip/hip_bf16.h>

// ---------------- problem constants ----------------
#define BB 8
#define TT 8
#define LL 257
#define DD 1024
#define HH 16
#define CC 64
#define SS 8
#define NTOK (BB*TT*LL)   // 16448
#define D3 (3*DD)         // 3072
#define DFF (4*DD)        // 4096
#define MMAIN 16384       // 64 x 256 m-tiles; tail = 64 rows
#define MTAIL 64

typedef unsigned short u16;   // bf16 bits
typedef __attribute__((ext_vector_type(8))) short short8;
typedef __attribute__((ext_vector_type(4))) short short4v;
typedef __attribute__((ext_vector_type(4))) float f32x4;

__device__ __forceinline__ float us2f(u16 u) {
    return __uint_as_float(((unsigned int)u) << 16);
}
__device__ __forceinline__ u16 f2us(float f) {
    unsigned int u = __float_as_uint(f);
    unsigned int rb = ((u >> 16) & 1u) + 0x7fffu;   // round-to-nearest-even
    return (u16)((u + rb) >> 16);
}

__device__ __forceinline__ void gload_lds16(const u16* g, u16* l) {
    __builtin_amdgcn_global_load_lds(
        (__attribute__((address_space(1))) void*)(void*)g,
        (__attribute__((address_space(3))) void*)(void*)l, 16, 0, 0);
}

// ---------------- fp32 -> bf16 weight conversion ----------------
__global__ __launch_bounds__(256)
void cvt_w(const float* __restrict__ in, u16* __restrict__ out, int n4)
{
    int i = blockIdx.x * 256 + threadIdx.x;
    if (i >= n4) return;
    float4 v = reinterpret_cast<const float4*>(in)[i];
    ushort4 o;
    o.x = f2us(v.x); o.y = f2us(v.y); o.z = f2us(v.z); o.w = f2us(v.w);
    reinterpret_cast<ushort4*>(out)[i] = o;
}

// ---------------- LayerNorm over last dim (1024), optional residual add ----------------
__global__ __launch_bounds__(256)
void ln_rows(const float* __restrict__ X, const float* __restrict__ R,
             const float* __restrict__ g, const float* __restrict__ bta,
             u16* __restrict__ out, int M)
{
    int row = blockIdx.x;
    if (row >= M) return;
    const float* x = X + (size_t)row * DD;
    const float* r = R ? R + (size_t)row * DD : nullptr;
    int t = threadIdx.x;
    float v[4]; float s1 = 0.f, s2 = 0.f;
#pragma unroll
    for (int i = 0; i < 4; ++i) {
        float val = x[t + 256 * i];
        if (r) val += r[t + 256 * i];
        v[i] = val; s1 += val; s2 += val * val;
    }
#pragma unroll
    for (int o = 32; o > 0; o >>= 1) { s1 += __shfl_xor(s1, o, 64); s2 += __shfl_xor(s2, o, 64); }
    __shared__ float red[10];
    int wid = t >> 6, lane = t & 63;
    if (lane == 0) { red[wid] = s1; red[4 + wid] = s2; }
    __syncthreads();
    if (t == 0) {
        float a = red[0] + red[1] + red[2] + red[3];
        float q = red[4] + red[5] + red[6] + red[7];
        float mu = a * (1.f / DD);
        float var = q * (1.f / DD) - mu * mu;
        red[8] = mu; red[9] = rsqrtf(var + 1e-5f);
    }
    __syncthreads();
    float mu = red[8], rs = red[9];
#pragma unroll
    for (int i = 0; i < 4; ++i) {
        int c = t + 256 * i;
        out[(size_t)row * DD + c] = f2us((v[i] - mu) * rs * g[c] + bta[c]);
    }
}

// ---------------- fused s-branch prep ----------------
__global__ __launch_bounds__(256)
void s_prep(const float* __restrict__ s, const float* __restrict__ te,
            const float* __restrict__ smlp_g, const float* __restrict__ smlp_b,
            const float* __restrict__ ln1_g, const float* __restrict__ ln1_b,
            const float* __restrict__ lnte_g, const float* __restrict__ lnte_b,
            const u16* __restrict__ w1b, const u16* __restrict__ w2b,
            u16* __restrict__ snte)
{
    const int blk = blockIdx.x, t = threadIdx.x;
    __shared__ float red[10];
    const int wid = t >> 6, lane = t & 63;

    if (blk == 64) {   // ln_te
        const int NE = TT * DD;
        float s1 = 0.f, s2 = 0.f;
        for (int i = t; i < NE; i += 256) { float v = te[i]; s1 += v; s2 += v * v; }
#pragma unroll
        for (int o = 32; o > 0; o >>= 1) { s1 += __shfl_xor(s1, o, 64); s2 += __shfl_xor(s2, o, 64); }
        if (lane == 0) { red[wid] = s1; red[4 + wid] = s2; }
        __syncthreads();
        if (t == 0) {
            float a = red[0] + red[1] + red[2] + red[3];
            float q = red[4] + red[5] + red[6] + red[7];
            float mu = a / (float)NE;
            float var = q / (float)NE - mu * mu;
            red[8] = mu; red[9] = rsqrtf(var + 1e-5f);
        }
        __syncthreads();
        float mu = red[8], rs = red[9];
        for (int i = t; i < NE; i += 256)
            snte[(size_t)64 * DD + i] = f2us((te[i] - mu) * rs * lnte_g[i] + lnte_b[i]);
        return;
    }

    __shared__ float xrow[1024];
    __shared__ float h1[128];
    const float* sr = s + (size_t)blk * DD;

    float v[4]; float s1 = 0.f, s2 = 0.f;
#pragma unroll
    for (int i = 0; i < 4; ++i) {
        float val = sr[t + 256 * i];
        v[i] = val; s1 += val; s2 += val * val;
    }
#pragma unroll
    for (int o = 32; o > 0; o >>= 1) { s1 += __shfl_xor(s1, o, 64); s2 += __shfl_xor(s2, o, 64); }
    if (lane == 0) { red[wid] = s1; red[4 + wid] = s2; }
    __syncthreads();
    if (t == 0) {
        float a = red[0] + red[1] + red[2] + red[3];
        float q = red[4] + red[5] + red[6] + red[7];
        float mu = a * (1.f / DD);
        float var = q * (1.f / DD) - mu * mu;
        red[8] = mu; red[9] = rsqrtf(var + 1e-5f);
    }
    __syncthreads();
    {
        float mu = red[8], rs = red[9];
#pragma unroll
        for (int i = 0; i < 4; ++i) {
            int c = t + 256 * i;
            xrow[c] = (v[i] - mu) * rs * smlp_g[c] + smlp_b[c];
        }
    }
    __syncthreads();
    if (t < 128) {
        const u16* wr_ = w1b + (size_t)t * DD;
        float a0 = 0.f, a1 = 0.f;
        for (int k = 0; k < DD; k += 8) {
            short4v wa = *reinterpret_cast<const short4v*>(&wr_[k]);
            short4v wb = *reinterpret_cast<const short4v*>(&wr_[k + 4]);
#pragma unroll
            for (int j = 0; j < 4; ++j) {
                a0 += xrow[k + j] * us2f((u16)wa[j]);
                a1 += xrow[k + 4 + j] * us2f((u16)wb[j]);
            }
        }
        h1[t] = a0 + a1;
    }
    __syncthreads();
    float w[4]; s1 = 0.f; s2 = 0.f;
#pragma unroll
    for (int i = 0; i < 4; ++i) {
        int d = t + 256 * i;
        const u16* w2r = w2b + (size_t)d * 128;
        float a = 0.f;
        for (int k = 0; k < 128; k += 4) {
            short4v wa = *reinterpret_cast<const short4v*>(&w2r[k]);
#pragma unroll
            for (int j = 0; j < 4; ++j) a += h1[k + j] * us2f((u16)wa[j]);
        }
        float val = sr[d] + a;
        w[i] = val; s1 += val; s2 += val * val;
    }
#pragma unroll
    for (int o = 32; o > 0; o >>= 1) { s1 += __shfl_xor(s1, o, 64); s2 += __shfl_xor(s2, o, 64); }
    __syncthreads();
    if (lane == 0) { red[wid] = s1; red[4 + wid] = s2; }
    __syncthreads();
    if (t == 0) {
        float a = red[0] + red[1] + red[2] + red[3];
        float q = red[4] + red[5] + red[6] + red[7];
        float mu = a * (1.f / DD);
        float var = q * (1.f / DD) - mu * mu;
        red[8] = mu; red[9] = rsqrtf(var + 1e-5f);
    }
    __syncthreads();
    {
        float mu = red[8], rs = red[9];
#pragma unroll
        for (int i = 0; i < 4; ++i) {
            int d = t + 256 * i;
            snte[(size_t)blk * DD + d] = f2us((w[i] - mu) * rs * ln1_g[d] + ln1_b[d]);
        }
    }
}

enum { EPI_BF16 = 0, EPI_GELU = 1, EPI_RES = 2, EPI_F32 = 3 };

// ---------------- 256x256 MFMA GEMM: BK=32 double-buffer, 64KB LDS ----------------
// 2 resident blocks/CU (16 waves) -> cross-BLOCK overlap hides the per-K-step
// vmcnt(0)+barrier drain (m114: blocks share no barrier). Per K-step:
// {issue stage(t+1); 12 ds_read frags; 32 MFMA (setprio); vmcnt(0); barrier}.
// M % 256 == 0, K % 32 == 0.
template<int EPI>
__global__ __launch_bounds__(512, 4)
void gemm256(const u16* __restrict__ A, const u16* __restrict__ W,
             const float* __restrict__ bias, int M, int N, int K,
             u16* __restrict__ outB, float* __restrict__ outF,
             const float* __restrict__ res)
{
    __shared__ u16 lds[2][2][8192];       // [buf][A,B][16KB]
    const int tid = threadIdx.x;
    const int lane = tid & 63;
    const int wid = tid >> 6;
    const int wr = wid >> 2, wc = wid & 3;   // per-wave C: 128(m) x 64(n)

    // XCD-chunked bijective swizzle
    const int gx = gridDim.x;
    const int nwg = gx * gridDim.y;
    int bid = blockIdx.y * gx + blockIdx.x;
    int qq = nwg >> 3, rr = nwg & 7;
    int xcd = bid & 7, idx = bid >> 3;
    int nb = (xcd < rr ? xcd * (qq + 1) : rr * (qq + 1) + (xcd - rr) * qq) + idx;
    const int m0 = (nb / gx) * 256, n0 = (nb % gx) * 256;

    int u0 = tid, u1 = tid + 512;
    int g0 = u0 >> 6, kb0 = (u0 >> 4) & 3, r0 = u0 & 15;
    int g1 = u1 >> 6, kb1 = (u1 >> 4) & 3, r1 = u1 & 15;
    int ar0 = m0 + g0 * 16 + r0; if (ar0 >= M) ar0 = M - 1;
    int ar1 = m0 + g1 * 16 + r1; if (ar1 >= M) ar1 = M - 1;
    int br0 = n0 + g0 * 16 + r0;
    int br1 = n0 + g1 * 16 + r1;
    const u16* pa0 = A + (size_t)ar0 * K + kb0 * 8;
    const u16* pa1 = A + (size_t)ar1 * K + kb1 * 8;
    const u16* pb0 = W + (size_t)br0 * K + kb0 * 8;
    const u16* pb1 = W + (size_t)br1 * K + kb1 * 8;

    f32x4 acc[8][4];
#pragma unroll
    for (int i = 0; i < 8; ++i)
#pragma unroll
        for (int j = 0; j < 4; ++j)
            acc[i][j] = (f32x4){0.f, 0.f, 0.f, 0.f};

    // stage K-step kt into buf bf (4 loads/thread)
    auto stage = [&](int kt, int bf) {
        int kc = kt << 5;
        gload_lds16(pa0 + kc, &lds[bf][0][u0 * 8]);
        gload_lds16(pa1 + kc, &lds[bf][0][u1 * 8]);
        gload_lds16(pb0 + kc, &lds[bf][1][u0 * 8]);
        gload_lds16(pb1 + kc, &lds[bf][1][u1 * 8]);
    };

    const int nk = K >> 5;   // >= 2
    stage(0, 0);
    asm volatile("s_waitcnt vmcnt(0)" ::: "memory");
    __builtin_amdgcn_s_barrier();
    __builtin_amdgcn_sched_barrier(0);

    for (int t = 0; t < nk; ++t) {
        const int bf = t & 1, bn = bf ^ 1;
        if (t + 1 < nk) stage(t + 1, bn);
        short8 aq[8], bq[4];
#pragma unroll
        for (int j = 0; j < 4; ++j)
            bq[j] = *reinterpret_cast<const short8*>(&lds[bf][1][(wc * 4 + j) * 512 + lane * 8]);
#pragma unroll
        for (int i = 0; i < 8; ++i)
            aq[i] = *reinterpret_cast<const short8*>(&lds[bf][0][(wr * 8 + i) * 512 + lane * 8]);
        __builtin_amdgcn_s_setprio(1);
#pragma unroll
        for (int i = 0; i < 8; ++i)
#pragma unroll
            for (int j = 0; j < 4; ++j)
                acc[i][j] = __builtin_amdgcn_mfma_f32_16x16x32_bf16(aq[i], bq[j], acc[i][j], 0, 0, 0);
        __builtin_amdgcn_s_setprio(0);
        asm volatile("s_waitcnt vmcnt(0)" ::: "memory");   // t+1 resident; co-resident block covers drain
        __builtin_amdgcn_s_barrier();
        __builtin_amdgcn_sched_barrier(0);
    }

    const int cn = lane & 15, cr = (lane >> 4) * 4;
#pragma unroll
    for (int i = 0; i < 8; ++i) {
#pragma unroll
        for (int r = 0; r < 4; ++r) {
            int m = m0 + wr * 128 + i * 16 + cr + r;
            if (m >= M) continue;
#pragma unroll
            for (int j = 0; j < 4; ++j) {
                int n = n0 + wc * 64 + j * 16 + cn;
                float c = acc[i][j][r];
                if (bias) c += bias[n];
                size_t o = (size_t)m * N + n;
                if (EPI == EPI_BF16) outB[o] = f2us(c);
                else if (EPI == EPI_GELU) { float gg = c / (1.f + __expf(-1.702f * c)); outB[o] = f2us(gg); }
                else if (EPI == EPI_RES) outF[o] = res[o] + c;
                else outF[o] = c;
            }
        }
    }
}

// ---------------- 128x128 MFMA GEMM (small-M / tail shapes): ring-3, counted vmcnt ----------------
template<int EPI>
__global__ __launch_bounds__(256)
void gemm_mfma(const u16* __restrict__ A, const u16* __restrict__ W,
               const float* __restrict__ bias, int M, int N, int K,
               u16* __restrict__ outB, float* __restrict__ outF,
               const float* __restrict__ res)
{
    __shared__ u16 Als[3][128 * 32];
    __shared__ u16 Bls[3][128 * 32];
    const int tid = threadIdx.x;
    const int lane = tid & 63;
    const int wid = tid >> 6;
    const int wm = (wid >> 1) * 64, wn = (wid & 1) * 64;

    const int gx = gridDim.x;
    const int nwg = gx * gridDim.y;
    int bid = blockIdx.y * gx + blockIdx.x;
    int qq = nwg >> 3, rr = nwg & 7;
    int xcd = bid & 7, idx = bid >> 3;
    int nb = (xcd < rr ? xcd * (qq + 1) : rr * (qq + 1) + (xcd - rr) * qq) + idx;
    const int m0 = (nb / gx) * 128, n0 = (nb % gx) * 128;

    int o0 = tid, o1 = tid + 256;
    int g0 = o0 >> 6, kb0 = (o0 >> 4) & 3, r0 = o0 & 15;
    int g1 = o1 >> 6, kb1 = (o1 >> 4) & 3, r1 = o1 & 15;
    int ar0 = m0 + g0 * 16 + r0; if (ar0 >= M) ar0 = M - 1;
    int ar1 = m0 + g1 * 16 + r1; if (ar1 >= M) ar1 = M - 1;
    int br0 = n0 + g0 * 16 + r0;
    int br1 = n0 + g1 * 16 + r1;
    const u16* a0 = A + (size_t)ar0 * K + kb0 * 8;
    const u16* a1 = A + (size_t)ar1 * K + kb1 * 8;
    const u16* b0 = W + (size_t)br0 * K + kb0 * 8;
    const u16* b1 = W + (size_t)br1 * K + kb1 * 8;

    f32x4 acc[4][4];
#pragma unroll
    for (int i = 0; i < 4; ++i)
#pragma unroll
        for (int j = 0; j < 4; ++j)
            acc[i][j] = (f32x4){0.f, 0.f, 0.f, 0.f};

    auto stage = [&](int kt, int sl) {
        int kk = kt << 5;
        gload_lds16(a0 + kk, &Als[sl][o0 * 8]);
        gload_lds16(a1 + kk, &Als[sl][o1 * 8]);
        gload_lds16(b0 + kk, &Bls[sl][o0 * 8]);
        gload_lds16(b1 + kk, &Bls[sl][o1 * 8]);
    };
    auto compute = [&](int sl) {
        short8 af[4], bfr[4];
#pragma unroll
        for (int i = 0; i < 4; ++i)
            af[i] = *reinterpret_cast<const short8*>(&Als[sl][((wm >> 4) + i) * 512 + lane * 8]);
#pragma unroll
        for (int j = 0; j < 4; ++j)
            bfr[j] = *reinterpret_cast<const short8*>(&Bls[sl][((wn >> 4) + j) * 512 + lane * 8]);
        __builtin_amdgcn_s_setprio(1);
#pragma unroll
        for (int i = 0; i < 4; ++i)
#pragma unroll
            for (int j = 0; j < 4; ++j)
                acc[i][j] = __builtin_amdgcn_mfma_f32_16x16x32_bf16(af[i], bfr[j], acc[i][j], 0, 0, 0);
        __builtin_amdgcn_s_setprio(0);
    };

    const int nk = K >> 5;   // >= 4
    stage(0, 0);
    stage(1, 1);
    asm volatile("s_waitcnt vmcnt(4)" ::: "memory");
    __builtin_amdgcn_s_barrier();
    __builtin_amdgcn_sched_barrier(0);

    int t = 0;
    for (; t < nk - 2; ++t) {
        stage(t + 2, (t + 2) % 3);
        compute(t % 3);
        asm volatile("s_waitcnt vmcnt(4)" ::: "memory");
        __builtin_amdgcn_s_barrier();
        __builtin_amdgcn_sched_barrier(0);
    }
    compute(t % 3);
    asm volatile("s_waitcnt vmcnt(0)" ::: "memory");
    __builtin_amdgcn_s_barrier();
    __builtin_amdgcn_sched_barrier(0);
    ++t;
    compute(t % 3);

    const int cn = lane & 15, cr = (lane >> 4) * 4;
#pragma unroll
    for (int i = 0; i < 4; ++i) {
#pragma unroll
        for (int r = 0; r < 4; ++r) {
            int m = m0 + wm + i * 16 + cr + r;
            if (m >= M) continue;
#pragma unroll
            for (int j = 0; j < 4; ++j) {
                int n = n0 + wn + j * 16 + cn;
                float c = acc[i][j][r];
                if (bias) c += bias[n];
                size_t o = (size_t)m * N + n;
                if (EPI == EPI_BF16) outB[o] = f2us(c);
                else if (EPI == EPI_GELU) { float gg = c / (1.f + __expf(-1.702f * c)); outB[o] = f2us(gg); }
                else if (EPI == EPI_RES) outF[o] = res[o] + c;
                else outF[o] = c;
            }
        }
    }
}

// ---------------- MFMA spatial attention: one block (4 waves) per (h, b*t) ----------------
#define KSTR 72
#define VSTR 296
#define PSTR 40

__global__ __launch_bounds__(256)
void spatial_attn(const u16* __restrict__ qkv, u16* __restrict__ mix)
{
    const int h = blockIdx.x, bt = blockIdx.y;
    const int hoff = h * CC;
    const size_t base = (size_t)bt * LL * D3;
    __shared__ u16 Kls[257 * KSTR];
    __shared__ u16 Vt[64 * VSTR];
    __shared__ u16 Pb[4][16 * PSTR];
    const int tid = threadIdx.x, lane = tid & 63, w = tid >> 6;
    const int c15 = lane & 15, g = lane >> 4;

    for (int idx = tid; idx < 257 * 8; idx += 256) {
        int row = idx >> 3, c8 = (idx & 7) << 3;
        float4 v = *reinterpret_cast<const float4*>(&qkv[base + (size_t)row * D3 + DD + hoff + c8]);
        *reinterpret_cast<float4*>(&Kls[row * KSTR + c8]) = v;
    }
    for (int idx = tid; idx < 288 * 64; idx += 256) {
        int key = idx >> 6, c = idx & 63;
        u16 v = 0;
        if (key < 257) v = qkv[base + (size_t)key * D3 + 2 * DD + hoff + c];
        Vt[c * VSTR + key] = v;
    }
    __syncthreads();

    u16* pb = Pb[w];
    for (int qt = w; qt < 17; qt += 4) {
        int qrow = qt * 16 + c15; if (qrow > 256) qrow = 256;
        const u16* qp = &qkv[base + (size_t)qrow * D3 + hoff + g * 8];
        short8 a0 = *reinterpret_cast<const short8*>(qp);
        short8 a1 = *reinterpret_cast<const short8*>(qp + 32);

        f32x4 sc[17];
#pragma unroll
        for (int t = 0; t < 17; ++t) sc[t] = (f32x4){0.f, 0.f, 0.f, 0.f};
        __builtin_amdgcn_s_setprio(1);
#pragma unroll
        for (int t = 0; t < 17; ++t) {
            int krow = t * 16 + c15; if (krow > 256) krow = 256;
            short8 b0 = *reinterpret_cast<const short8*>(&Kls[krow * KSTR + g * 8]);
            short8 b1 = *reinterpret_cast<const short8*>(&Kls[krow * KSTR + 32 + g * 8]);
            sc[t] = __builtin_amdgcn_mfma_f32_16x16x32_bf16(a0, b0, sc[t], 0, 0, 0);
            sc[t] = __builtin_amdgcn_mfma_f32_16x16x32_bf16(a1, b1, sc[t], 0, 0, 0);
        }
        __builtin_amdgcn_s_setprio(0);

        const bool lastv = (c15 == 0);
#pragma unroll
        for (int r = 0; r < 4; ++r) {
            float mx = -1e30f;
#pragma unroll
            for (int t = 0; t < 17; ++t) {
                float v = sc[t][r] * 0.125f;
                if (t == 16 && !lastv) v = -1e30f;
                sc[t][r] = v;
                mx = fmaxf(mx, v);
            }
            mx = fmaxf(mx, __shfl_xor(mx, 1, 64));
            mx = fmaxf(mx, __shfl_xor(mx, 2, 64));
            mx = fmaxf(mx, __shfl_xor(mx, 4, 64));
            mx = fmaxf(mx, __shfl_xor(mx, 8, 64));
            float sum = 0.f;
#pragma unroll
            for (int t = 0; t < 17; ++t) { float e = __expf(sc[t][r] - mx); sc[t][r] = e; sum += e; }
            sum += __shfl_xor(sum, 1, 64);
            sum += __shfl_xor(sum, 2, 64);
            sum += __shfl_xor(sum, 4, 64);
            sum += __shfl_xor(sum, 8, 64);
            float is = 1.f / sum;
#pragma unroll
            for (int t = 0; t < 17; ++t) sc[t][r] *= is;
        }

        f32x4 oacc[4];
#pragma unroll
        for (int ct = 0; ct < 4; ++ct) oacc[ct] = (f32x4){0.f, 0.f, 0.f, 0.f};
#pragma unroll
        for (int k0 = 0; k0 < 9; ++k0) {
            const int t0 = 2 * k0, t1 = 2 * k0 + 1;
#pragma unroll
            for (int r = 0; r < 4; ++r) {
                pb[(4 * g + r) * PSTR + c15]      = f2us(sc[t0][r]);
                pb[(4 * g + r) * PSTR + 16 + c15] = (t1 < 17) ? f2us(sc[t1][r]) : (u16)0;
            }
            short8 pa = *reinterpret_cast<const short8*>(&pb[c15 * PSTR + 8 * g]);
            __builtin_amdgcn_s_setprio(1);
#pragma unroll
            for (int ct = 0; ct < 4; ++ct) {
                short8 vb = *reinterpret_cast<const short8*>(&Vt[(16 * ct + c15) * VSTR + 32 * k0 + 8 * g]);
                oacc[ct] = __builtin_amdgcn_mfma_f32_16x16x32_bf16(pa, vb, oacc[ct], 0, 0, 0);
            }
            __builtin_amdgcn_s_setprio(0);
        }

#pragma unroll
        for (int r = 0; r < 4; ++r) {
            int q = qt * 16 + 4 * g + r;
            if (q >= LL) continue;
            size_t ob = ((size_t)bt * LL + q) * DD + hoff;
#pragma unroll
            for (int ct = 0; ct < 4; ++ct)
                mix[ob + 16 * ct + c15] = f2us(oacc[ct][r]);
        }
    }
}

// ---------------- syno-token attention: one block (4 waves) per (h, b*t) ----------------
#define SK 68

__global__ __launch_bounds__(256)
void s_attn(const u16* __restrict__ qkv, const u16* __restrict__ snqkv,
            const u16* __restrict__ teqkv, const float* __restrict__ pmask,
            float* __restrict__ smix)
{
    const int h = blockIdx.x, bt = blockIdx.y, b = bt >> 3, t = bt & 7;
    const int hoff = h * CC;
    const int tid = threadIdx.x, lane = tid & 63, w = tid >> 6;
    __shared__ u16 Kls[256 * SK];
    __shared__ u16 Vls[256 * SK];
    __shared__ float pls[4][256];
    const size_t base = (size_t)bt * LL * D3;

    const int c8 = (tid & 7) * 8;
    const u16* tekp = &teqkv[t * D3 + DD + hoff + c8];
    const u16* tevp = &teqkv[t * D3 + 2 * DD + hoff + c8];
    float tek[8], tev[8];
#pragma unroll
    for (int j = 0; j < 8; ++j) { tek[j] = us2f(tekp[j]); tev[j] = us2f(tevp[j]); }
#pragma unroll
    for (int pass = 0; pass < 8; ++pass) {
        int key = (tid >> 3) + 32 * pass;
        const u16* kp = &qkv[base + (size_t)(key + 1) * D3 + DD + hoff + c8];
        const u16* vp = &qkv[base + (size_t)(key + 1) * D3 + 2 * DD + hoff + c8];
        short4v k0 = *reinterpret_cast<const short4v*>(kp);
        short4v k1 = *reinterpret_cast<const short4v*>(kp + 4);
        short4v v0 = *reinterpret_cast<const short4v*>(vp);
        short4v v1 = *reinterpret_cast<const short4v*>(vp + 4);
        short4v ok0, ok1, ov0, ov1;
#pragma unroll
        for (int j = 0; j < 4; ++j) {
            ok0[j] = (short)f2us(us2f((u16)k0[j]) + tek[j]);
            ok1[j] = (short)f2us(us2f((u16)k1[j]) + tek[4 + j]);
            ov0[j] = (short)f2us(us2f((u16)v0[j]) + tev[j]);
            ov1[j] = (short)f2us(us2f((u16)v1[j]) + tev[4 + j]);
        }
        *reinterpret_cast<short4v*>(&Kls[key * SK + c8]) = ok0;
        *reinterpret_cast<short4v*>(&Kls[key * SK + c8 + 4]) = ok1;
        *reinterpret_cast<short4v*>(&Vls[key * SK + c8]) = ov0;
        *reinterpret_cast<short4v*>(&Vls[key * SK + c8 + 4]) = ov1;
    }
    __syncthreads();

    const float* pm = pmask + (size_t)bt * 256;
    for (int qi = w; qi < SS; qi += 4) {
        float qc = us2f(snqkv[(size_t)(b * SS + qi) * D3 + hoff + lane]) * 0.125f;
        float sc[4] = {0.f, 0.f, 0.f, 0.f};
        for (int c = 0; c < CC; ++c) {
            float qv = __shfl(qc, c, 64);
#pragma unroll
            for (int j = 0; j < 4; ++j)
                sc[j] += qv * us2f(Kls[(lane + 64 * j) * SK + c]);
        }
#pragma unroll
        for (int j = 0; j < 4; ++j) sc[j] += pm[lane + 64 * j];
        float mx = fmaxf(fmaxf(sc[0], sc[1]), fmaxf(sc[2], sc[3]));
#pragma unroll
        for (int o = 32; o > 0; o >>= 1) mx = fmaxf(mx, __shfl_xor(mx, o, 64));
        float sum = 0.f;
#pragma unroll
        for (int j = 0; j < 4; ++j) { sc[j] = __expf(sc[j] - mx); sum += sc[j]; }
#pragma unroll
        for (int o = 32; o > 0; o >>= 1) sum += __shfl_xor(sum, o, 64);
        float inv = 1.f / sum;
#pragma unroll
        for (int j = 0; j < 4; ++j) pls[w][lane + 64 * j] = sc[j] * inv;
        float acc = 0.f;
        for (int key = 0; key < 256; ++key)
            acc += pls[w][key] * us2f(Vls[key * SK + lane]);
        smix[(((size_t)bt * SS + qi) * HH + h) * CC + lane] = acc;
    }
}

// ---------------- depthwise temporal conv + residual + mean over T ----------------
__global__ __launch_bounds__(256)
void conv_mean(const float* __restrict__ smix, const float* __restrict__ cw,
               const float* __restrict__ cb, u16* __restrict__ out)
{
    int idx = blockIdx.x * 256 + threadIdx.x;
    int d = idx & 1023;
    int bs = idx >> 10;
    int b = bs >> 3, s_ = bs & 7;
    float z[TT];
#pragma unroll
    for (int t = 0; t < TT; ++t)
        z[t] = smix[((size_t)(b * TT + t) * SS + s_) * DD + d];
    float w0 = cw[d * 3], w1 = cw[d * 3 + 1], w2 = cw[d * 3 + 2];
    float acc = 0.f;
#pragma unroll
    for (int t = 0; t < TT; ++t) {
        float zc = w1 * z[t];
        if (t > 0)      zc += w0 * z[t - 1];
        if (t < TT - 1) zc += w2 * z[t + 1];
        acc += z[t] + zc;
    }
    out[(size_t)bs * DD + d] = f2us(acc * 0.125f + cb[d]);
}

// ---------------- host: launch sequence ----------------
extern "C" void kernel_launch(void* const* d_in, const int* in_sizes, int n_in,
                              void* d_out, int out_size, void* d_ws, size_t ws_size,
                              hipStream_t stream)
{
    const float* x      = (const float*)d_in[0];
    const float* s      = (const float*)d_in[1];
    const float* te     = (const float*)d_in[2];
    const float* pmask  = (const float*)d_in[3];
    const float* in_w   = (const float*)d_in[4];
    const float* in_b   = (const float*)d_in[5];
    const float* out_w  = (const float*)d_in[6];
    const float* out_b  = (const float*)d_in[7];
    const float* ln1_g  = (const float*)d_in[8];
    const float* ln1_b  = (const float*)d_in[9];
    const float* ln2_g  = (const float*)d_in[10];
    const float* ln2_b  = (const float*)d_in[11];
    const float* fc_w   = (const float*)d_in[12];
    const float* fc_b   = (const float*)d_in[13];
    const float* proj_w = (const float*)d_in[14];
    const float* proj_b = (const float*)d_in[15];
    const float* smlp_g = (const float*)d_in[16];
    const float* smlp_b = (const float*)d_in[17];
    const float* w1     = (const float*)d_in[18];
    const float* w2     = (const float*)d_in[19];
    const float* lnte_g = (const float*)d_in[20];
    const float* lnte_b = (const float*)d_in[21];
    const float* conv_w = (const float*)d_in[22];
    const float* conv_b = (const float*)d_in[23];

    float* outx = (float*)d_out;                     // [NTOK, 1024]
    float* outs = outx + (size_t)NTOK * DD;          // [64, 1024]

    char* ws = (char*)d_ws;
    u16* qkv    = (u16*)ws;                                      // [NTOK,3072] bf16
    u16* mixb   = (u16*)(ws + (size_t)NTOK * D3 * 2);            // [NTOK,1024] bf16
    u16* hidden = qkv;                                           // [NTOK,4096] overlay (exact)
    u16* xn     = (u16*)(ws + (size_t)NTOK * DFF * 2);           // [NTOK,1024] bf16
    char* sm    = ws + (size_t)NTOK * DFF * 2 + (size_t)NTOK * DD * 2;
    u16*  snte   = (u16*)sm;  sm += (size_t)72 * DD * 2;         // [72,1024]
    u16*  sqkv72 = (u16*)sm;  sm += (size_t)72 * D3 * 2;         // [72,3072]
    float* smix = (float*)sm; sm += (size_t)BB * TT * SS * DD * 4;
    u16*  smm   = (u16*)sm;   sm += 64 * DD * 2;
    u16*  ln2s  = (u16*)sm;   sm += 64 * DD * 2;
    u16*  hids  = (u16*)sm;   sm += 64 * DFF * 2;
    // bf16 weights
    u16* in_wb   = (u16*)sm;  sm += (size_t)D3 * DD * 2;
    u16* out_wb  = (u16*)sm;  sm += (size_t)DD * DD * 2;
    u16* fc_wb   = (u16*)sm;  sm += (size_t)DFF * DD * 2;
    u16* proj_wb = (u16*)sm;  sm += (size_t)DD * DFF * 2;
    u16* w1b     = (u16*)sm;  sm += (size_t)128 * DD * 2;
    u16* w2b     = (u16*)sm;  sm += (size_t)DD * 128 * 2;

    const float* FNULL = nullptr;
    u16* UNULL = nullptr;

    // 0. weight conversions
    auto cvt = [&](const float* src, u16* dst, int n) {
        hipLaunchKernelGGL(cvt_w, dim3((n / 4 + 255) / 256), dim3(256), 0, stream, src, dst, n / 4);
    };
    cvt(in_w,   in_wb,   D3 * DD);
    cvt(out_w,  out_wb,  DD * DD);
    cvt(fc_w,   fc_wb,   DFF * DD);
    cvt(proj_w, proj_wb, DD * DFF);
    cvt(w1,     w1b,     128 * DD);
    cvt(w2,     w2b,     DD * 128);

    const int MT64 = MMAIN / 256;   // 64 m-tiles -> grid multiples of 256

    // 1. xn = LN1(x)
    hipLaunchKernelGGL(ln_rows, dim3(NTOK), dim3(256), 0, stream, x, FNULL, ln1_g, ln1_b, xn, NTOK);
    // 2. qkv = xn @ in_proj_w^T + b   (main + tail)
    hipLaunchKernelGGL((gemm256<EPI_BF16>), dim3(D3 / 256, MT64), dim3(512), 0, stream,
                       xn, in_wb, in_b, MMAIN, D3, DD, qkv, (float*)nullptr, FNULL);
    hipLaunchKernelGGL((gemm_mfma<EPI_BF16>), dim3(D3 / 128, 1), dim3(256), 0, stream,
                       xn + (size_t)MMAIN * DD, in_wb, in_b, MTAIL, D3, DD,
                       qkv + (size_t)MMAIN * D3, (float*)nullptr, FNULL);
    // 3. spatial attention -> mix
    hipLaunchKernelGGL(spatial_attn, dim3(HH, BB * TT), dim3(256), 0, stream, qkv, mixb);
    // 4. outx = x + mix @ out_w^T + out_b
    hipLaunchKernelGGL((gemm256<EPI_RES>), dim3(DD / 256, MT64), dim3(512), 0, stream,
                       mixb, out_wb, out_b, MMAIN, DD, DD, UNULL, outx, x);
    hipLaunchKernelGGL((gemm_mfma<EPI_RES>), dim3(DD / 128, 1), dim3(256), 0, stream,
                       mixb + (size_t)MMAIN * DD, out_wb, out_b, MTAIL, DD, DD,
                       UNULL, outx + (size_t)MMAIN * DD, x + (size_t)MMAIN * DD);
    // 5. syno-token branch
    hipLaunchKernelGGL(s_prep, dim3(65), dim3(256), 0, stream,
                       s, te, smlp_g, smlp_b, ln1_g, ln1_b, lnte_g, lnte_b, w1b, w2b, snte);
    hipLaunchKernelGGL((gemm_mfma<EPI_BF16>), dim3(D3 / 128, 1), dim3(256), 0, stream,
                       snte, in_wb, in_b, 72, D3, DD, sqkv72, (float*)nullptr, FNULL);
    hipLaunchKernelGGL(s_attn, dim3(HH, BB * TT), dim3(256), 0, stream,
                       qkv, sqkv72, sqkv72 + (size_t)64 * D3, pmask, smix);
    hipLaunchKernelGGL(conv_mean, dim3(256), dim3(256), 0, stream, smix, conv_w, conv_b, smm);
    hipLaunchKernelGGL((gemm_mfma<EPI_RES>), dim3(DD / 128, 1), dim3(256), 0, stream,
                       smm, out_wb, out_b, 64, DD, DD, UNULL, outs, s);
    // 6. x MLP: outx += proj(gelu(fc(LN2(outx))))
    hipLaunchKernelGGL(ln_rows, dim3(NTOK), dim3(256), 0, stream, outx, FNULL, ln2_g, ln2_b, xn, NTOK);
    hipLaunchKernelGGL((gemm256<EPI_GELU>), dim3(DFF / 256, MT64), dim3(512), 0, stream,
                       xn, fc_wb, fc_b, MMAIN, DFF, DD, hidden, (float*)nullptr, FNULL);
    hipLaunchKernelGGL((gemm_mfma<EPI_GELU>), dim3(DFF / 128, 1), dim3(256), 0, stream,
                       xn + (size_t)MMAIN * DD, fc_wb, fc_b, MTAIL, DFF, DD,
                       hidden + (size_t)MMAIN * DFF, (float*)nullptr, FNULL);
    hipLaunchKernelGGL((gemm256<EPI_RES>), dim3(DD / 256, MT64), dim3(512), 0, stream,
                       hidden, proj_wb, proj_b, MMAIN, DD, DFF, UNULL, outx, outx);
    hipLaunchKernelGGL((gemm_mfma<EPI_RES>), dim3(DD / 128, 1), dim3(256), 0, stream,
                       hidden + (size_t)MMAIN * DFF, proj_wb, proj_b, MTAIL, DD, DFF,
                       UNULL, outx + (size_t)MMAIN * DD, outx + (size_t)MMAIN * DD);
    // 7. s MLP
    hipLaunchKernelGGL(ln_rows, dim3(64), dim3(256), 0, stream, outs, FNULL, ln2_g, ln2_b, ln2s, 64);
    hipLaunchKernelGGL((gemm_mfma<EPI_GELU>), dim3(DFF / 128, 1), dim3(256), 0, stream,
                       ln2s, fc_wb, fc_b, 64, DFF, DD, hids, (float*)nullptr, FNULL);
    hipLaunchKernelGGL((gemm_mfma<EPI_RES>), dim3(DD / 128, 1), dim3(256), 0, stream,
                       hids, proj_wb, proj_b, 64, DD, DFF, UNULL, outs, outs);
}

// Round 14
// 1433.680 us; speedup vs baseline: 3.6206x; 3.6206x over previous
//
#include <hip/hip_runtime.h>
#include <hip/hip_bf16.h>

// ---------------- problem constants ----------------
#define BB 8
#define TT 8
#define LL 257
#define DD 1024
#define HH 16
#define CC 64
#define SS 8
#define NTOK (BB*TT*LL)   // 16448
#define D3 (3*DD)         // 3072
#define DFF (4*DD)        // 4096
#define MMAIN 16384       // 64 x 256 m-tiles; tail = 64 rows
#define MTAIL 64

typedef unsigned short u16;   // bf16 bits
typedef __attribute__((ext_vector_type(8))) short short8;
typedef __attribute__((ext_vector_type(4))) short short4v;
typedef __attribute__((ext_vector_type(4))) float f32x4;

__device__ __forceinline__ float us2f(u16 u) {
    return __uint_as_float(((unsigned int)u) << 16);
}
__device__ __forceinline__ u16 f2us(float f) {
    unsigned int u = __float_as_uint(f);
    unsigned int rb = ((u >> 16) & 1u) + 0x7fffu;   // round-to-nearest-even
    return (u16)((u + rb) >> 16);
}

__device__ __forceinline__ void gload_lds16(const u16* g, u16* l) {
    __builtin_amdgcn_global_load_lds(
        (__attribute__((address_space(1))) void*)(void*)g,
        (__attribute__((address_space(3))) void*)(void*)l, 16, 0, 0);
}

// ---------------- fp32 -> bf16 weight conversion ----------------
__global__ __launch_bounds__(256)
void cvt_w(const float* __restrict__ in, u16* __restrict__ out, int n4)
{
    int i = blockIdx.x * 256 + threadIdx.x;
    if (i >= n4) return;
    float4 v = reinterpret_cast<const float4*>(in)[i];
    ushort4 o;
    o.x = f2us(v.x); o.y = f2us(v.y); o.z = f2us(v.z); o.w = f2us(v.w);
    reinterpret_cast<ushort4*>(out)[i] = o;
}

// ---------------- LayerNorm over last dim (1024), optional residual add ----------------
__global__ __launch_bounds__(256)
void ln_rows(const float* __restrict__ X, const float* __restrict__ R,
             const float* __restrict__ g, const float* __restrict__ bta,
             u16* __restrict__ out, int M)
{
    int row = blockIdx.x;
    if (row >= M) return;
    const float* x = X + (size_t)row * DD;
    const float* r = R ? R + (size_t)row * DD : nullptr;
    int t = threadIdx.x;
    float v[4]; float s1 = 0.f, s2 = 0.f;
#pragma unroll
    for (int i = 0; i < 4; ++i) {
        float val = x[t + 256 * i];
        if (r) val += r[t + 256 * i];
        v[i] = val; s1 += val; s2 += val * val;
    }
#pragma unroll
    for (int o = 32; o > 0; o >>= 1) { s1 += __shfl_xor(s1, o, 64); s2 += __shfl_xor(s2, o, 64); }
    __shared__ float red[10];
    int wid = t >> 6, lane = t & 63;
    if (lane == 0) { red[wid] = s1; red[4 + wid] = s2; }
    __syncthreads();
    if (t == 0) {
        float a = red[0] + red[1] + red[2] + red[3];
        float q = red[4] + red[5] + red[6] + red[7];
        float mu = a * (1.f / DD);
        float var = q * (1.f / DD) - mu * mu;
        red[8] = mu; red[9] = rsqrtf(var + 1e-5f);
    }
    __syncthreads();
    float mu = red[8], rs = red[9];
#pragma unroll
    for (int i = 0; i < 4; ++i) {
        int c = t + 256 * i;
        out[(size_t)row * DD + c] = f2us((v[i] - mu) * rs * g[c] + bta[c]);
    }
}

// ---------------- fused s-branch prep ----------------
__global__ __launch_bounds__(256)
void s_prep(const float* __restrict__ s, const float* __restrict__ te,
            const float* __restrict__ smlp_g, const float* __restrict__ smlp_b,
            const float* __restrict__ ln1_g, const float* __restrict__ ln1_b,
            const float* __restrict__ lnte_g, const float* __restrict__ lnte_b,
            const u16* __restrict__ w1b, const u16* __restrict__ w2b,
            u16* __restrict__ snte)
{
    const int blk = blockIdx.x, t = threadIdx.x;
    __shared__ float red[10];
    const int wid = t >> 6, lane = t & 63;

    if (blk == 64) {   // ln_te
        const int NE = TT * DD;
        float s1 = 0.f, s2 = 0.f;
        for (int i = t; i < NE; i += 256) { float v = te[i]; s1 += v; s2 += v * v; }
#pragma unroll
        for (int o = 32; o > 0; o >>= 1) { s1 += __shfl_xor(s1, o, 64); s2 += __shfl_xor(s2, o, 64); }
        if (lane == 0) { red[wid] = s1; red[4 + wid] = s2; }
        __syncthreads();
        if (t == 0) {
            float a = red[0] + red[1] + red[2] + red[3];
            float q = red[4] + red[5] + red[6] + red[7];
            float mu = a / (float)NE;
            float var = q / (float)NE - mu * mu;
            red[8] = mu; red[9] = rsqrtf(var + 1e-5f);
        }
        __syncthreads();
        float mu = red[8], rs = red[9];
        for (int i = t; i < NE; i += 256)
            snte[(size_t)64 * DD + i] = f2us((te[i] - mu) * rs * lnte_g[i] + lnte_b[i]);
        return;
    }

    __shared__ float xrow[1024];
    __shared__ float h1[128];
    const float* sr = s + (size_t)blk * DD;

    float v[4]; float s1 = 0.f, s2 = 0.f;
#pragma unroll
    for (int i = 0; i < 4; ++i) {
        float val = sr[t + 256 * i];
        v[i] = val; s1 += val; s2 += val * val;
    }
#pragma unroll
    for (int o = 32; o > 0; o >>= 1) { s1 += __shfl_xor(s1, o, 64); s2 += __shfl_xor(s2, o, 64); }
    if (lane == 0) { red[wid] = s1; red[4 + wid] = s2; }
    __syncthreads();
    if (t == 0) {
        float a = red[0] + red[1] + red[2] + red[3];
        float q = red[4] + red[5] + red[6] + red[7];
        float mu = a * (1.f / DD);
        float var = q * (1.f / DD) - mu * mu;
        red[8] = mu; red[9] = rsqrtf(var + 1e-5f);
    }
    __syncthreads();
    {
        float mu = red[8], rs = red[9];
#pragma unroll
        for (int i = 0; i < 4; ++i) {
            int c = t + 256 * i;
            xrow[c] = (v[i] - mu) * rs * smlp_g[c] + smlp_b[c];
        }
    }
    __syncthreads();
    if (t < 128) {
        const u16* wr_ = w1b + (size_t)t * DD;
        float a0 = 0.f, a1 = 0.f;
        for (int k = 0; k < DD; k += 8) {
            short4v wa = *reinterpret_cast<const short4v*>(&wr_[k]);
            short4v wb = *reinterpret_cast<const short4v*>(&wr_[k + 4]);
#pragma unroll
            for (int j = 0; j < 4; ++j) {
                a0 += xrow[k + j] * us2f((u16)wa[j]);
                a1 += xrow[k + 4 + j] * us2f((u16)wb[j]);
            }
        }
        h1[t] = a0 + a1;
    }
    __syncthreads();
    float w[4]; s1 = 0.f; s2 = 0.f;
#pragma unroll
    for (int i = 0; i < 4; ++i) {
        int d = t + 256 * i;
        const u16* w2r = w2b + (size_t)d * 128;
        float a = 0.f;
        for (int k = 0; k < 128; k += 4) {
            short4v wa = *reinterpret_cast<const short4v*>(&w2r[k]);
#pragma unroll
            for (int j = 0; j < 4; ++j) a += h1[k + j] * us2f((u16)wa[j]);
        }
        float val = sr[d] + a;
        w[i] = val; s1 += val; s2 += val * val;
    }
#pragma unroll
    for (int o = 32; o > 0; o >>= 1) { s1 += __shfl_xor(s1, o, 64); s2 += __shfl_xor(s2, o, 64); }
    __syncthreads();
    if (lane == 0) { red[wid] = s1; red[4 + wid] = s2; }
    __syncthreads();
    if (t == 0) {
        float a = red[0] + red[1] + red[2] + red[3];
        float q = red[4] + red[5] + red[6] + red[7];
        float mu = a * (1.f / DD);
        float var = q * (1.f / DD) - mu * mu;
        red[8] = mu; red[9] = rsqrtf(var + 1e-5f);
    }
    __syncthreads();
    {
        float mu = red[8], rs = red[9];
#pragma unroll
        for (int i = 0; i < 4; ++i) {
            int d = t + 256 * i;
            snte[(size_t)blk * DD + d] = f2us((w[i] - mu) * rs * ln1_g[d] + ln1_b[d]);
        }
    }
}

enum { EPI_BF16 = 0, EPI_GELU = 1, EPI_RES = 2, EPI_F32 = 3 };

// ---------------- 256x256 MFMA GEMM, 4-phase lockstep (R10 proven config) ----------------
// Per phase: {ds_read frags; stage 1 half-tile(t+1); barrier; setprio MFMA x16;
// [vmcnt(4) at P1,P3]; barrier; sched_barrier}. M % 256 == 0, K % 64 == 0.
template<int EPI>
__global__ __launch_bounds__(512)
void gemm256(const u16* __restrict__ A, const u16* __restrict__ W,
             const float* __restrict__ bias, int M, int N, int K,
             u16* __restrict__ outB, float* __restrict__ outF,
             const float* __restrict__ res)
{
    __shared__ u16 lds[2][4][8192];       // [buf][half: Ak0,Bk0,Ak1,Bk1][16KB]
    const int tid = threadIdx.x;
    const int lane = tid & 63;
    const int wid = tid >> 6;
    const int wr = wid >> 2, wc = wid & 3;   // per-wave C: 128(m) x 64(n)

    // XCD-chunked bijective swizzle
    const int gx = gridDim.x;
    const int nwg = gx * gridDim.y;
    int bid = blockIdx.y * gx + blockIdx.x;
    int qq = nwg >> 3, rr = nwg & 7;
    int xcd = bid & 7, idx = bid >> 3;
    int nb = (xcd < rr ? xcd * (qq + 1) : rr * (qq + 1) + (xcd - rr) * qq) + idx;
    const int m0 = (nb / gx) * 256, n0 = (nb % gx) * 256;

    int u0 = tid, u1 = tid + 512;
    int g0 = u0 >> 6, kb0 = (u0 >> 4) & 3, r0 = u0 & 15;
    int g1 = u1 >> 6, kb1 = (u1 >> 4) & 3, r1 = u1 & 15;
    int ar0 = m0 + g0 * 16 + r0; if (ar0 >= M) ar0 = M - 1;
    int ar1 = m0 + g1 * 16 + r1; if (ar1 >= M) ar1 = M - 1;
    int br0 = n0 + g0 * 16 + r0;
    int br1 = n0 + g1 * 16 + r1;
    const u16* pa0 = A + (size_t)ar0 * K + kb0 * 8;
    const u16* pa1 = A + (size_t)ar1 * K + kb1 * 8;
    const u16* pb0 = W + (size_t)br0 * K + kb0 * 8;
    const u16* pb1 = W + (size_t)br1 * K + kb1 * 8;

    f32x4 acc[8][4];
#pragma unroll
    for (int i = 0; i < 8; ++i)
#pragma unroll
        for (int j = 0; j < 4; ++j)
            acc[i][j] = (f32x4){0.f, 0.f, 0.f, 0.f};

    auto stageA = [&](int kt, int s, int bf) {
        int kc = kt * 64 + s * 32;
        gload_lds16(pa0 + kc, &lds[bf][s * 2][u0 * 8]);
        gload_lds16(pa1 + kc, &lds[bf][s * 2][u1 * 8]);
    };
    auto stageB = [&](int kt, int s, int bf) {
        int kc = kt * 64 + s * 32;
        gload_lds16(pb0 + kc, &lds[bf][s * 2 + 1][u0 * 8]);
        gload_lds16(pb1 + kc, &lds[bf][s * 2 + 1][u1 * 8]);
    };

    const int nk = K >> 6;   // >= 2
    stageA(0, 0, 0); stageB(0, 0, 0); stageA(0, 1, 0); stageB(0, 1, 0);
    asm volatile("s_waitcnt vmcnt(4)" ::: "memory");   // h0,h1 of tile 0 resident
    __builtin_amdgcn_s_barrier();
    __builtin_amdgcn_sched_barrier(0);

    for (int t = 0; t < nk; ++t) {
        const int bf = t & 1, bn = bf ^ 1;
        const bool st = (t + 1 < nk);
        short8 aq[4], bq[4];
        // ---------- P0: k-slice 0, m-frags 0..3 ----------
#pragma unroll
        for (int j = 0; j < 4; ++j)
            bq[j] = *reinterpret_cast<const short8*>(&lds[bf][1][(wc * 4 + j) * 512 + lane * 8]);
#pragma unroll
        for (int i = 0; i < 4; ++i)
            aq[i] = *reinterpret_cast<const short8*>(&lds[bf][0][(wr * 8 + i) * 512 + lane * 8]);
        if (st) stageA(t + 1, 0, bn);
        __builtin_amdgcn_s_barrier();
        __builtin_amdgcn_s_setprio(1);
#pragma unroll
        for (int i = 0; i < 4; ++i)
#pragma unroll
            for (int j = 0; j < 4; ++j)
                acc[i][j] = __builtin_amdgcn_mfma_f32_16x16x32_bf16(aq[i], bq[j], acc[i][j], 0, 0, 0);
        __builtin_amdgcn_s_setprio(0);
        __builtin_amdgcn_s_barrier();
        __builtin_amdgcn_sched_barrier(0);
        // ---------- P1: k-slice 0, m-frags 4..7 ----------
#pragma unroll
        for (int i = 0; i < 4; ++i)
            aq[i] = *reinterpret_cast<const short8*>(&lds[bf][0][(wr * 8 + 4 + i) * 512 + lane * 8]);
        if (st) stageB(t + 1, 0, bn);
        __builtin_amdgcn_s_barrier();
        __builtin_amdgcn_s_setprio(1);
#pragma unroll
        for (int i = 0; i < 4; ++i)
#pragma unroll
            for (int j = 0; j < 4; ++j)
                acc[4 + i][j] = __builtin_amdgcn_mfma_f32_16x16x32_bf16(aq[i], bq[j], acc[4 + i][j], 0, 0, 0);
        __builtin_amdgcn_s_setprio(0);
        if (st) asm volatile("s_waitcnt vmcnt(4)" ::: "memory");
        else    asm volatile("s_waitcnt vmcnt(0)" ::: "memory");
        __builtin_amdgcn_s_barrier();
        __builtin_amdgcn_sched_barrier(0);
        // ---------- P2: k-slice 1, m-frags 0..3 ----------
#pragma unroll
        for (int j = 0; j < 4; ++j)
            bq[j] = *reinterpret_cast<const short8*>(&lds[bf][3][(wc * 4 + j) * 512 + lane * 8]);
#pragma unroll
        for (int i = 0; i < 4; ++i)
            aq[i] = *reinterpret_cast<const short8*>(&lds[bf][2][(wr * 8 + i) * 512 + lane * 8]);
        if (st) stageA(t + 1, 1, bn);
        __builtin_amdgcn_s_barrier();
        __builtin_amdgcn_s_setprio(1);
#pragma unroll
        for (int i = 0; i < 4; ++i)
#pragma unroll
            for (int j = 0; j < 4; ++j)
                acc[i][j] = __builtin_amdgcn_mfma_f32_16x16x32_bf16(aq[i], bq[j], acc[i][j], 0, 0, 0);
        __builtin_amdgcn_s_setprio(0);
        __builtin_amdgcn_s_barrier();
        __builtin_amdgcn_sched_barrier(0);
        // ---------- P3: k-slice 1, m-frags 4..7 ----------
#pragma unroll
        for (int i = 0; i < 4; ++i)
            aq[i] = *reinterpret_cast<const short8*>(&lds[bf][2][(wr * 8 + 4 + i) * 512 + lane * 8]);
        if (st) stageB(t + 1, 1, bn);
        __builtin_amdgcn_s_barrier();
        __builtin_amdgcn_s_setprio(1);
#pragma unroll
        for (int i = 0; i < 4; ++i)
#pragma unroll
            for (int j = 0; j < 4; ++j)
                acc[4 + i][j] = __builtin_amdgcn_mfma_f32_16x16x32_bf16(aq[i], bq[j], acc[4 + i][j], 0, 0, 0);
        __builtin_amdgcn_s_setprio(0);
        if (st) asm volatile("s_waitcnt vmcnt(4)" ::: "memory");
        __builtin_amdgcn_s_barrier();
        __builtin_amdgcn_sched_barrier(0);
    }

    const int cn = lane & 15, cr = (lane >> 4) * 4;
#pragma unroll
    for (int i = 0; i < 8; ++i) {
#pragma unroll
        for (int r = 0; r < 4; ++r) {
            int m = m0 + wr * 128 + i * 16 + cr + r;
            if (m >= M) continue;
#pragma unroll
            for (int j = 0; j < 4; ++j) {
                int n = n0 + wc * 64 + j * 16 + cn;
                float c = acc[i][j][r];
                if (bias) c += bias[n];
                size_t o = (size_t)m * N + n;
                if (EPI == EPI_BF16) outB[o] = f2us(c);
                else if (EPI == EPI_GELU) { float gg = c / (1.f + __expf(-1.702f * c)); outB[o] = f2us(gg); }
                else if (EPI == EPI_RES) outF[o] = res[o] + c;
                else outF[o] = c;
            }
        }
    }
}

// ---------------- 128x128 MFMA GEMM (small-M / tail shapes): ring-3, counted vmcnt ----------------
template<int EPI>
__global__ __launch_bounds__(256)
void gemm_mfma(const u16* __restrict__ A, const u16* __restrict__ W,
               const float* __restrict__ bias, int M, int N, int K,
               u16* __restrict__ outB, float* __restrict__ outF,
               const float* __restrict__ res)
{
    __shared__ u16 Als[3][128 * 32];
    __shared__ u16 Bls[3][128 * 32];
    const int tid = threadIdx.x;
    const int lane = tid & 63;
    const int wid = tid >> 6;
    const int wm = (wid >> 1) * 64, wn = (wid & 1) * 64;

    const int gx = gridDim.x;
    const int nwg = gx * gridDim.y;
    int bid = blockIdx.y * gx + blockIdx.x;
    int qq = nwg >> 3, rr = nwg & 7;
    int xcd = bid & 7, idx = bid >> 3;
    int nb = (xcd < rr ? xcd * (qq + 1) : rr * (qq + 1) + (xcd - rr) * qq) + idx;
    const int m0 = (nb / gx) * 128, n0 = (nb % gx) * 128;

    int o0 = tid, o1 = tid + 256;
    int g0 = o0 >> 6, kb0 = (o0 >> 4) & 3, r0 = o0 & 15;
    int g1 = o1 >> 6, kb1 = (o1 >> 4) & 3, r1 = o1 & 15;
    int ar0 = m0 + g0 * 16 + r0; if (ar0 >= M) ar0 = M - 1;
    int ar1 = m0 + g1 * 16 + r1; if (ar1 >= M) ar1 = M - 1;
    int br0 = n0 + g0 * 16 + r0;
    int br1 = n0 + g1 * 16 + r1;
    const u16* a0 = A + (size_t)ar0 * K + kb0 * 8;
    const u16* a1 = A + (size_t)ar1 * K + kb1 * 8;
    const u16* b0 = W + (size_t)br0 * K + kb0 * 8;
    const u16* b1 = W + (size_t)br1 * K + kb1 * 8;

    f32x4 acc[4][4];
#pragma unroll
    for (int i = 0; i < 4; ++i)
#pragma unroll
        for (int j = 0; j < 4; ++j)
            acc[i][j] = (f32x4){0.f, 0.f, 0.f, 0.f};

    auto stage = [&](int kt, int sl) {
        int kk = kt << 5;
        gload_lds16(a0 + kk, &Als[sl][o0 * 8]);
        gload_lds16(a1 + kk, &Als[sl][o1 * 8]);
        gload_lds16(b0 + kk, &Bls[sl][o0 * 8]);
        gload_lds16(b1 + kk, &Bls[sl][o1 * 8]);
    };
    auto compute = [&](int sl) {
        short8 af[4], bfr[4];
#pragma unroll
        for (int i = 0; i < 4; ++i)
            af[i] = *reinterpret_cast<const short8*>(&Als[sl][((wm >> 4) + i) * 512 + lane * 8]);
#pragma unroll
        for (int j = 0; j < 4; ++j)
            bfr[j] = *reinterpret_cast<const short8*>(&Bls[sl][((wn >> 4) + j) * 512 + lane * 8]);
        __builtin_amdgcn_s_setprio(1);
#pragma unroll
        for (int i = 0; i < 4; ++i)
#pragma unroll
            for (int j = 0; j < 4; ++j)
                acc[i][j] = __builtin_amdgcn_mfma_f32_16x16x32_bf16(af[i], bfr[j], acc[i][j], 0, 0, 0);
        __builtin_amdgcn_s_setprio(0);
    };

    const int nk = K >> 5;   // >= 4
    stage(0, 0);
    stage(1, 1);
    asm volatile("s_waitcnt vmcnt(4)" ::: "memory");
    __builtin_amdgcn_s_barrier();
    __builtin_amdgcn_sched_barrier(0);

    int t = 0;
    for (; t < nk - 2; ++t) {
        stage(t + 2, (t + 2) % 3);
        compute(t % 3);
        asm volatile("s_waitcnt vmcnt(4)" ::: "memory");
        __builtin_amdgcn_s_barrier();
        __builtin_amdgcn_sched_barrier(0);
    }
    compute(t % 3);
    asm volatile("s_waitcnt vmcnt(0)" ::: "memory");
    __builtin_amdgcn_s_barrier();
    __builtin_amdgcn_sched_barrier(0);
    ++t;
    compute(t % 3);

    const int cn = lane & 15, cr = (lane >> 4) * 4;
#pragma unroll
    for (int i = 0; i < 4; ++i) {
#pragma unroll
        for (int r = 0; r < 4; ++r) {
            int m = m0 + wm + i * 16 + cr + r;
            if (m >= M) continue;
#pragma unroll
            for (int j = 0; j < 4; ++j) {
                int n = n0 + wn + j * 16 + cn;
                float c = acc[i][j][r];
                if (bias) c += bias[n];
                size_t o = (size_t)m * N + n;
                if (EPI == EPI_BF16) outB[o] = f2us(c);
                else if (EPI == EPI_GELU) { float gg = c / (1.f + __expf(-1.702f * c)); outB[o] = f2us(gg); }
                else if (EPI == EPI_RES) outF[o] = res[o] + c;
                else outF[o] = c;
            }
        }
    }
}

// ---------------- MFMA spatial attention: one block (4 waves) per (h, b*t) ----------------
// VSTR = 298 (149 dwords, odd) -> V-transpose stores/reads spread across all 32
// banks (was 148 dwords: 8-bank cycle -> ~8-way conflicts).
#define KSTR 72
#define VSTR 298
#define PSTR 40

__global__ __launch_bounds__(256)
void spatial_attn(const u16* __restrict__ qkv, u16* __restrict__ mix)
{
    const int h = blockIdx.x, bt = blockIdx.y;
    const int hoff = h * CC;
    const size_t base = (size_t)bt * LL * D3;
    __shared__ u16 Kls[257 * KSTR];
    __shared__ u16 Vt[64 * VSTR];
    __shared__ u16 Pb[4][16 * PSTR];
    const int tid = threadIdx.x, lane = tid & 63, w = tid >> 6;
    const int c15 = lane & 15, g = lane >> 4;

    for (int idx = tid; idx < 257 * 8; idx += 256) {
        int row = idx >> 3, c8 = (idx & 7) << 3;
        float4 v = *reinterpret_cast<const float4*>(&qkv[base + (size_t)row * D3 + DD + hoff + c8]);
        *reinterpret_cast<float4*>(&Kls[row * KSTR + c8]) = v;
    }
    for (int idx = tid; idx < 288 * 64; idx += 256) {
        int key = idx >> 6, c = idx & 63;
        u16 v = 0;
        if (key < 257) v = qkv[base + (size_t)key * D3 + 2 * DD + hoff + c];
        Vt[c * VSTR + key] = v;
    }
    __syncthreads();

    u16* pb = Pb[w];
    for (int qt = w; qt < 17; qt += 4) {
        int qrow = qt * 16 + c15; if (qrow > 256) qrow = 256;
        const u16* qp = &qkv[base + (size_t)qrow * D3 + hoff + g * 8];
        short8 a0 = *reinterpret_cast<const short8*>(qp);
        short8 a1 = *reinterpret_cast<const short8*>(qp + 32);

        f32x4 sc[17];
#pragma unroll
        for (int t = 0; t < 17; ++t) sc[t] = (f32x4){0.f, 0.f, 0.f, 0.f};
        __builtin_amdgcn_s_setprio(1);
#pragma unroll
        for (int t = 0; t < 17; ++t) {
            int krow = t * 16 + c15; if (krow > 256) krow = 256;
            short8 b0 = *reinterpret_cast<const short8*>(&Kls[krow * KSTR + g * 8]);
            short8 b1 = *reinterpret_cast<const short8*>(&Kls[krow * KSTR + 32 + g * 8]);
            sc[t] = __builtin_amdgcn_mfma_f32_16x16x32_bf16(a0, b0, sc[t], 0, 0, 0);
            sc[t] = __builtin_amdgcn_mfma_f32_16x16x32_bf16(a1, b1, sc[t], 0, 0, 0);
        }
        __builtin_amdgcn_s_setprio(0);

        const bool lastv = (c15 == 0);
#pragma unroll
        for (int r = 0; r < 4; ++r) {
            float mx = -1e30f;
#pragma unroll
            for (int t = 0; t < 17; ++t) {
                float v = sc[t][r] * 0.125f;
                if (t == 16 && !lastv) v = -1e30f;
                sc[t][r] = v;
                mx = fmaxf(mx, v);
            }
            mx = fmaxf(mx, __shfl_xor(mx, 1, 64));
            mx = fmaxf(mx, __shfl_xor(mx, 2, 64));
            mx = fmaxf(mx, __shfl_xor(mx, 4, 64));
            mx = fmaxf(mx, __shfl_xor(mx, 8, 64));
            float sum = 0.f;
#pragma unroll
            for (int t = 0; t < 17; ++t) { float e = __expf(sc[t][r] - mx); sc[t][r] = e; sum += e; }
            sum += __shfl_xor(sum, 1, 64);
            sum += __shfl_xor(sum, 2, 64);
            sum += __shfl_xor(sum, 4, 64);
            sum += __shfl_xor(sum, 8, 64);
            float is = 1.f / sum;
#pragma unroll
            for (int t = 0; t < 17; ++t) sc[t][r] *= is;
        }

        f32x4 oacc[4];
#pragma unroll
        for (int ct = 0; ct < 4; ++ct) oacc[ct] = (f32x4){0.f, 0.f, 0.f, 0.f};
#pragma unroll
        for (int k0 = 0; k0 < 9; ++k0) {
            const int t0 = 2 * k0, t1 = 2 * k0 + 1;
#pragma unroll
            for (int r = 0; r < 4; ++r) {
                pb[(4 * g + r) * PSTR + c15]      = f2us(sc[t0][r]);
                pb[(4 * g + r) * PSTR + 16 + c15] = (t1 < 17) ? f2us(sc[t1][r]) : (u16)0;
            }
            short8 pa = *reinterpret_cast<const short8*>(&pb[c15 * PSTR + 8 * g]);
            __builtin_amdgcn_s_setprio(1);
#pragma unroll
            for (int ct = 0; ct < 4; ++ct) {
                short8 vb = *reinterpret_cast<const short8*>(&Vt[(16 * ct + c15) * VSTR + 32 * k0 + 8 * g]);
                oacc[ct] = __builtin_amdgcn_mfma_f32_16x16x32_bf16(pa, vb, oacc[ct], 0, 0, 0);
            }
            __builtin_amdgcn_s_setprio(0);
        }

#pragma unroll
        for (int r = 0; r < 4; ++r) {
            int q = qt * 16 + 4 * g + r;
            if (q >= LL) continue;
            size_t ob = ((size_t)bt * LL + q) * DD + hoff;
#pragma unroll
            for (int ct = 0; ct < 4; ++ct)
                mix[ob + 16 * ct + c15] = f2us(oacc[ct][r]);
        }
    }
}

// ---------------- syno-token attention: one block (4 waves) per (h, b*t) ----------------
#define SK 68

__global__ __launch_bounds__(256)
void s_attn(const u16* __restrict__ qkv, const u16* __restrict__ snqkv,
            const u16* __restrict__ teqkv, const float* __restrict__ pmask,
            float* __restrict__ smix)
{
    const int h = blockIdx.x, bt = blockIdx.y, b = bt >> 3, t = bt & 7;
    const int hoff = h * CC;
    const int tid = threadIdx.x, lane = tid & 63, w = tid >> 6;
    __shared__ u16 Kls[256 * SK];
    __shared__ u16 Vls[256 * SK];
    __shared__ float pls[4][256];
    const size_t base = (size_t)bt * LL * D3;

    const int c8 = (tid & 7) * 8;
    const u16* tekp = &teqkv[t * D3 + DD + hoff + c8];
    const u16* tevp = &teqkv[t * D3 + 2 * DD + hoff + c8];
    float tek[8], tev[8];
#pragma unroll
    for (int j = 0; j < 8; ++j) { tek[j] = us2f(tekp[j]); tev[j] = us2f(tevp[j]); }
#pragma unroll
    for (int pass = 0; pass < 8; ++pass) {
        int key = (tid >> 3) + 32 * pass;
        const u16* kp = &qkv[base + (size_t)(key + 1) * D3 + DD + hoff + c8];
        const u16* vp = &qkv[base + (size_t)(key + 1) * D3 + 2 * DD + hoff + c8];
        short4v k0 = *reinterpret_cast<const short4v*>(kp);
        short4v k1 = *reinterpret_cast<const short4v*>(kp + 4);
        short4v v0 = *reinterpret_cast<const short4v*>(vp);
        short4v v1 = *reinterpret_cast<const short4v*>(vp + 4);
        short4v ok0, ok1, ov0, ov1;
#pragma unroll
        for (int j = 0; j < 4; ++j) {
            ok0[j] = (short)f2us(us2f((u16)k0[j]) + tek[j]);
            ok1[j] = (short)f2us(us2f((u16)k1[j]) + tek[4 + j]);
            ov0[j] = (short)f2us(us2f((u16)v0[j]) + tev[j]);
            ov1[j] = (short)f2us(us2f((u16)v1[j]) + tev[4 + j]);
        }
        *reinterpret_cast<short4v*>(&Kls[key * SK + c8]) = ok0;
        *reinterpret_cast<short4v*>(&Kls[key * SK + c8 + 4]) = ok1;
        *reinterpret_cast<short4v*>(&Vls[key * SK + c8]) = ov0;
        *reinterpret_cast<short4v*>(&Vls[key * SK + c8 + 4]) = ov1;
    }
    __syncthreads();

    const float* pm = pmask + (size_t)bt * 256;
    for (int qi = w; qi < SS; qi += 4) {
        float qc = us2f(snqkv[(size_t)(b * SS + qi) * D3 + hoff + lane]) * 0.125f;
        float sc[4] = {0.f, 0.f, 0.f, 0.f};
        for (int c = 0; c < CC; ++c) {
            float qv = __shfl(qc, c, 64);
#pragma unroll
            for (int j = 0; j < 4; ++j)
                sc[j] += qv * us2f(Kls[(lane + 64 * j) * SK + c]);
        }
#pragma unroll
        for (int j = 0; j < 4; ++j) sc[j] += pm[lane + 64 * j];
        float mx = fmaxf(fmaxf(sc[0], sc[1]), fmaxf(sc[2], sc[3]));
#pragma unroll
        for (int o = 32; o > 0; o >>= 1) mx = fmaxf(mx, __shfl_xor(mx, o, 64));
        float sum = 0.f;
#pragma unroll
        for (int j = 0; j < 4; ++j) { sc[j] = __expf(sc[j] - mx); sum += sc[j]; }
#pragma unroll
        for (int o = 32; o > 0; o >>= 1) sum += __shfl_xor(sum, o, 64);
        float inv = 1.f / sum;
#pragma unroll
        for (int j = 0; j < 4; ++j) pls[w][lane + 64 * j] = sc[j] * inv;
        float acc = 0.f;
        for (int key = 0; key < 256; ++key)
            acc += pls[w][key] * us2f(Vls[key * SK + lane]);
        smix[(((size_t)bt * SS + qi) * HH + h) * CC + lane] = acc;
    }
}

// ---------------- depthwise temporal conv + residual + mean over T ----------------
__global__ __launch_bounds__(256)
void conv_mean(const float* __restrict__ smix, const float* __restrict__ cw,
               const float* __restrict__ cb, u16* __restrict__ out)
{
    int idx = blockIdx.x * 256 + threadIdx.x;
    int d = idx & 1023;
    int bs = idx >> 10;
    int b = bs >> 3, s_ = bs & 7;
    float z[TT];
#pragma unroll
    for (int t = 0; t < TT; ++t)
        z[t] = smix[((size_t)(b * TT + t) * SS + s_) * DD + d];
    float w0 = cw[d * 3], w1 = cw[d * 3 + 1], w2 = cw[d * 3 + 2];
    float acc = 0.f;
#pragma unroll
    for (int t = 0; t < TT; ++t) {
        float zc = w1 * z[t];
        if (t > 0)      zc += w0 * z[t - 1];
        if (t < TT - 1) zc += w2 * z[t + 1];
        acc += z[t] + zc;
    }
    out[(size_t)bs * DD + d] = f2us(acc * 0.125f + cb[d]);
}

// ---------------- host: launch sequence ----------------
extern "C" void kernel_launch(void* const* d_in, const int* in_sizes, int n_in,
                              void* d_out, int out_size, void* d_ws, size_t ws_size,
                              hipStream_t stream)
{
    const float* x      = (const float*)d_in[0];
    const float* s      = (const float*)d_in[1];
    const float* te     = (const float*)d_in[2];
    const float* pmask  = (const float*)d_in[3];
    const float* in_w   = (const float*)d_in[4];
    const float* in_b   = (const float*)d_in[5];
    const float* out_w  = (const float*)d_in[6];
    const float* out_b  = (const float*)d_in[7];
    const float* ln1_g  = (const float*)d_in[8];
    const float* ln1_b  = (const float*)d_in[9];
    const float* ln2_g  = (const float*)d_in[10];
    const float* ln2_b  = (const float*)d_in[11];
    const float* fc_w   = (const float*)d_in[12];
    const float* fc_b   = (const float*)d_in[13];
    const float* proj_w = (const float*)d_in[14];
    const float* proj_b = (const float*)d_in[15];
    const float* smlp_g = (const float*)d_in[16];
    const float* smlp_b = (const float*)d_in[17];
    const float* w1     = (const float*)d_in[18];
    const float* w2     = (const float*)d_in[19];
    const float* lnte_g = (const float*)d_in[20];
    const float* lnte_b = (const float*)d_in[21];
    const float* conv_w = (const float*)d_in[22];
    const float* conv_b = (const float*)d_in[23];

    float* outx = (float*)d_out;                     // [NTOK, 1024]
    float* outs = outx + (size_t)NTOK * DD;          // [64, 1024]

    char* ws = (char*)d_ws;
    u16* qkv    = (u16*)ws;                                      // [NTOK,3072] bf16
    u16* mixb   = (u16*)(ws + (size_t)NTOK * D3 * 2);            // [NTOK,1024] bf16
    u16* hidden = qkv;                                           // [NTOK,4096] overlay (exact)
    u16* xn     = (u16*)(ws + (size_t)NTOK * DFF * 2);           // [NTOK,1024] bf16
    char* sm    = ws + (size_t)NTOK * DFF * 2 + (size_t)NTOK * DD * 2;
    u16*  snte   = (u16*)sm;  sm += (size_t)72 * DD * 2;         // [72,1024]
    u16*  sqkv72 = (u16*)sm;  sm += (size_t)72 * D3 * 2;         // [72,3072]
    float* smix = (float*)sm; sm += (size_t)BB * TT * SS * DD * 4;
    u16*  smm   = (u16*)sm;   sm += 64 * DD * 2;
    u16*  ln2s  = (u16*)sm;   sm += 64 * DD * 2;
    u16*  hids  = (u16*)sm;   sm += 64 * DFF * 2;
    // bf16 weights
    u16* in_wb   = (u16*)sm;  sm += (size_t)D3 * DD * 2;
    u16* out_wb  = (u16*)sm;  sm += (size_t)DD * DD * 2;
    u16* fc_wb   = (u16*)sm;  sm += (size_t)DFF * DD * 2;
    u16* proj_wb = (u16*)sm;  sm += (size_t)DD * DFF * 2;
    u16* w1b     = (u16*)sm;  sm += (size_t)128 * DD * 2;
    u16* w2b     = (u16*)sm;  sm += (size_t)DD * 128 * 2;

    const float* FNULL = nullptr;
    u16* UNULL = nullptr;

    // 0. weight conversions
    auto cvt = [&](const float* src, u16* dst, int n) {
        hipLaunchKernelGGL(cvt_w, dim3((n / 4 + 255) / 256), dim3(256), 0, stream, src, dst, n / 4);
    };
    cvt(in_w,   in_wb,   D3 * DD);
    cvt(out_w,  out_wb,  DD * DD);
    cvt(fc_w,   fc_wb,   DFF * DD);
    cvt(proj_w, proj_wb, DD * DFF);
    cvt(w1,     w1b,     128 * DD);
    cvt(w2,     w2b,     DD * 128);

    const int MT64 = MMAIN / 256;   // 64 m-tiles -> grid multiples of 256

    // 1. xn = LN1(x)
    hipLaunchKernelGGL(ln_rows, dim3(NTOK), dim3(256), 0, stream, x, FNULL, ln1_g, ln1_b, xn, NTOK);
    // 2. qkv = xn @ in_proj_w^T + b   (main + tail)
    hipLaunchKernelGGL((gemm256<EPI_BF16>), dim3(D3 / 256, MT64), dim3(512), 0, stream,
                       xn, in_wb, in_b, MMAIN, D3, DD, qkv, (float*)nullptr, FNULL);
    hipLaunchKernelGGL((gemm_mfma<EPI_BF16>), dim3(D3 / 128, 1), dim3(256), 0, stream,
                       xn + (size_t)MMAIN * DD, in_wb, in_b, MTAIL, D3, DD,
                       qkv + (size_t)MMAIN * D3, (float*)nullptr, FNULL);
    // 3. spatial attention -> mix
    hipLaunchKernelGGL(spatial_attn, dim3(HH, BB * TT), dim3(256), 0, stream, qkv, mixb);
    // 4. outx = x + mix @ out_w^T + out_b
    hipLaunchKernelGGL((gemm256<EPI_RES>), dim3(DD / 256, MT64), dim3(512), 0, stream,
                       mixb, out_wb, out_b, MMAIN, DD, DD, UNULL, outx, x);
    hipLaunchKernelGGL((gemm_mfma<EPI_RES>), dim3(DD / 128, 1), dim3(256), 0, stream,
                       mixb + (size_t)MMAIN * DD, out_wb, out_b, MTAIL, DD, DD,
                       UNULL, outx + (size_t)MMAIN * DD, x + (size_t)MMAIN * DD);
    // 5. syno-token branch
    hipLaunchKernelGGL(s_prep, dim3(65), dim3(256), 0, stream,
                       s, te, smlp_g, smlp_b, ln1_g, ln1_b, lnte_g, lnte_b, w1b, w2b, snte);
    hipLaunchKernelGGL((gemm_mfma<EPI_BF16>), dim3(D3 / 128, 1), dim3(256), 0, stream,
                       snte, in_wb, in_b, 72, D3, DD, sqkv72, (float*)nullptr, FNULL);
    hipLaunchKernelGGL(s_attn, dim3(HH, BB * TT), dim3(256), 0, stream,
                       qkv, sqkv72, sqkv72 + (size_t)64 * D3, pmask, smix);
    hipLaunchKernelGGL(conv_mean, dim3(256), dim3(256), 0, stream, smix, conv_w, conv_b, smm);
    hipLaunchKernelGGL((gemm_mfma<EPI_RES>), dim3(DD / 128, 1), dim3(256), 0, stream,
                       smm, out_wb, out_b, 64, DD, DD, UNULL, outs, s);
    // 6. x MLP: outx += proj(gelu(fc(LN2(outx))))
    hipLaunchKernelGGL(ln_rows, dim3(NTOK), dim3(256), 0, stream, outx, FNULL, ln2_g, ln2_b, xn, NTOK);
    hipLaunchKernelGGL((gemm256<EPI_GELU>), dim3(DFF / 256, MT64), dim3(512), 0, stream,
                       xn, fc_wb, fc_b, MMAIN, DFF, DD, hidden, (float*)nullptr, FNULL);
    hipLaunchKernelGGL((gemm_mfma<EPI_GELU>), dim3(DFF / 128, 1), dim3(256), 0, stream,
                       xn + (size_t)MMAIN * DD, fc_wb, fc_b, MTAIL, DFF, DD,
                       hidden + (size_t)MMAIN * DFF, (float*)nullptr, FNULL);
    hipLaunchKernelGGL((gemm256<EPI_RES>), dim3(DD / 256, MT64), dim3(512), 0, stream,
                       hidden, proj_wb, proj_b, MMAIN, DD, DFF, UNULL, outx, outx);
    hipLaunchKernelGGL((gemm_mfma<EPI_RES>), dim3(DD / 128, 1), dim3(256), 0, stream,
                       hidden + (size_t)MMAIN * DFF, proj_wb, proj_b, MTAIL, DD, DFF,
                       UNULL, outx + (size_t)MMAIN * DD, outx + (size_t)MMAIN * DD);
    // 7. s MLP
    hipLaunchKernelGGL(ln_rows, dim3(64), dim3(256), 0, stream, outs, FNULL, ln2_g, ln2_b, ln2s, 64);
    hipLaunchKernelGGL((gemm_mfma<EPI_GELU>), dim3(DFF / 128, 1), dim3(256), 0, stream,
                       ln2s, fc_wb, fc_b, 64, DFF, DD, hids, (float*)nullptr, FNULL);
    hipLaunchKernelGGL((gemm_mfma<EPI_RES>), dim3(DD / 128, 1), dim3(256), 0, stream,
                       hids, proj_wb, proj_b, 64, DD, DFF, UNULL, outs, outs);
}

// Round 15
// 1418.967 us; speedup vs baseline: 3.6581x; 1.0104x over previous
//
#include <hip/hip_runtime.h>
#include <hip/hip_bf16.h>

// ---------------- problem constants ----------------
#define BB 8
#define TT 8
#define LL 257
#define DD 1024
#define HH 16
#define CC 64
#define SS 8
#define NTOK (BB*TT*LL)   // 16448
#define D3 (3*DD)         // 3072
#define DFF (4*DD)        // 4096
#define MMAIN 16384       // 64 x 256 m-tiles; tail = 64 rows
#define MTAIL 64

typedef unsigned short u16;   // bf16 bits
typedef __attribute__((ext_vector_type(8))) short short8;
typedef __attribute__((ext_vector_type(4))) short short4v;
typedef __attribute__((ext_vector_type(4))) float f32x4;

__device__ __forceinline__ float us2f(u16 u) {
    return __uint_as_float(((unsigned int)u) << 16);
}
__device__ __forceinline__ u16 f2us(float f) {
    unsigned int u = __float_as_uint(f);
    unsigned int rb = ((u >> 16) & 1u) + 0x7fffu;   // round-to-nearest-even
    return (u16)((u + rb) >> 16);
}

__device__ __forceinline__ void gload_lds16(const u16* g, u16* l) {
    __builtin_amdgcn_global_load_lds(
        (__attribute__((address_space(1))) void*)(void*)g,
        (__attribute__((address_space(3))) void*)(void*)l, 16, 0, 0);
}

// ---------------- fp32 -> bf16 weight conversion ----------------
__global__ __launch_bounds__(256)
void cvt_w(const float* __restrict__ in, u16* __restrict__ out, int n4)
{
    int i = blockIdx.x * 256 + threadIdx.x;
    if (i >= n4) return;
    float4 v = reinterpret_cast<const float4*>(in)[i];
    ushort4 o;
    o.x = f2us(v.x); o.y = f2us(v.y); o.z = f2us(v.z); o.w = f2us(v.w);
    reinterpret_cast<ushort4*>(out)[i] = o;
}

// ---------------- LayerNorm over last dim (1024), optional residual add ----------------
// float4 loads (16B/lane) + ushort4 store: G13 vectorization.
__global__ __launch_bounds__(256)
void ln_rows(const float* __restrict__ X, const float* __restrict__ R,
             const float* __restrict__ g, const float* __restrict__ bta,
             u16* __restrict__ out, int M)
{
    int row = blockIdx.x;
    if (row >= M) return;
    const float* x = X + (size_t)row * DD;
    const float* r = R ? R + (size_t)row * DD : nullptr;
    int t = threadIdx.x;
    float4 v = *reinterpret_cast<const float4*>(&x[t * 4]);
    if (r) {
        float4 rv = *reinterpret_cast<const float4*>(&r[t * 4]);
        v.x += rv.x; v.y += rv.y; v.z += rv.z; v.w += rv.w;
    }
    float s1 = v.x + v.y + v.z + v.w;
    float s2 = v.x * v.x + v.y * v.y + v.z * v.z + v.w * v.w;
#pragma unroll
    for (int o = 32; o > 0; o >>= 1) { s1 += __shfl_xor(s1, o, 64); s2 += __shfl_xor(s2, o, 64); }
    __shared__ float red[10];
    int wid = t >> 6, lane = t & 63;
    if (lane == 0) { red[wid] = s1; red[4 + wid] = s2; }
    __syncthreads();
    if (t == 0) {
        float a = red[0] + red[1] + red[2] + red[3];
        float q = red[4] + red[5] + red[6] + red[7];
        float mu = a * (1.f / DD);
        float var = q * (1.f / DD) - mu * mu;
        red[8] = mu; red[9] = rsqrtf(var + 1e-5f);
    }
    __syncthreads();
    float mu = red[8], rs = red[9];
    float4 gv = *reinterpret_cast<const float4*>(&g[t * 4]);
    float4 bv = *reinterpret_cast<const float4*>(&bta[t * 4]);
    ushort4 o4;
    o4.x = f2us((v.x - mu) * rs * gv.x + bv.x);
    o4.y = f2us((v.y - mu) * rs * gv.y + bv.y);
    o4.z = f2us((v.z - mu) * rs * gv.z + bv.z);
    o4.w = f2us((v.w - mu) * rs * gv.w + bv.w);
    *reinterpret_cast<ushort4*>(&out[(size_t)row * DD + t * 4]) = o4;
}

// ---------------- fused s-branch prep ----------------
__global__ __launch_bounds__(256)
void s_prep(const float* __restrict__ s, const float* __restrict__ te,
            const float* __restrict__ smlp_g, const float* __restrict__ smlp_b,
            const float* __restrict__ ln1_g, const float* __restrict__ ln1_b,
            const float* __restrict__ lnte_g, const float* __restrict__ lnte_b,
            const u16* __restrict__ w1b, const u16* __restrict__ w2b,
            u16* __restrict__ snte)
{
    const int blk = blockIdx.x, t = threadIdx.x;
    __shared__ float red[10];
    const int wid = t >> 6, lane = t & 63;

    if (blk == 64) {   // ln_te
        const int NE = TT * DD;
        float s1 = 0.f, s2 = 0.f;
        for (int i = t; i < NE; i += 256) { float v = te[i]; s1 += v; s2 += v * v; }
#pragma unroll
        for (int o = 32; o > 0; o >>= 1) { s1 += __shfl_xor(s1, o, 64); s2 += __shfl_xor(s2, o, 64); }
        if (lane == 0) { red[wid] = s1; red[4 + wid] = s2; }
        __syncthreads();
        if (t == 0) {
            float a = red[0] + red[1] + red[2] + red[3];
            float q = red[4] + red[5] + red[6] + red[7];
            float mu = a / (float)NE;
            float var = q / (float)NE - mu * mu;
            red[8] = mu; red[9] = rsqrtf(var + 1e-5f);
        }
        __syncthreads();
        float mu = red[8], rs = red[9];
        for (int i = t; i < NE; i += 256)
            snte[(size_t)64 * DD + i] = f2us((te[i] - mu) * rs * lnte_g[i] + lnte_b[i]);
        return;
    }

    __shared__ float xrow[1024];
    __shared__ float h1[128];
    const float* sr = s + (size_t)blk * DD;

    float v[4]; float s1 = 0.f, s2 = 0.f;
#pragma unroll
    for (int i = 0; i < 4; ++i) {
        float val = sr[t + 256 * i];
        v[i] = val; s1 += val; s2 += val * val;
    }
#pragma unroll
    for (int o = 32; o > 0; o >>= 1) { s1 += __shfl_xor(s1, o, 64); s2 += __shfl_xor(s2, o, 64); }
    if (lane == 0) { red[wid] = s1; red[4 + wid] = s2; }
    __syncthreads();
    if (t == 0) {
        float a = red[0] + red[1] + red[2] + red[3];
        float q = red[4] + red[5] + red[6] + red[7];
        float mu = a * (1.f / DD);
        float var = q * (1.f / DD) - mu * mu;
        red[8] = mu; red[9] = rsqrtf(var + 1e-5f);
    }
    __syncthreads();
    {
        float mu = red[8], rs = red[9];
#pragma unroll
        for (int i = 0; i < 4; ++i) {
            int c = t + 256 * i;
            xrow[c] = (v[i] - mu) * rs * smlp_g[c] + smlp_b[c];
        }
    }
    __syncthreads();
    if (t < 128) {
        const u16* wr_ = w1b + (size_t)t * DD;
        float a0 = 0.f, a1 = 0.f;
        for (int k = 0; k < DD; k += 8) {
            short4v wa = *reinterpret_cast<const short4v*>(&wr_[k]);
            short4v wb = *reinterpret_cast<const short4v*>(&wr_[k + 4]);
#pragma unroll
            for (int j = 0; j < 4; ++j) {
                a0 += xrow[k + j] * us2f((u16)wa[j]);
                a1 += xrow[k + 4 + j] * us2f((u16)wb[j]);
            }
        }
        h1[t] = a0 + a1;
    }
    __syncthreads();
    float w[4]; s1 = 0.f; s2 = 0.f;
#pragma unroll
    for (int i = 0; i < 4; ++i) {
        int d = t + 256 * i;
        const u16* w2r = w2b + (size_t)d * 128;
        float a = 0.f;
        for (int k = 0; k < 128; k += 4) {
            short4v wa = *reinterpret_cast<const short4v*>(&w2r[k]);
#pragma unroll
            for (int j = 0; j < 4; ++j) a += h1[k + j] * us2f((u16)wa[j]);
        }
        float val = sr[d] + a;
        w[i] = val; s1 += val; s2 += val * val;
    }
#pragma unroll
    for (int o = 32; o > 0; o >>= 1) { s1 += __shfl_xor(s1, o, 64); s2 += __shfl_xor(s2, o, 64); }
    __syncthreads();
    if (lane == 0) { red[wid] = s1; red[4 + wid] = s2; }
    __syncthreads();
    if (t == 0) {
        float a = red[0] + red[1] + red[2] + red[3];
        float q = red[4] + red[5] + red[6] + red[7];
        float mu = a * (1.f / DD);
        float var = q * (1.f / DD) - mu * mu;
        red[8] = mu; red[9] = rsqrtf(var + 1e-5f);
    }
    __syncthreads();
    {
        float mu = red[8], rs = red[9];
#pragma unroll
        for (int i = 0; i < 4; ++i) {
            int d = t + 256 * i;
            snte[(size_t)blk * DD + d] = f2us((w[i] - mu) * rs * ln1_g[d] + ln1_b[d]);
        }
    }
}

enum { EPI_BF16 = 0, EPI_GELU = 1, EPI_RES = 2, EPI_F32 = 3 };

// ---------------- 256x256 MFMA GEMM, 4-phase lockstep (R10 proven config) ----------------
template<int EPI>
__global__ __launch_bounds__(512)
void gemm256(const u16* __restrict__ A, const u16* __restrict__ W,
             const float* __restrict__ bias, int M, int N, int K,
             u16* __restrict__ outB, float* __restrict__ outF,
             const float* __restrict__ res)
{
    __shared__ u16 lds[2][4][8192];       // [buf][half: Ak0,Bk0,Ak1,Bk1][16KB]
    const int tid = threadIdx.x;
    const int lane = tid & 63;
    const int wid = tid >> 6;
    const int wr = wid >> 2, wc = wid & 3;   // per-wave C: 128(m) x 64(n)

    // XCD-chunked bijective swizzle
    const int gx = gridDim.x;
    const int nwg = gx * gridDim.y;
    int bid = blockIdx.y * gx + blockIdx.x;
    int qq = nwg >> 3, rr = nwg & 7;
    int xcd = bid & 7, idx = bid >> 3;
    int nb = (xcd < rr ? xcd * (qq + 1) : rr * (qq + 1) + (xcd - rr) * qq) + idx;
    const int m0 = (nb / gx) * 256, n0 = (nb % gx) * 256;

    int u0 = tid, u1 = tid + 512;
    int g0 = u0 >> 6, kb0 = (u0 >> 4) & 3, r0 = u0 & 15;
    int g1 = u1 >> 6, kb1 = (u1 >> 4) & 3, r1 = u1 & 15;
    int ar0 = m0 + g0 * 16 + r0; if (ar0 >= M) ar0 = M - 1;
    int ar1 = m0 + g1 * 16 + r1; if (ar1 >= M) ar1 = M - 1;
    int br0 = n0 + g0 * 16 + r0;
    int br1 = n0 + g1 * 16 + r1;
    const u16* pa0 = A + (size_t)ar0 * K + kb0 * 8;
    const u16* pa1 = A + (size_t)ar1 * K + kb1 * 8;
    const u16* pb0 = W + (size_t)br0 * K + kb0 * 8;
    const u16* pb1 = W + (size_t)br1 * K + kb1 * 8;

    f32x4 acc[8][4];
#pragma unroll
    for (int i = 0; i < 8; ++i)
#pragma unroll
        for (int j = 0; j < 4; ++j)
            acc[i][j] = (f32x4){0.f, 0.f, 0.f, 0.f};

    auto stageA = [&](int kt, int s, int bf) {
        int kc = kt * 64 + s * 32;
        gload_lds16(pa0 + kc, &lds[bf][s * 2][u0 * 8]);
        gload_lds16(pa1 + kc, &lds[bf][s * 2][u1 * 8]);
    };
    auto stageB = [&](int kt, int s, int bf) {
        int kc = kt * 64 + s * 32;
        gload_lds16(pb0 + kc, &lds[bf][s * 2 + 1][u0 * 8]);
        gload_lds16(pb1 + kc, &lds[bf][s * 2 + 1][u1 * 8]);
    };

    const int nk = K >> 6;   // >= 2
    stageA(0, 0, 0); stageB(0, 0, 0); stageA(0, 1, 0); stageB(0, 1, 0);
    asm volatile("s_waitcnt vmcnt(4)" ::: "memory");   // h0,h1 of tile 0 resident
    __builtin_amdgcn_s_barrier();
    __builtin_amdgcn_sched_barrier(0);

    for (int t = 0; t < nk; ++t) {
        const int bf = t & 1, bn = bf ^ 1;
        const bool st = (t + 1 < nk);
        short8 aq[4], bq[4];
        // ---------- P0: k-slice 0, m-frags 0..3 ----------
#pragma unroll
        for (int j = 0; j < 4; ++j)
            bq[j] = *reinterpret_cast<const short8*>(&lds[bf][1][(wc * 4 + j) * 512 + lane * 8]);
#pragma unroll
        for (int i = 0; i < 4; ++i)
            aq[i] = *reinterpret_cast<const short8*>(&lds[bf][0][(wr * 8 + i) * 512 + lane * 8]);
        if (st) stageA(t + 1, 0, bn);
        __builtin_amdgcn_s_barrier();
        __builtin_amdgcn_s_setprio(1);
#pragma unroll
        for (int i = 0; i < 4; ++i)
#pragma unroll
            for (int j = 0; j < 4; ++j)
                acc[i][j] = __builtin_amdgcn_mfma_f32_16x16x32_bf16(aq[i], bq[j], acc[i][j], 0, 0, 0);
        __builtin_amdgcn_s_setprio(0);
        __builtin_amdgcn_s_barrier();
        __builtin_amdgcn_sched_barrier(0);
        // ---------- P1: k-slice 0, m-frags 4..7 ----------
#pragma unroll
        for (int i = 0; i < 4; ++i)
            aq[i] = *reinterpret_cast<const short8*>(&lds[bf][0][(wr * 8 + 4 + i) * 512 + lane * 8]);
        if (st) stageB(t + 1, 0, bn);
        __builtin_amdgcn_s_barrier();
        __builtin_amdgcn_s_setprio(1);
#pragma unroll
        for (int i = 0; i < 4; ++i)
#pragma unroll
            for (int j = 0; j < 4; ++j)
                acc[4 + i][j] = __builtin_amdgcn_mfma_f32_16x16x32_bf16(aq[i], bq[j], acc[4 + i][j], 0, 0, 0);
        __builtin_amdgcn_s_setprio(0);
        if (st) asm volatile("s_waitcnt vmcnt(4)" ::: "memory");
        else    asm volatile("s_waitcnt vmcnt(0)" ::: "memory");
        __builtin_amdgcn_s_barrier();
        __builtin_amdgcn_sched_barrier(0);
        // ---------- P2: k-slice 1, m-frags 0..3 ----------
#pragma unroll
        for (int j = 0; j < 4; ++j)
            bq[j] = *reinterpret_cast<const short8*>(&lds[bf][3][(wc * 4 + j) * 512 + lane * 8]);
#pragma unroll
        for (int i = 0; i < 4; ++i)
            aq[i] = *reinterpret_cast<const short8*>(&lds[bf][2][(wr * 8 + i) * 512 + lane * 8]);
        if (st) stageA(t + 1, 1, bn);
        __builtin_amdgcn_s_barrier();
        __builtin_amdgcn_s_setprio(1);
#pragma unroll
        for (int i = 0; i < 4; ++i)
#pragma unroll
            for (int j = 0; j < 4; ++j)
                acc[i][j] = __builtin_amdgcn_mfma_f32_16x16x32_bf16(aq[i], bq[j], acc[i][j], 0, 0, 0);
        __builtin_amdgcn_s_setprio(0);
        __builtin_amdgcn_s_barrier();
        __builtin_amdgcn_sched_barrier(0);
        // ---------- P3: k-slice 1, m-frags 4..7 ----------
#pragma unroll
        for (int i = 0; i < 4; ++i)
            aq[i] = *reinterpret_cast<const short8*>(&lds[bf][2][(wr * 8 + 4 + i) * 512 + lane * 8]);
        if (st) stageB(t + 1, 1, bn);
        __builtin_amdgcn_s_barrier();
        __builtin_amdgcn_s_setprio(1);
#pragma unroll
        for (int i = 0; i < 4; ++i)
#pragma unroll
            for (int j = 0; j < 4; ++j)
                acc[4 + i][j] = __builtin_amdgcn_mfma_f32_16x16x32_bf16(aq[i], bq[j], acc[4 + i][j], 0, 0, 0);
        __builtin_amdgcn_s_setprio(0);
        if (st) asm volatile("s_waitcnt vmcnt(4)" ::: "memory");
        __builtin_amdgcn_s_barrier();
        __builtin_amdgcn_sched_barrier(0);
    }

    const int cn = lane & 15, cr = (lane >> 4) * 4;
#pragma unroll
    for (int i = 0; i < 8; ++i) {
#pragma unroll
        for (int r = 0; r < 4; ++r) {
            int m = m0 + wr * 128 + i * 16 + cr + r;
            if (m >= M) continue;
#pragma unroll
            for (int j = 0; j < 4; ++j) {
                int n = n0 + wc * 64 + j * 16 + cn;
                float c = acc[i][j][r];
                if (bias) c += bias[n];
                size_t o = (size_t)m * N + n;
                if (EPI == EPI_BF16) outB[o] = f2us(c);
                else if (EPI == EPI_GELU) { float gg = c / (1.f + __expf(-1.702f * c)); outB[o] = f2us(gg); }
                else if (EPI == EPI_RES) outF[o] = res[o] + c;
                else outF[o] = c;
            }
        }
    }
}

// ---------------- 128x128 MFMA GEMM (small-M / tail shapes): ring-3, counted vmcnt ----------------
template<int EPI>
__global__ __launch_bounds__(256)
void gemm_mfma(const u16* __restrict__ A, const u16* __restrict__ W,
               const float* __restrict__ bias, int M, int N, int K,
               u16* __restrict__ outB, float* __restrict__ outF,
               const float* __restrict__ res)
{
    __shared__ u16 Als[3][128 * 32];
    __shared__ u16 Bls[3][128 * 32];
    const int tid = threadIdx.x;
    const int lane = tid & 63;
    const int wid = tid >> 6;
    const int wm = (wid >> 1) * 64, wn = (wid & 1) * 64;

    const int gx = gridDim.x;
    const int nwg = gx * gridDim.y;
    int bid = blockIdx.y * gx + blockIdx.x;
    int qq = nwg >> 3, rr = nwg & 7;
    int xcd = bid & 7, idx = bid >> 3;
    int nb = (xcd < rr ? xcd * (qq + 1) : rr * (qq + 1) + (xcd - rr) * qq) + idx;
    const int m0 = (nb / gx) * 128, n0 = (nb % gx) * 128;

    int o0 = tid, o1 = tid + 256;
    int g0 = o0 >> 6, kb0 = (o0 >> 4) & 3, r0 = o0 & 15;
    int g1 = o1 >> 6, kb1 = (o1 >> 4) & 3, r1 = o1 & 15;
    int ar0 = m0 + g0 * 16 + r0; if (ar0 >= M) ar0 = M - 1;
    int ar1 = m0 + g1 * 16 + r1; if (ar1 >= M) ar1 = M - 1;
    int br0 = n0 + g0 * 16 + r0;
    int br1 = n0 + g1 * 16 + r1;
    const u16* a0 = A + (size_t)ar0 * K + kb0 * 8;
    const u16* a1 = A + (size_t)ar1 * K + kb1 * 8;
    const u16* b0 = W + (size_t)br0 * K + kb0 * 8;
    const u16* b1 = W + (size_t)br1 * K + kb1 * 8;

    f32x4 acc[4][4];
#pragma unroll
    for (int i = 0; i < 4; ++i)
#pragma unroll
        for (int j = 0; j < 4; ++j)
            acc[i][j] = (f32x4){0.f, 0.f, 0.f, 0.f};

    auto stage = [&](int kt, int sl) {
        int kk = kt << 5;
        gload_lds16(a0 + kk, &Als[sl][o0 * 8]);
        gload_lds16(a1 + kk, &Als[sl][o1 * 8]);
        gload_lds16(b0 + kk, &Bls[sl][o0 * 8]);
        gload_lds16(b1 + kk, &Bls[sl][o1 * 8]);
    };
    auto compute = [&](int sl) {
        short8 af[4], bfr[4];
#pragma unroll
        for (int i = 0; i < 4; ++i)
            af[i] = *reinterpret_cast<const short8*>(&Als[sl][((wm >> 4) + i) * 512 + lane * 8]);
#pragma unroll
        for (int j = 0; j < 4; ++j)
            bfr[j] = *reinterpret_cast<const short8*>(&Bls[sl][((wn >> 4) + j) * 512 + lane * 8]);
        __builtin_amdgcn_s_setprio(1);
#pragma unroll
        for (int i = 0; i < 4; ++i)
#pragma unroll
            for (int j = 0; j < 4; ++j)
                acc[i][j] = __builtin_amdgcn_mfma_f32_16x16x32_bf16(af[i], bfr[j], acc[i][j], 0, 0, 0);
        __builtin_amdgcn_s_setprio(0);
    };

    const int nk = K >> 5;   // >= 4
    stage(0, 0);
    stage(1, 1);
    asm volatile("s_waitcnt vmcnt(4)" ::: "memory");
    __builtin_amdgcn_s_barrier();
    __builtin_amdgcn_sched_barrier(0);

    int t = 0;
    for (; t < nk - 2; ++t) {
        stage(t + 2, (t + 2) % 3);
        compute(t % 3);
        asm volatile("s_waitcnt vmcnt(4)" ::: "memory");
        __builtin_amdgcn_s_barrier();
        __builtin_amdgcn_sched_barrier(0);
    }
    compute(t % 3);
    asm volatile("s_waitcnt vmcnt(0)" ::: "memory");
    __builtin_amdgcn_s_barrier();
    __builtin_amdgcn_sched_barrier(0);
    ++t;
    compute(t % 3);

    const int cn = lane & 15, cr = (lane >> 4) * 4;
#pragma unroll
    for (int i = 0; i < 4; ++i) {
#pragma unroll
        for (int r = 0; r < 4; ++r) {
            int m = m0 + wm + i * 16 + cr + r;
            if (m >= M) continue;
#pragma unroll
            for (int j = 0; j < 4; ++j) {
                int n = n0 + wn + j * 16 + cn;
                float c = acc[i][j][r];
                if (bias) c += bias[n];
                size_t o = (size_t)m * N + n;
                if (EPI == EPI_BF16) outB[o] = f2us(c);
                else if (EPI == EPI_GELU) { float gg = c / (1.f + __expf(-1.702f * c)); outB[o] = f2us(gg); }
                else if (EPI == EPI_RES) outF[o] = res[o] + c;
                else outF[o] = c;
            }
        }
    }
}

// ---------------- MFMA spatial attention: one block (4 waves) per (h, b*t) ----------------
// VSTR = 290 (145 dwords, odd -> bank-spread); LDS total 79.2KB -> guaranteed
// 2 blocks/CU co-residency (cross-block latency hiding).
#define KSTR 72
#define VSTR 290
#define PSTR 40

__global__ __launch_bounds__(256)
void spatial_attn(const u16* __restrict__ qkv, u16* __restrict__ mix)
{
    const int h = blockIdx.x, bt = blockIdx.y;
    const int hoff = h * CC;
    const size_t base = (size_t)bt * LL * D3;
    __shared__ u16 Kls[257 * KSTR];
    __shared__ u16 Vt[64 * VSTR];
    __shared__ u16 Pb[4][16 * PSTR];
    const int tid = threadIdx.x, lane = tid & 63, w = tid >> 6;
    const int c15 = lane & 15, g = lane >> 4;

    for (int idx = tid; idx < 257 * 8; idx += 256) {
        int row = idx >> 3, c8 = (idx & 7) << 3;
        float4 v = *reinterpret_cast<const float4*>(&qkv[base + (size_t)row * D3 + DD + hoff + c8]);
        *reinterpret_cast<float4*>(&Kls[row * KSTR + c8]) = v;
    }
    for (int idx = tid; idx < 288 * 64; idx += 256) {
        int key = idx >> 6, c = idx & 63;
        u16 v = 0;
        if (key < 257) v = qkv[base + (size_t)key * D3 + 2 * DD + hoff + c];
        Vt[c * VSTR + key] = v;
    }
    __syncthreads();

    u16* pb = Pb[w];
    for (int qt = w; qt < 17; qt += 4) {
        int qrow = qt * 16 + c15; if (qrow > 256) qrow = 256;
        const u16* qp = &qkv[base + (size_t)qrow * D3 + hoff + g * 8];
        short8 a0 = *reinterpret_cast<const short8*>(qp);
        short8 a1 = *reinterpret_cast<const short8*>(qp + 32);

        f32x4 sc[17];
#pragma unroll
        for (int t = 0; t < 17; ++t) sc[t] = (f32x4){0.f, 0.f, 0.f, 0.f};
        __builtin_amdgcn_s_setprio(1);
#pragma unroll
        for (int t = 0; t < 17; ++t) {
            int krow = t * 16 + c15; if (krow > 256) krow = 256;
            short8 b0 = *reinterpret_cast<const short8*>(&Kls[krow * KSTR + g * 8]);
            short8 b1 = *reinterpret_cast<const short8*>(&Kls[krow * KSTR + 32 + g * 8]);
            sc[t] = __builtin_amdgcn_mfma_f32_16x16x32_bf16(a0, b0, sc[t], 0, 0, 0);
            sc[t] = __builtin_amdgcn_mfma_f32_16x16x32_bf16(a1, b1, sc[t], 0, 0, 0);
        }
        __builtin_amdgcn_s_setprio(0);

        const bool lastv = (c15 == 0);
#pragma unroll
        for (int r = 0; r < 4; ++r) {
            float mx = -1e30f;
#pragma unroll
            for (int t = 0; t < 17; ++t) {
                float v = sc[t][r] * 0.125f;
                if (t == 16 && !lastv) v = -1e30f;
                sc[t][r] = v;
                mx = fmaxf(mx, v);
            }
            mx = fmaxf(mx, __shfl_xor(mx, 1, 64));
            mx = fmaxf(mx, __shfl_xor(mx, 2, 64));
            mx = fmaxf(mx, __shfl_xor(mx, 4, 64));
            mx = fmaxf(mx, __shfl_xor(mx, 8, 64));
            float sum = 0.f;
#pragma unroll
            for (int t = 0; t < 17; ++t) { float e = __expf(sc[t][r] - mx); sc[t][r] = e; sum += e; }
            sum += __shfl_xor(sum, 1, 64);
            sum += __shfl_xor(sum, 2, 64);
            sum += __shfl_xor(sum, 4, 64);
            sum += __shfl_xor(sum, 8, 64);
            float is = 1.f / sum;
#pragma unroll
            for (int t = 0; t < 17; ++t) sc[t][r] *= is;
        }

        f32x4 oacc[4];
#pragma unroll
        for (int ct = 0; ct < 4; ++ct) oacc[ct] = (f32x4){0.f, 0.f, 0.f, 0.f};
#pragma unroll
        for (int k0 = 0; k0 < 9; ++k0) {
            const int t0 = 2 * k0, t1 = 2 * k0 + 1;
#pragma unroll
            for (int r = 0; r < 4; ++r) {
                pb[(4 * g + r) * PSTR + c15]      = f2us(sc[t0][r]);
                pb[(4 * g + r) * PSTR + 16 + c15] = (t1 < 17) ? f2us(sc[t1][r]) : (u16)0;
            }
            short8 pa = *reinterpret_cast<const short8*>(&pb[c15 * PSTR + 8 * g]);
            __builtin_amdgcn_s_setprio(1);
#pragma unroll
            for (int ct = 0; ct < 4; ++ct) {
                short8 vb = *reinterpret_cast<const short8*>(&Vt[(16 * ct + c15) * VSTR + 32 * k0 + 8 * g]);
                oacc[ct] = __builtin_amdgcn_mfma_f32_16x16x32_bf16(pa, vb, oacc[ct], 0, 0, 0);
            }
            __builtin_amdgcn_s_setprio(0);
        }

#pragma unroll
        for (int r = 0; r < 4; ++r) {
            int q = qt * 16 + 4 * g + r;
            if (q >= LL) continue;
            size_t ob = ((size_t)bt * LL + q) * DD + hoff;
#pragma unroll
            for (int ct = 0; ct < 4; ++ct)
                mix[ob + 16 * ct + c15] = f2us(oacc[ct][r]);
        }
    }
}

// ---------------- syno-token attention: one block (4 waves) per (h, b*t) ----------------
#define SK 68

__global__ __launch_bounds__(256)
void s_attn(const u16* __restrict__ qkv, const u16* __restrict__ snqkv,
            const u16* __restrict__ teqkv, const float* __restrict__ pmask,
            float* __restrict__ smix)
{
    const int h = blockIdx.x, bt = blockIdx.y, b = bt >> 3, t = bt & 7;
    const int hoff = h * CC;
    const int tid = threadIdx.x, lane = tid & 63, w = tid >> 6;
    __shared__ u16 Kls[256 * SK];
    __shared__ u16 Vls[256 * SK];
    __shared__ float pls[4][256];
    const size_t base = (size_t)bt * LL * D3;

    const int c8 = (tid & 7) * 8;
    const u16* tekp = &teqkv[t * D3 + DD + hoff + c8];
    const u16* tevp = &teqkv[t * D3 + 2 * DD + hoff + c8];
    float tek[8], tev[8];
#pragma unroll
    for (int j = 0; j < 8; ++j) { tek[j] = us2f(tekp[j]); tev[j] = us2f(tevp[j]); }
#pragma unroll
    for (int pass = 0; pass < 8; ++pass) {
        int key = (tid >> 3) + 32 * pass;
        const u16* kp = &qkv[base + (size_t)(key + 1) * D3 + DD + hoff + c8];
        const u16* vp = &qkv[base + (size_t)(key + 1) * D3 + 2 * DD + hoff + c8];
        short4v k0 = *reinterpret_cast<const short4v*>(kp);
        short4v k1 = *reinterpret_cast<const short4v*>(kp + 4);
        short4v v0 = *reinterpret_cast<const short4v*>(vp);
        short4v v1 = *reinterpret_cast<const short4v*>(vp + 4);
        short4v ok0, ok1, ov0, ov1;
#pragma unroll
        for (int j = 0; j < 4; ++j) {
            ok0[j] = (short)f2us(us2f((u16)k0[j]) + tek[j]);
            ok1[j] = (short)f2us(us2f((u16)k1[j]) + tek[4 + j]);
            ov0[j] = (short)f2us(us2f((u16)v0[j]) + tev[j]);
            ov1[j] = (short)f2us(us2f((u16)v1[j]) + tev[4 + j]);
        }
        *reinterpret_cast<short4v*>(&Kls[key * SK + c8]) = ok0;
        *reinterpret_cast<short4v*>(&Kls[key * SK + c8 + 4]) = ok1;
        *reinterpret_cast<short4v*>(&Vls[key * SK + c8]) = ov0;
        *reinterpret_cast<short4v*>(&Vls[key * SK + c8 + 4]) = ov1;
    }
    __syncthreads();

    const float* pm = pmask + (size_t)bt * 256;
    for (int qi = w; qi < SS; qi += 4) {
        float qc = us2f(snqkv[(size_t)(b * SS + qi) * D3 + hoff + lane]) * 0.125f;
        float sc[4] = {0.f, 0.f, 0.f, 0.f};
        for (int c = 0; c < CC; ++c) {
            float qv = __shfl(qc, c, 64);
#pragma unroll
            for (int j = 0; j < 4; ++j)
                sc[j] += qv * us2f(Kls[(lane + 64 * j) * SK + c]);
        }
#pragma unroll
        for (int j = 0; j < 4; ++j) sc[j] += pm[lane + 64 * j];
        float mx = fmaxf(fmaxf(sc[0], sc[1]), fmaxf(sc[2], sc[3]));
#pragma unroll
        for (int o = 32; o > 0; o >>= 1) mx = fmaxf(mx, __shfl_xor(mx, o, 64));
        float sum = 0.f;
#pragma unroll
        for (int j = 0; j < 4; ++j) { sc[j] = __expf(sc[j] - mx); sum += sc[j]; }
#pragma unroll
        for (int o = 32; o > 0; o >>= 1) sum += __shfl_xor(sum, o, 64);
        float inv = 1.f / sum;
#pragma unroll
        for (int j = 0; j < 4; ++j) pls[w][lane + 64 * j] = sc[j] * inv;
        float acc = 0.f;
        for (int key = 0; key < 256; ++key)
            acc += pls[w][key] * us2f(Vls[key * SK + lane]);
        smix[(((size_t)bt * SS + qi) * HH + h) * CC + lane] = acc;
    }
}

// ---------------- depthwise temporal conv + residual + mean over T ----------------
__global__ __launch_bounds__(256)
void conv_mean(const float* __restrict__ smix, const float* __restrict__ cw,
               const float* __restrict__ cb, u16* __restrict__ out)
{
    int idx = blockIdx.x * 256 + threadIdx.x;
    int d = idx & 1023;
    int bs = idx >> 10;
    int b = bs >> 3, s_ = bs & 7;
    float z[TT];
#pragma unroll
    for (int t = 0; t < TT; ++t)
        z[t] = smix[((size_t)(b * TT + t) * SS + s_) * DD + d];
    float w0 = cw[d * 3], w1 = cw[d * 3 + 1], w2 = cw[d * 3 + 2];
    float acc = 0.f;
#pragma unroll
    for (int t = 0; t < TT; ++t) {
        float zc = w1 * z[t];
        if (t > 0)      zc += w0 * z[t - 1];
        if (t < TT - 1) zc += w2 * z[t + 1];
        acc += z[t] + zc;
    }
    out[(size_t)bs * DD + d] = f2us(acc * 0.125f + cb[d]);
}

// ---------------- host: launch sequence ----------------
extern "C" void kernel_launch(void* const* d_in, const int* in_sizes, int n_in,
                              void* d_out, int out_size, void* d_ws, size_t ws_size,
                              hipStream_t stream)
{
    const float* x      = (const float*)d_in[0];
    const float* s      = (const float*)d_in[1];
    const float* te     = (const float*)d_in[2];
    const float* pmask  = (const float*)d_in[3];
    const float* in_w   = (const float*)d_in[4];
    const float* in_b   = (const float*)d_in[5];
    const float* out_w  = (const float*)d_in[6];
    const float* out_b  = (const float*)d_in[7];
    const float* ln1_g  = (const float*)d_in[8];
    const float* ln1_b  = (const float*)d_in[9];
    const float* ln2_g  = (const float*)d_in[10];
    const float* ln2_b  = (const float*)d_in[11];
    const float* fc_w   = (const float*)d_in[12];
    const float* fc_b   = (const float*)d_in[13];
    const float* proj_w = (const float*)d_in[14];
    const float* proj_b = (const float*)d_in[15];
    const float* smlp_g = (const float*)d_in[16];
    const float* smlp_b = (const float*)d_in[17];
    const float* w1     = (const float*)d_in[18];
    const float* w2     = (const float*)d_in[19];
    const float* lnte_g = (const float*)d_in[20];
    const float* lnte_b = (const float*)d_in[21];
    const float* conv_w = (const float*)d_in[22];
    const float* conv_b = (const float*)d_in[23];

    float* outx = (float*)d_out;                     // [NTOK, 1024]
    float* outs = outx + (size_t)NTOK * DD;          // [64, 1024]

    char* ws = (char*)d_ws;
    u16* qkv    = (u16*)ws;                                      // [NTOK,3072] bf16
    u16* mixb   = (u16*)(ws + (size_t)NTOK * D3 * 2);            // [NTOK,1024] bf16
    u16* hidden = qkv;                                           // [NTOK,4096] overlay (exact)
    u16* xn     = (u16*)(ws + (size_t)NTOK * DFF * 2);           // [NTOK,1024] bf16
    char* sm    = ws + (size_t)NTOK * DFF * 2 + (size_t)NTOK * DD * 2;
    u16*  snte   = (u16*)sm;  sm += (size_t)72 * DD * 2;         // [72,1024]
    u16*  sqkv72 = (u16*)sm;  sm += (size_t)72 * D3 * 2;         // [72,3072]
    float* smix = (float*)sm; sm += (size_t)BB * TT * SS * DD * 4;
    u16*  smm   = (u16*)sm;   sm += 64 * DD * 2;
    u16*  ln2s  = (u16*)sm;   sm += 64 * DD * 2;
    u16*  hids  = (u16*)sm;   sm += 64 * DFF * 2;
    // bf16 weights
    u16* in_wb   = (u16*)sm;  sm += (size_t)D3 * DD * 2;
    u16* out_wb  = (u16*)sm;  sm += (size_t)DD * DD * 2;
    u16* fc_wb   = (u16*)sm;  sm += (size_t)DFF * DD * 2;
    u16* proj_wb = (u16*)sm;  sm += (size_t)DD * DFF * 2;
    u16* w1b     = (u16*)sm;  sm += (size_t)128 * DD * 2;
    u16* w2b     = (u16*)sm;  sm += (size_t)DD * 128 * 2;

    const float* FNULL = nullptr;
    u16* UNULL = nullptr;

    // 0. weight conversions
    auto cvt = [&](const float* src, u16* dst, int n) {
        hipLaunchKernelGGL(cvt_w, dim3((n / 4 + 255) / 256), dim3(256), 0, stream, src, dst, n / 4);
    };
    cvt(in_w,   in_wb,   D3 * DD);
    cvt(out_w,  out_wb,  DD * DD);
    cvt(fc_w,   fc_wb,   DFF * DD);
    cvt(proj_w, proj_wb, DD * DFF);
    cvt(w1,     w1b,     128 * DD);
    cvt(w2,     w2b,     DD * 128);

    const int MT64 = MMAIN / 256;   // 64 m-tiles -> grid multiples of 256

    // 1. xn = LN1(x)
    hipLaunchKernelGGL(ln_rows, dim3(NTOK), dim3(256), 0, stream, x, FNULL, ln1_g, ln1_b, xn, NTOK);
    // 2. qkv = xn @ in_proj_w^T + b   (main + tail)
    hipLaunchKernelGGL((gemm256<EPI_BF16>), dim3(D3 / 256, MT64), dim3(512), 0, stream,
                       xn, in_wb, in_b, MMAIN, D3, DD, qkv, (float*)nullptr, FNULL);
    hipLaunchKernelGGL((gemm_mfma<EPI_BF16>), dim3(D3 / 128, 1), dim3(256), 0, stream,
                       xn + (size_t)MMAIN * DD, in_wb, in_b, MTAIL, D3, DD,
                       qkv + (size_t)MMAIN * D3, (float*)nullptr, FNULL);
    // 3. spatial attention -> mix
    hipLaunchKernelGGL(spatial_attn, dim3(HH, BB * TT), dim3(256), 0, stream, qkv, mixb);
    // 4. outx = x + mix @ out_w^T + out_b
    hipLaunchKernelGGL((gemm256<EPI_RES>), dim3(DD / 256, MT64), dim3(512), 0, stream,
                       mixb, out_wb, out_b, MMAIN, DD, DD, UNULL, outx, x);
    hipLaunchKernelGGL((gemm_mfma<EPI_RES>), dim3(DD / 128, 1), dim3(256), 0, stream,
                       mixb + (size_t)MMAIN * DD, out_wb, out_b, MTAIL, DD, DD,
                       UNULL, outx + (size_t)MMAIN * DD, x + (size_t)MMAIN * DD);
    // 5. syno-token branch
    hipLaunchKernelGGL(s_prep, dim3(65), dim3(256), 0, stream,
                       s, te, smlp_g, smlp_b, ln1_g, ln1_b, lnte_g, lnte_b, w1b, w2b, snte);
    hipLaunchKernelGGL((gemm_mfma<EPI_BF16>), dim3(D3 / 128, 1), dim3(256), 0, stream,
                       snte, in_wb, in_b, 72, D3, DD, sqkv72, (float*)nullptr, FNULL);
    hipLaunchKernelGGL(s_attn, dim3(HH, BB * TT), dim3(256), 0, stream,
                       qkv, sqkv72, sqkv72 + (size_t)64 * D3, pmask, smix);
    hipLaunchKernelGGL(conv_mean, dim3(256), dim3(256), 0, stream, smix, conv_w, conv_b, smm);
    hipLaunchKernelGGL((gemm_mfma<EPI_RES>), dim3(DD / 128, 1), dim3(256), 0, stream,
                       smm, out_wb, out_b, 64, DD, DD, UNULL, outs, s);
    // 6. x MLP: outx += proj(gelu(fc(LN2(outx))))
    hipLaunchKernelGGL(ln_rows, dim3(NTOK), dim3(256), 0, stream, outx, FNULL, ln2_g, ln2_b, xn, NTOK);
    hipLaunchKernelGGL((gemm256<EPI_GELU>), dim3(DFF / 256, MT64), dim3(512), 0, stream,
                       xn, fc_wb, fc_b, MMAIN, DFF, DD, hidden, (float*)nullptr, FNULL);
    hipLaunchKernelGGL((gemm_mfma<EPI_GELU>), dim3(DFF / 128, 1), dim3(256), 0, stream,
                       xn + (size_t)MMAIN * DD, fc_wb, fc_b, MTAIL, DFF, DD,
                       hidden + (size_t)MMAIN * DFF, (float*)nullptr, FNULL);
    hipLaunchKernelGGL((gemm256<EPI_RES>), dim3(DD / 256, MT64), dim3(512), 0, stream,
                       hidden, proj_wb, proj_b, MMAIN, DD, DFF, UNULL, outx, outx);
    hipLaunchKernelGGL((gemm_mfma<EPI_RES>), dim3(DD / 128, 1), dim3(256), 0, stream,
                       hidden + (size_t)MMAIN * DFF, proj_wb, proj_b, MTAIL, DD, DFF,
                       UNULL, outx + (size_t)MMAIN * DD, outx + (size_t)MMAIN * DD);
    // 7. s MLP
    hipLaunchKernelGGL(ln_rows, dim3(64), dim3(256), 0, stream, outs, FNULL, ln2_g, ln2_b, ln2s, 64);
    hipLaunchKernelGGL((gemm_mfma<EPI_GELU>), dim3(DFF / 128, 1), dim3(256), 0, stream,
                       ln2s, fc_wb, fc_b, 64, DFF, DD, hids, (float*)nullptr, FNULL);
    hipLaunchKernelGGL((gemm_mfma<EPI_RES>), dim3(DD / 128, 1), dim3(256), 0, stream,
                       hids, proj_wb, proj_b, 64, DD, DFF, UNULL, outs, outs);
}

// Round 16
// 1366.352 us; speedup vs baseline: 3.7990x; 1.0385x over previous
//
#include <hip/hip_runtime.h>
#include <hip/hip_bf16.h>

// ---------------- problem constants ----------------
#define BB 8
#define TT 8
#define LL 257
#define DD 1024
#define HH 16
#define CC 64
#define SS 8
#define NTOK (BB*TT*LL)   // 16448
#define D3 (3*DD)         // 3072
#define DFF (4*DD)        // 4096
#define MMAIN 16384       // 64 x 256 m-tiles; tail = 64 rows
#define MTAIL 64

typedef unsigned short u16;   // bf16 bits
typedef __attribute__((ext_vector_type(8))) short short8;
typedef __attribute__((ext_vector_type(4))) short short4v;
typedef __attribute__((ext_vector_type(4))) float f32x4;

__device__ __forceinline__ float us2f(u16 u) {
    return __uint_as_float(((unsigned int)u) << 16);
}
__device__ __forceinline__ u16 f2us(float f) {
    unsigned int u = __float_as_uint(f);
    unsigned int rb = ((u >> 16) & 1u) + 0x7fffu;   // round-to-nearest-even
    return (u16)((u + rb) >> 16);
}

__device__ __forceinline__ void gload_lds16(const u16* g, u16* l) {
    __builtin_amdgcn_global_load_lds(
        (__attribute__((address_space(1))) void*)(void*)g,
        (__attribute__((address_space(3))) void*)(void*)l, 16, 0, 0);
}

// ---------------- fp32 -> bf16 weight conversion ----------------
__global__ __launch_bounds__(256)
void cvt_w(const float* __restrict__ in, u16* __restrict__ out, int n4)
{
    int i = blockIdx.x * 256 + threadIdx.x;
    if (i >= n4) return;
    float4 v = reinterpret_cast<const float4*>(in)[i];
    ushort4 o;
    o.x = f2us(v.x); o.y = f2us(v.y); o.z = f2us(v.z); o.w = f2us(v.w);
    reinterpret_cast<ushort4*>(out)[i] = o;
}

// ---------------- LayerNorm over last dim (1024), optional residual add ----------------
__global__ __launch_bounds__(256)
void ln_rows(const float* __restrict__ X, const float* __restrict__ R,
             const float* __restrict__ g, const float* __restrict__ bta,
             u16* __restrict__ out, int M)
{
    int row = blockIdx.x;
    if (row >= M) return;
    const float* x = X + (size_t)row * DD;
    const float* r = R ? R + (size_t)row * DD : nullptr;
    int t = threadIdx.x;
    float4 v = *reinterpret_cast<const float4*>(&x[t * 4]);
    if (r) {
        float4 rv = *reinterpret_cast<const float4*>(&r[t * 4]);
        v.x += rv.x; v.y += rv.y; v.z += rv.z; v.w += rv.w;
    }
    float s1 = v.x + v.y + v.z + v.w;
    float s2 = v.x * v.x + v.y * v.y + v.z * v.z + v.w * v.w;
#pragma unroll
    for (int o = 32; o > 0; o >>= 1) { s1 += __shfl_xor(s1, o, 64); s2 += __shfl_xor(s2, o, 64); }
    __shared__ float red[10];
    int wid = t >> 6, lane = t & 63;
    if (lane == 0) { red[wid] = s1; red[4 + wid] = s2; }
    __syncthreads();
    if (t == 0) {
        float a = red[0] + red[1] + red[2] + red[3];
        float q = red[4] + red[5] + red[6] + red[7];
        float mu = a * (1.f / DD);
        float var = q * (1.f / DD) - mu * mu;
        red[8] = mu; red[9] = rsqrtf(var + 1e-5f);
    }
    __syncthreads();
    float mu = red[8], rs = red[9];
    float4 gv = *reinterpret_cast<const float4*>(&g[t * 4]);
    float4 bv = *reinterpret_cast<const float4*>(&bta[t * 4]);
    ushort4 o4;
    o4.x = f2us((v.x - mu) * rs * gv.x + bv.x);
    o4.y = f2us((v.y - mu) * rs * gv.y + bv.y);
    o4.z = f2us((v.z - mu) * rs * gv.z + bv.z);
    o4.w = f2us((v.w - mu) * rs * gv.w + bv.w);
    *reinterpret_cast<ushort4*>(&out[(size_t)row * DD + t * 4]) = o4;
}

// ---------------- fused s-branch prep ----------------
__global__ __launch_bounds__(256)
void s_prep(const float* __restrict__ s, const float* __restrict__ te,
            const float* __restrict__ smlp_g, const float* __restrict__ smlp_b,
            const float* __restrict__ ln1_g, const float* __restrict__ ln1_b,
            const float* __restrict__ lnte_g, const float* __restrict__ lnte_b,
            const u16* __restrict__ w1b, const u16* __restrict__ w2b,
            u16* __restrict__ snte)
{
    const int blk = blockIdx.x, t = threadIdx.x;
    __shared__ float red[10];
    const int wid = t >> 6, lane = t & 63;

    if (blk == 64) {   // ln_te
        const int NE = TT * DD;
        float s1 = 0.f, s2 = 0.f;
        for (int i = t; i < NE; i += 256) { float v = te[i]; s1 += v; s2 += v * v; }
#pragma unroll
        for (int o = 32; o > 0; o >>= 1) { s1 += __shfl_xor(s1, o, 64); s2 += __shfl_xor(s2, o, 64); }
        if (lane == 0) { red[wid] = s1; red[4 + wid] = s2; }
        __syncthreads();
        if (t == 0) {
            float a = red[0] + red[1] + red[2] + red[3];
            float q = red[4] + red[5] + red[6] + red[7];
            float mu = a / (float)NE;
            float var = q / (float)NE - mu * mu;
            red[8] = mu; red[9] = rsqrtf(var + 1e-5f);
        }
        __syncthreads();
        float mu = red[8], rs = red[9];
        for (int i = t; i < NE; i += 256)
            snte[(size_t)64 * DD + i] = f2us((te[i] - mu) * rs * lnte_g[i] + lnte_b[i]);
        return;
    }

    __shared__ float xrow[1024];
    __shared__ float h1[128];
    const float* sr = s + (size_t)blk * DD;

    float v[4]; float s1 = 0.f, s2 = 0.f;
#pragma unroll
    for (int i = 0; i < 4; ++i) {
        float val = sr[t + 256 * i];
        v[i] = val; s1 += val; s2 += val * val;
    }
#pragma unroll
    for (int o = 32; o > 0; o >>= 1) { s1 += __shfl_xor(s1, o, 64); s2 += __shfl_xor(s2, o, 64); }
    if (lane == 0) { red[wid] = s1; red[4 + wid] = s2; }
    __syncthreads();
    if (t == 0) {
        float a = red[0] + red[1] + red[2] + red[3];
        float q = red[4] + red[5] + red[6] + red[7];
        float mu = a * (1.f / DD);
        float var = q * (1.f / DD) - mu * mu;
        red[8] = mu; red[9] = rsqrtf(var + 1e-5f);
    }
    __syncthreads();
    {
        float mu = red[8], rs = red[9];
#pragma unroll
        for (int i = 0; i < 4; ++i) {
            int c = t + 256 * i;
            xrow[c] = (v[i] - mu) * rs * smlp_g[c] + smlp_b[c];
        }
    }
    __syncthreads();
    if (t < 128) {
        const u16* wr_ = w1b + (size_t)t * DD;
        float a0 = 0.f, a1 = 0.f;
        for (int k = 0; k < DD; k += 8) {
            short4v wa = *reinterpret_cast<const short4v*>(&wr_[k]);
            short4v wb = *reinterpret_cast<const short4v*>(&wr_[k + 4]);
#pragma unroll
            for (int j = 0; j < 4; ++j) {
                a0 += xrow[k + j] * us2f((u16)wa[j]);
                a1 += xrow[k + 4 + j] * us2f((u16)wb[j]);
            }
        }
        h1[t] = a0 + a1;
    }
    __syncthreads();
    float w[4]; s1 = 0.f; s2 = 0.f;
#pragma unroll
    for (int i = 0; i < 4; ++i) {
        int d = t + 256 * i;
        const u16* w2r = w2b + (size_t)d * 128;
        float a = 0.f;
        for (int k = 0; k < 128; k += 4) {
            short4v wa = *reinterpret_cast<const short4v*>(&w2r[k]);
#pragma unroll
            for (int j = 0; j < 4; ++j) a += h1[k + j] * us2f((u16)wa[j]);
        }
        float val = sr[d] + a;
        w[i] = val; s1 += val; s2 += val * val;
    }
#pragma unroll
    for (int o = 32; o > 0; o >>= 1) { s1 += __shfl_xor(s1, o, 64); s2 += __shfl_xor(s2, o, 64); }
    __syncthreads();
    if (lane == 0) { red[wid] = s1; red[4 + wid] = s2; }
    __syncthreads();
    if (t == 0) {
        float a = red[0] + red[1] + red[2] + red[3];
        float q = red[4] + red[5] + red[6] + red[7];
        float mu = a * (1.f / DD);
        float var = q * (1.f / DD) - mu * mu;
        red[8] = mu; red[9] = rsqrtf(var + 1e-5f);
    }
    __syncthreads();
    {
        float mu = red[8], rs = red[9];
#pragma unroll
        for (int i = 0; i < 4; ++i) {
            int d = t + 256 * i;
            snte[(size_t)blk * DD + d] = f2us((w[i] - mu) * rs * ln1_g[d] + ln1_b[d]);
        }
    }
}

enum { EPI_BF16 = 0, EPI_GELU = 1, EPI_RES = 2, EPI_F32 = 3 };

// ---------------- 256x256 MFMA GEMM, 4-phase lockstep (frozen R10 config) ----------------
template<int EPI>
__global__ __launch_bounds__(512)
void gemm256(const u16* __restrict__ A, const u16* __restrict__ W,
             const float* __restrict__ bias, int M, int N, int K,
             u16* __restrict__ outB, float* __restrict__ outF,
             const float* __restrict__ res)
{
    __shared__ u16 lds[2][4][8192];       // [buf][half: Ak0,Bk0,Ak1,Bk1][16KB]
    const int tid = threadIdx.x;
    const int lane = tid & 63;
    const int wid = tid >> 6;
    const int wr = wid >> 2, wc = wid & 3;   // per-wave C: 128(m) x 64(n)

    const int gx = gridDim.x;
    const int nwg = gx * gridDim.y;
    int bid = blockIdx.y * gx + blockIdx.x;
    int qq = nwg >> 3, rr = nwg & 7;
    int xcd = bid & 7, idx = bid >> 3;
    int nb = (xcd < rr ? xcd * (qq + 1) : rr * (qq + 1) + (xcd - rr) * qq) + idx;
    const int m0 = (nb / gx) * 256, n0 = (nb % gx) * 256;

    int u0 = tid, u1 = tid + 512;
    int g0 = u0 >> 6, kb0 = (u0 >> 4) & 3, r0 = u0 & 15;
    int g1 = u1 >> 6, kb1 = (u1 >> 4) & 3, r1 = u1 & 15;
    int ar0 = m0 + g0 * 16 + r0; if (ar0 >= M) ar0 = M - 1;
    int ar1 = m0 + g1 * 16 + r1; if (ar1 >= M) ar1 = M - 1;
    int br0 = n0 + g0 * 16 + r0;
    int br1 = n0 + g1 * 16 + r1;
    const u16* pa0 = A + (size_t)ar0 * K + kb0 * 8;
    const u16* pa1 = A + (size_t)ar1 * K + kb1 * 8;
    const u16* pb0 = W + (size_t)br0 * K + kb0 * 8;
    const u16* pb1 = W + (size_t)br1 * K + kb1 * 8;

    f32x4 acc[8][4];
#pragma unroll
    for (int i = 0; i < 8; ++i)
#pragma unroll
        for (int j = 0; j < 4; ++j)
            acc[i][j] = (f32x4){0.f, 0.f, 0.f, 0.f};

    auto stageA = [&](int kt, int s, int bf) {
        int kc = kt * 64 + s * 32;
        gload_lds16(pa0 + kc, &lds[bf][s * 2][u0 * 8]);
        gload_lds16(pa1 + kc, &lds[bf][s * 2][u1 * 8]);
    };
    auto stageB = [&](int kt, int s, int bf) {
        int kc = kt * 64 + s * 32;
        gload_lds16(pb0 + kc, &lds[bf][s * 2 + 1][u0 * 8]);
        gload_lds16(pb1 + kc, &lds[bf][s * 2 + 1][u1 * 8]);
    };

    const int nk = K >> 6;   // >= 2
    stageA(0, 0, 0); stageB(0, 0, 0); stageA(0, 1, 0); stageB(0, 1, 0);
    asm volatile("s_waitcnt vmcnt(4)" ::: "memory");
    __builtin_amdgcn_s_barrier();
    __builtin_amdgcn_sched_barrier(0);

    for (int t = 0; t < nk; ++t) {
        const int bf = t & 1, bn = bf ^ 1;
        const bool st = (t + 1 < nk);
        short8 aq[4], bq[4];
        // ---------- P0 ----------
#pragma unroll
        for (int j = 0; j < 4; ++j)
            bq[j] = *reinterpret_cast<const short8*>(&lds[bf][1][(wc * 4 + j) * 512 + lane * 8]);
#pragma unroll
        for (int i = 0; i < 4; ++i)
            aq[i] = *reinterpret_cast<const short8*>(&lds[bf][0][(wr * 8 + i) * 512 + lane * 8]);
        if (st) stageA(t + 1, 0, bn);
        __builtin_amdgcn_s_barrier();
        __builtin_amdgcn_s_setprio(1);
#pragma unroll
        for (int i = 0; i < 4; ++i)
#pragma unroll
            for (int j = 0; j < 4; ++j)
                acc[i][j] = __builtin_amdgcn_mfma_f32_16x16x32_bf16(aq[i], bq[j], acc[i][j], 0, 0, 0);
        __builtin_amdgcn_s_setprio(0);
        __builtin_amdgcn_s_barrier();
        __builtin_amdgcn_sched_barrier(0);
        // ---------- P1 ----------
#pragma unroll
        for (int i = 0; i < 4; ++i)
            aq[i] = *reinterpret_cast<const short8*>(&lds[bf][0][(wr * 8 + 4 + i) * 512 + lane * 8]);
        if (st) stageB(t + 1, 0, bn);
        __builtin_amdgcn_s_barrier();
        __builtin_amdgcn_s_setprio(1);
#pragma unroll
        for (int i = 0; i < 4; ++i)
#pragma unroll
            for (int j = 0; j < 4; ++j)
                acc[4 + i][j] = __builtin_amdgcn_mfma_f32_16x16x32_bf16(aq[i], bq[j], acc[4 + i][j], 0, 0, 0);
        __builtin_amdgcn_s_setprio(0);
        if (st) asm volatile("s_waitcnt vmcnt(4)" ::: "memory");
        else    asm volatile("s_waitcnt vmcnt(0)" ::: "memory");
        __builtin_amdgcn_s_barrier();
        __builtin_amdgcn_sched_barrier(0);
        // ---------- P2 ----------
#pragma unroll
        for (int j = 0; j < 4; ++j)
            bq[j] = *reinterpret_cast<const short8*>(&lds[bf][3][(wc * 4 + j) * 512 + lane * 8]);
#pragma unroll
        for (int i = 0; i < 4; ++i)
            aq[i] = *reinterpret_cast<const short8*>(&lds[bf][2][(wr * 8 + i) * 512 + lane * 8]);
        if (st) stageA(t + 1, 1, bn);
        __builtin_amdgcn_s_barrier();
        __builtin_amdgcn_s_setprio(1);
#pragma unroll
        for (int i = 0; i < 4; ++i)
#pragma unroll
            for (int j = 0; j < 4; ++j)
                acc[i][j] = __builtin_amdgcn_mfma_f32_16x16x32_bf16(aq[i], bq[j], acc[i][j], 0, 0, 0);
        __builtin_amdgcn_s_setprio(0);
        __builtin_amdgcn_s_barrier();
        __builtin_amdgcn_sched_barrier(0);
        // ---------- P3 ----------
#pragma unroll
        for (int i = 0; i < 4; ++i)
            aq[i] = *reinterpret_cast<const short8*>(&lds[bf][2][(wr * 8 + 4 + i) * 512 + lane * 8]);
        if (st) stageB(t + 1, 1, bn);
        __builtin_amdgcn_s_barrier();
        __builtin_amdgcn_s_setprio(1);
#pragma unroll
        for (int i = 0; i < 4; ++i)
#pragma unroll
            for (int j = 0; j < 4; ++j)
                acc[4 + i][j] = __builtin_amdgcn_mfma_f32_16x16x32_bf16(aq[i], bq[j], acc[4 + i][j], 0, 0, 0);
        __builtin_amdgcn_s_setprio(0);
        if (st) asm volatile("s_waitcnt vmcnt(4)" ::: "memory");
        __builtin_amdgcn_s_barrier();
        __builtin_amdgcn_sched_barrier(0);
    }

    const int cn = lane & 15, cr = (lane >> 4) * 4;
#pragma unroll
    for (int i = 0; i < 8; ++i) {
#pragma unroll
        for (int r = 0; r < 4; ++r) {
            int m = m0 + wr * 128 + i * 16 + cr + r;
            if (m >= M) continue;
#pragma unroll
            for (int j = 0; j < 4; ++j) {
                int n = n0 + wc * 64 + j * 16 + cn;
                float c = acc[i][j][r];
                if (bias) c += bias[n];
                size_t o = (size_t)m * N + n;
                if (EPI == EPI_BF16) outB[o] = f2us(c);
                else if (EPI == EPI_GELU) { float gg = c / (1.f + __expf(-1.702f * c)); outB[o] = f2us(gg); }
                else if (EPI == EPI_RES) outF[o] = res[o] + c;
                else outF[o] = c;
            }
        }
    }
}

// ---------------- 128x128 MFMA GEMM (small-M / tail shapes): ring-3, counted vmcnt ----------------
template<int EPI>
__global__ __launch_bounds__(256)
void gemm_mfma(const u16* __restrict__ A, const u16* __restrict__ W,
               const float* __restrict__ bias, int M, int N, int K,
               u16* __restrict__ outB, float* __restrict__ outF,
               const float* __restrict__ res)
{
    __shared__ u16 Als[3][128 * 32];
    __shared__ u16 Bls[3][128 * 32];
    const int tid = threadIdx.x;
    const int lane = tid & 63;
    const int wid = tid >> 6;
    const int wm = (wid >> 1) * 64, wn = (wid & 1) * 64;

    const int gx = gridDim.x;
    const int nwg = gx * gridDim.y;
    int bid = blockIdx.y * gx + blockIdx.x;
    int qq = nwg >> 3, rr = nwg & 7;
    int xcd = bid & 7, idx = bid >> 3;
    int nb = (xcd < rr ? xcd * (qq + 1) : rr * (qq + 1) + (xcd - rr) * qq) + idx;
    const int m0 = (nb / gx) * 128, n0 = (nb % gx) * 128;

    int o0 = tid, o1 = tid + 256;
    int g0 = o0 >> 6, kb0 = (o0 >> 4) & 3, r0 = o0 & 15;
    int g1 = o1 >> 6, kb1 = (o1 >> 4) & 3, r1 = o1 & 15;
    int ar0 = m0 + g0 * 16 + r0; if (ar0 >= M) ar0 = M - 1;
    int ar1 = m0 + g1 * 16 + r1; if (ar1 >= M) ar1 = M - 1;
    int br0 = n0 + g0 * 16 + r0;
    int br1 = n0 + g1 * 16 + r1;
    const u16* a0 = A + (size_t)ar0 * K + kb0 * 8;
    const u16* a1 = A + (size_t)ar1 * K + kb1 * 8;
    const u16* b0 = W + (size_t)br0 * K + kb0 * 8;
    const u16* b1 = W + (size_t)br1 * K + kb1 * 8;

    f32x4 acc[4][4];
#pragma unroll
    for (int i = 0; i < 4; ++i)
#pragma unroll
        for (int j = 0; j < 4; ++j)
            acc[i][j] = (f32x4){0.f, 0.f, 0.f, 0.f};

    auto stage = [&](int kt, int sl) {
        int kk = kt << 5;
        gload_lds16(a0 + kk, &Als[sl][o0 * 8]);
        gload_lds16(a1 + kk, &Als[sl][o1 * 8]);
        gload_lds16(b0 + kk, &Bls[sl][o0 * 8]);
        gload_lds16(b1 + kk, &Bls[sl][o1 * 8]);
    };
    auto compute = [&](int sl) {
        short8 af[4], bfr[4];
#pragma unroll
        for (int i = 0; i < 4; ++i)
            af[i] = *reinterpret_cast<const short8*>(&Als[sl][((wm >> 4) + i) * 512 + lane * 8]);
#pragma unroll
        for (int j = 0; j < 4; ++j)
            bfr[j] = *reinterpret_cast<const short8*>(&Bls[sl][((wn >> 4) + j) * 512 + lane * 8]);
        __builtin_amdgcn_s_setprio(1);
#pragma unroll
        for (int i = 0; i < 4; ++i)
#pragma unroll
            for (int j = 0; j < 4; ++j)
                acc[i][j] = __builtin_amdgcn_mfma_f32_16x16x32_bf16(af[i], bfr[j], acc[i][j], 0, 0, 0);
        __builtin_amdgcn_s_setprio(0);
    };

    const int nk = K >> 5;   // >= 4
    stage(0, 0);
    stage(1, 1);
    asm volatile("s_waitcnt vmcnt(4)" ::: "memory");
    __builtin_amdgcn_s_barrier();
    __builtin_amdgcn_sched_barrier(0);

    int t = 0;
    for (; t < nk - 2; ++t) {
        stage(t + 2, (t + 2) % 3);
        compute(t % 3);
        asm volatile("s_waitcnt vmcnt(4)" ::: "memory");
        __builtin_amdgcn_s_barrier();
        __builtin_amdgcn_sched_barrier(0);
    }
    compute(t % 3);
    asm volatile("s_waitcnt vmcnt(0)" ::: "memory");
    __builtin_amdgcn_s_barrier();
    __builtin_amdgcn_sched_barrier(0);
    ++t;
    compute(t % 3);

    const int cn = lane & 15, cr = (lane >> 4) * 4;
#pragma unroll
    for (int i = 0; i < 4; ++i) {
#pragma unroll
        for (int r = 0; r < 4; ++r) {
            int m = m0 + wm + i * 16 + cr + r;
            if (m >= M) continue;
#pragma unroll
            for (int j = 0; j < 4; ++j) {
                int n = n0 + wn + j * 16 + cn;
                float c = acc[i][j][r];
                if (bias) c += bias[n];
                size_t o = (size_t)m * N + n;
                if (EPI == EPI_BF16) outB[o] = f2us(c);
                else if (EPI == EPI_GELU) { float gg = c / (1.f + __expf(-1.702f * c)); outB[o] = f2us(gg); }
                else if (EPI == EPI_RES) outF[o] = res[o] + c;
                else outF[o] = c;
            }
        }
    }
}

// ---------------- MFMA spatial attention: one block (4 waves) per (h, b*t) ----------------
// K read directly from global (L2-resident, same 16B/lane pattern as Q) -> LDS
// drops to Vt+Pb = 42.2KB -> 3 blocks/CU co-resident (was 1): 3x latency hiding.
#define VSTR 290
#define PSTR 40

__global__ __launch_bounds__(256)
void spatial_attn(const u16* __restrict__ qkv, u16* __restrict__ mix)
{
    const int h = blockIdx.x, bt = blockIdx.y;
    const int hoff = h * CC;
    const size_t base = (size_t)bt * LL * D3;
    __shared__ u16 Vt[64 * VSTR];
    __shared__ u16 Pb[4][16 * PSTR];
    const int tid = threadIdx.x, lane = tid & 63, w = tid >> 6;
    const int c15 = lane & 15, g = lane >> 4;

    for (int idx = tid; idx < 288 * 64; idx += 256) {
        int key = idx >> 6, c = idx & 63;
        u16 v = 0;
        if (key < 257) v = qkv[base + (size_t)key * D3 + 2 * DD + hoff + c];
        Vt[c * VSTR + key] = v;
    }
    __syncthreads();

    u16* pb = Pb[w];
    for (int qt = w; qt < 17; qt += 4) {
        int qrow = qt * 16 + c15; if (qrow > 256) qrow = 256;
        const u16* qp = &qkv[base + (size_t)qrow * D3 + hoff + g * 8];
        short8 a0 = *reinterpret_cast<const short8*>(qp);
        short8 a1 = *reinterpret_cast<const short8*>(qp + 32);

        f32x4 sc[17];
#pragma unroll
        for (int t = 0; t < 17; ++t) sc[t] = (f32x4){0.f, 0.f, 0.f, 0.f};
#pragma unroll
        for (int t = 0; t < 17; ++t) {
            int krow = t * 16 + c15; if (krow > 256) krow = 256;
            const u16* kp = &qkv[base + (size_t)krow * D3 + DD + hoff + g * 8];
            short8 b0 = *reinterpret_cast<const short8*>(kp);
            short8 b1 = *reinterpret_cast<const short8*>(kp + 32);
            sc[t] = __builtin_amdgcn_mfma_f32_16x16x32_bf16(a0, b0, sc[t], 0, 0, 0);
            sc[t] = __builtin_amdgcn_mfma_f32_16x16x32_bf16(a1, b1, sc[t], 0, 0, 0);
        }

        const bool lastv = (c15 == 0);
#pragma unroll
        for (int r = 0; r < 4; ++r) {
            float mx = -1e30f;
#pragma unroll
            for (int t = 0; t < 17; ++t) {
                float v = sc[t][r] * 0.125f;
                if (t == 16 && !lastv) v = -1e30f;
                sc[t][r] = v;
                mx = fmaxf(mx, v);
            }
            mx = fmaxf(mx, __shfl_xor(mx, 1, 64));
            mx = fmaxf(mx, __shfl_xor(mx, 2, 64));
            mx = fmaxf(mx, __shfl_xor(mx, 4, 64));
            mx = fmaxf(mx, __shfl_xor(mx, 8, 64));
            float sum = 0.f;
#pragma unroll
            for (int t = 0; t < 17; ++t) { float e = __expf(sc[t][r] - mx); sc[t][r] = e; sum += e; }
            sum += __shfl_xor(sum, 1, 64);
            sum += __shfl_xor(sum, 2, 64);
            sum += __shfl_xor(sum, 4, 64);
            sum += __shfl_xor(sum, 8, 64);
            float is = 1.f / sum;
#pragma unroll
            for (int t = 0; t < 17; ++t) sc[t][r] *= is;
        }

        f32x4 oacc[4];
#pragma unroll
        for (int ct = 0; ct < 4; ++ct) oacc[ct] = (f32x4){0.f, 0.f, 0.f, 0.f};
#pragma unroll
        for (int k0 = 0; k0 < 9; ++k0) {
            const int t0 = 2 * k0, t1 = 2 * k0 + 1;
#pragma unroll
            for (int r = 0; r < 4; ++r) {
                pb[(4 * g + r) * PSTR + c15]      = f2us(sc[t0][r]);
                pb[(4 * g + r) * PSTR + 16 + c15] = (t1 < 17) ? f2us(sc[t1][r]) : (u16)0;
            }
            short8 pa = *reinterpret_cast<const short8*>(&pb[c15 * PSTR + 8 * g]);
            __builtin_amdgcn_s_setprio(1);
#pragma unroll
            for (int ct = 0; ct < 4; ++ct) {
                short8 vb = *reinterpret_cast<const short8*>(&Vt[(16 * ct + c15) * VSTR + 32 * k0 + 8 * g]);
                oacc[ct] = __builtin_amdgcn_mfma_f32_16x16x32_bf16(pa, vb, oacc[ct], 0, 0, 0);
            }
            __builtin_amdgcn_s_setprio(0);
        }

#pragma unroll
        for (int r = 0; r < 4; ++r) {
            int q = qt * 16 + 4 * g + r;
            if (q >= LL) continue;
            size_t ob = ((size_t)bt * LL + q) * DD + hoff;
#pragma unroll
            for (int ct = 0; ct < 4; ++ct)
                mix[ob + 16 * ct + c15] = f2us(oacc[ct][r]);
        }
    }
}

// ---------------- syno-token attention: one block (4 waves) per (h, b*t) ----------------
#define SK 68

__global__ __launch_bounds__(256)
void s_attn(const u16* __restrict__ qkv, const u16* __restrict__ snqkv,
            const u16* __restrict__ teqkv, const float* __restrict__ pmask,
            float* __restrict__ smix)
{
    const int h = blockIdx.x, bt = blockIdx.y, b = bt >> 3, t = bt & 7;
    const int hoff = h * CC;
    const int tid = threadIdx.x, lane = tid & 63, w = tid >> 6;
    __shared__ u16 Kls[256 * SK];
    __shared__ u16 Vls[256 * SK];
    __shared__ float pls[4][256];
    const size_t base = (size_t)bt * LL * D3;

    const int c8 = (tid & 7) * 8;
    const u16* tekp = &teqkv[t * D3 + DD + hoff + c8];
    const u16* tevp = &teqkv[t * D3 + 2 * DD + hoff + c8];
    float tek[8], tev[8];
#pragma unroll
    for (int j = 0; j < 8; ++j) { tek[j] = us2f(tekp[j]); tev[j] = us2f(tevp[j]); }
#pragma unroll
    for (int pass = 0; pass < 8; ++pass) {
        int key = (tid >> 3) + 32 * pass;
        const u16* kp = &qkv[base + (size_t)(key + 1) * D3 + DD + hoff + c8];
        const u16* vp = &qkv[base + (size_t)(key + 1) * D3 + 2 * DD + hoff + c8];
        short4v k0 = *reinterpret_cast<const short4v*>(kp);
        short4v k1 = *reinterpret_cast<const short4v*>(kp + 4);
        short4v v0 = *reinterpret_cast<const short4v*>(vp);
        short4v v1 = *reinterpret_cast<const short4v*>(vp + 4);
        short4v ok0, ok1, ov0, ov1;
#pragma unroll
        for (int j = 0; j < 4; ++j) {
            ok0[j] = (short)f2us(us2f((u16)k0[j]) + tek[j]);
            ok1[j] = (short)f2us(us2f((u16)k1[j]) + tek[4 + j]);
            ov0[j] = (short)f2us(us2f((u16)v0[j]) + tev[j]);
            ov1[j] = (short)f2us(us2f((u16)v1[j]) + tev[4 + j]);
        }
        *reinterpret_cast<short4v*>(&Kls[key * SK + c8]) = ok0;
        *reinterpret_cast<short4v*>(&Kls[key * SK + c8 + 4]) = ok1;
        *reinterpret_cast<short4v*>(&Vls[key * SK + c8]) = ov0;
        *reinterpret_cast<short4v*>(&Vls[key * SK + c8 + 4]) = ov1;
    }
    __syncthreads();

    const float* pm = pmask + (size_t)bt * 256;
    for (int qi = w; qi < SS; qi += 4) {
        float qc = us2f(snqkv[(size_t)(b * SS + qi) * D3 + hoff + lane]) * 0.125f;
        float sc[4] = {0.f, 0.f, 0.f, 0.f};
        for (int c = 0; c < CC; ++c) {
            float qv = __shfl(qc, c, 64);
#pragma unroll
            for (int j = 0; j < 4; ++j)
                sc[j] += qv * us2f(Kls[(lane + 64 * j) * SK + c]);
        }
#pragma unroll
        for (int j = 0; j < 4; ++j) sc[j] += pm[lane + 64 * j];
        float mx = fmaxf(fmaxf(sc[0], sc[1]), fmaxf(sc[2], sc[3]));
#pragma unroll
        for (int o = 32; o > 0; o >>= 1) mx = fmaxf(mx, __shfl_xor(mx, o, 64));
        float sum = 0.f;
#pragma unroll
        for (int j = 0; j < 4; ++j) { sc[j] = __expf(sc[j] - mx); sum += sc[j]; }
#pragma unroll
        for (int o = 32; o > 0; o >>= 1) sum += __shfl_xor(sum, o, 64);
        float inv = 1.f / sum;
#pragma unroll
        for (int j = 0; j < 4; ++j) pls[w][lane + 64 * j] = sc[j] * inv;
        float acc = 0.f;
        for (int key = 0; key < 256; ++key)
            acc += pls[w][key] * us2f(Vls[key * SK + lane]);
        smix[(((size_t)bt * SS + qi) * HH + h) * CC + lane] = acc;
    }
}

// ---------------- depthwise temporal conv + residual + mean over T ----------------
__global__ __launch_bounds__(256)
void conv_mean(const float* __restrict__ smix, const float* __restrict__ cw,
               const float* __restrict__ cb, u16* __restrict__ out)
{
    int idx = blockIdx.x * 256 + threadIdx.x;
    int d = idx & 1023;
    int bs = idx >> 10;
    int b = bs >> 3, s_ = bs & 7;
    float z[TT];
#pragma unroll
    for (int t = 0; t < TT; ++t)
        z[t] = smix[((size_t)(b * TT + t) * SS + s_) * DD + d];
    float w0 = cw[d * 3], w1 = cw[d * 3 + 1], w2 = cw[d * 3 + 2];
    float acc = 0.f;
#pragma unroll
    for (int t = 0; t < TT; ++t) {
        float zc = w1 * z[t];
        if (t > 0)      zc += w0 * z[t - 1];
        if (t < TT - 1) zc += w2 * z[t + 1];
        acc += z[t] + zc;
    }
    out[(size_t)bs * DD + d] = f2us(acc * 0.125f + cb[d]);
}

// ---------------- host: launch sequence ----------------
extern "C" void kernel_launch(void* const* d_in, const int* in_sizes, int n_in,
                              void* d_out, int out_size, void* d_ws, size_t ws_size,
                              hipStream_t stream)
{
    const float* x      = (const float*)d_in[0];
    const float* s      = (const float*)d_in[1];
    const float* te     = (const float*)d_in[2];
    const float* pmask  = (const float*)d_in[3];
    const float* in_w   = (const float*)d_in[4];
    const float* in_b   = (const float*)d_in[5];
    const float* out_w  = (const float*)d_in[6];
    const float* out_b  = (const float*)d_in[7];
    const float* ln1_g  = (const float*)d_in[8];
    const float* ln1_b  = (const float*)d_in[9];
    const float* ln2_g  = (const float*)d_in[10];
    const float* ln2_b  = (const float*)d_in[11];
    const float* fc_w   = (const float*)d_in[12];
    const float* fc_b   = (const float*)d_in[13];
    const float* proj_w = (const float*)d_in[14];
    const float* proj_b = (const float*)d_in[15];
    const float* smlp_g = (const float*)d_in[16];
    const float* smlp_b = (const float*)d_in[17];
    const float* w1     = (const float*)d_in[18];
    const float* w2     = (const float*)d_in[19];
    const float* lnte_g = (const float*)d_in[20];
    const float* lnte_b = (const float*)d_in[21];
    const float* conv_w = (const float*)d_in[22];
    const float* conv_b = (const float*)d_in[23];

    float* outx = (float*)d_out;                     // [NTOK, 1024]
    float* outs = outx + (size_t)NTOK * DD;          // [64, 1024] (contiguous after outx)

    char* ws = (char*)d_ws;
    u16* qkv    = (u16*)ws;                                      // [NTOK,3072] bf16
    u16* mixb   = (u16*)(ws + (size_t)NTOK * D3 * 2);            // [NTOK,1024] bf16
    u16* hidden = qkv;                                           // [NTOK+64,4096] overlay (tail rows
                                                                 // spill into dead xn rows 0..255)
    u16* xn     = (u16*)(ws + (size_t)NTOK * DFF * 2);           // [NTOK+64,1024] bf16 (rows NTOK.. = ln2s)
    char* sm    = ws + (size_t)NTOK * DFF * 2 + (size_t)(NTOK + 64) * DD * 2;
    u16*  snte   = (u16*)sm;  sm += (size_t)72 * DD * 2;         // [72,1024]
    u16*  sqkv72 = (u16*)sm;  sm += (size_t)72 * D3 * 2;         // [72,3072]
    float* smix = (float*)sm; sm += (size_t)BB * TT * SS * DD * 4;
    u16*  smm   = (u16*)sm;   sm += 64 * DD * 2;
    // bf16 weights
    u16* in_wb   = (u16*)sm;  sm += (size_t)D3 * DD * 2;
    u16* out_wb  = (u16*)sm;  sm += (size_t)DD * DD * 2;
    u16* fc_wb   = (u16*)sm;  sm += (size_t)DFF * DD * 2;
    u16* proj_wb = (u16*)sm;  sm += (size_t)DD * DFF * 2;
    u16* w1b     = (u16*)sm;  sm += (size_t)128 * DD * 2;
    u16* w2b     = (u16*)sm;  sm += (size_t)DD * 128 * 2;

    const float* FNULL = nullptr;
    u16* UNULL = nullptr;

    // 0. weight conversions
    auto cvt = [&](const float* src, u16* dst, int n) {
        hipLaunchKernelGGL(cvt_w, dim3((n / 4 + 255) / 256), dim3(256), 0, stream, src, dst, n / 4);
    };
    cvt(in_w,   in_wb,   D3 * DD);
    cvt(out_w,  out_wb,  DD * DD);
    cvt(fc_w,   fc_wb,   DFF * DD);
    cvt(proj_w, proj_wb, DD * DFF);
    cvt(w1,     w1b,     128 * DD);
    cvt(w2,     w2b,     DD * 128);

    const int MT64 = MMAIN / 256;   // 64 m-tiles -> grid multiples of 256

    // 1. xn = LN1(x)
    hipLaunchKernelGGL(ln_rows, dim3(NTOK), dim3(256), 0, stream, x, FNULL, ln1_g, ln1_b, xn, NTOK);
    // 2. qkv = xn @ in_proj_w^T + b   (main + tail)
    hipLaunchKernelGGL((gemm256<EPI_BF16>), dim3(D3 / 256, MT64), dim3(512), 0, stream,
                       xn, in_wb, in_b, MMAIN, D3, DD, qkv, (float*)nullptr, FNULL);
    hipLaunchKernelGGL((gemm_mfma<EPI_BF16>), dim3(D3 / 128, 1), dim3(256), 0, stream,
                       xn + (size_t)MMAIN * DD, in_wb, in_b, MTAIL, D3, DD,
                       qkv + (size_t)MMAIN * D3, (float*)nullptr, FNULL);
    // 3. spatial attention -> mix
    hipLaunchKernelGGL(spatial_attn, dim3(HH, BB * TT), dim3(256), 0, stream, qkv, mixb);
    // 4. outx = x + mix @ out_w^T + out_b
    hipLaunchKernelGGL((gemm256<EPI_RES>), dim3(DD / 256, MT64), dim3(512), 0, stream,
                       mixb, out_wb, out_b, MMAIN, DD, DD, UNULL, outx, x);
    hipLaunchKernelGGL((gemm_mfma<EPI_RES>), dim3(DD / 128, 1), dim3(256), 0, stream,
                       mixb + (size_t)MMAIN * DD, out_wb, out_b, MTAIL, DD, DD,
                       UNULL, outx + (size_t)MMAIN * DD, x + (size_t)MMAIN * DD);
    // 5. syno-token branch
    hipLaunchKernelGGL(s_prep, dim3(65), dim3(256), 0, stream,
                       s, te, smlp_g, smlp_b, ln1_g, ln1_b, lnte_g, lnte_b, w1b, w2b, snte);
    hipLaunchKernelGGL((gemm_mfma<EPI_BF16>), dim3(D3 / 128, 1), dim3(256), 0, stream,
                       snte, in_wb, in_b, 72, D3, DD, sqkv72, (float*)nullptr, FNULL);
    hipLaunchKernelGGL(s_attn, dim3(HH, BB * TT), dim3(256), 0, stream,
                       qkv, sqkv72, sqkv72 + (size_t)64 * D3, pmask, smix);
    hipLaunchKernelGGL(conv_mean, dim3(256), dim3(256), 0, stream, smix, conv_w, conv_b, smm);
    hipLaunchKernelGGL((gemm_mfma<EPI_RES>), dim3(DD / 128, 1), dim3(256), 0, stream,
                       smm, out_wb, out_b, 64, DD, DD, UNULL, outs, s);
    // 6. MLP (x main + merged x-tail/s rows):
    //    ln2 over outx (NTOK rows) -> xn rows 0..NTOK-1; ln2 over outs -> xn rows NTOK..NTOK+63
    hipLaunchKernelGGL(ln_rows, dim3(NTOK), dim3(256), 0, stream, outx, FNULL, ln2_g, ln2_b, xn, NTOK);
    hipLaunchKernelGGL(ln_rows, dim3(64), dim3(256), 0, stream, outs, FNULL, ln2_g, ln2_b,
                       xn + (size_t)NTOK * DD, 64);
    // fc: main (MMAIN rows) + merged tail (128 rows = x-tail 64 + s 64)
    hipLaunchKernelGGL((gemm256<EPI_GELU>), dim3(DFF / 256, MT64), dim3(512), 0, stream,
                       xn, fc_wb, fc_b, MMAIN, DFF, DD, hidden, (float*)nullptr, FNULL);
    hipLaunchKernelGGL((gemm_mfma<EPI_GELU>), dim3(DFF / 128, 1), dim3(256), 0, stream,
                       xn + (size_t)MMAIN * DD, fc_wb, fc_b, 128, DFF, DD,
                       hidden + (size_t)MMAIN * DFF, (float*)nullptr, FNULL);
    // proj: main + merged tail (outputs [outx_tail; outs] contiguous in d_out)
    hipLaunchKernelGGL((gemm256<EPI_RES>), dim3(DD / 256, MT64), dim3(512), 0, stream,
                       hidden, proj_wb, proj_b, MMAIN, DD, DFF, UNULL, outx, outx);
    hipLaunchKernelGGL((gemm_mfma<EPI_RES>), dim3(DD / 128, 1), dim3(256), 0, stream,
                       hidden + (size_t)MMAIN * DFF, proj_wb, proj_b, 128, DD, DFF,
                       UNULL, outx + (size_t)MMAIN * DD, outx + (size_t)MMAIN * DD);
}

// Round 18
// 1365.238 us; speedup vs baseline: 3.8021x; 1.0008x over previous
//
#include <hip/hip_runtime.h>
#include <hip/hip_bf16.h>

// ---------------- problem constants ----------------
#define BB 8
#define TT 8
#define LL 257
#define DD 1024
#define HH 16
#define CC 64
#define SS 8
#define NTOK (BB*TT*LL)   // 16448
#define D3 (3*DD)         // 3072
#define DFF (4*DD)        // 4096
#define MMAIN 16384       // 64 x 256 m-tiles; tail = 64 rows
#define MTAIL 64

typedef unsigned short u16;   // bf16 bits
typedef __attribute__((ext_vector_type(8))) short short8;
typedef __attribute__((ext_vector_type(4))) short short4v;
typedef __attribute__((ext_vector_type(4))) float f32x4;

__device__ __forceinline__ float us2f(u16 u) {
    return __uint_as_float(((unsigned int)u) << 16);
}
__device__ __forceinline__ u16 f2us(float f) {
    unsigned int u = __float_as_uint(f);
    unsigned int rb = ((u >> 16) & 1u) + 0x7fffu;   // round-to-nearest-even
    return (u16)((u + rb) >> 16);
}

__device__ __forceinline__ void gload_lds16(const u16* g, u16* l) {
    __builtin_amdgcn_global_load_lds(
        (__attribute__((address_space(1))) void*)(void*)g,
        (__attribute__((address_space(3))) void*)(void*)l, 16, 0, 0);
}

// ---------------- fp32 -> bf16 weight conversion ----------------
__global__ __launch_bounds__(256)
void cvt_w(const float* __restrict__ in, u16* __restrict__ out, int n4)
{
    int i = blockIdx.x * 256 + threadIdx.x;
    if (i >= n4) return;
    float4 v = reinterpret_cast<const float4*>(in)[i];
    ushort4 o;
    o.x = f2us(v.x); o.y = f2us(v.y); o.z = f2us(v.z); o.w = f2us(v.w);
    reinterpret_cast<ushort4*>(out)[i] = o;
}

// ---------------- LayerNorm over last dim (1024), optional residual add ----------------
__global__ __launch_bounds__(256)
void ln_rows(const float* __restrict__ X, const float* __restrict__ R,
             const float* __restrict__ g, const float* __restrict__ bta,
             u16* __restrict__ out, int M)
{
    int row = blockIdx.x;
    if (row >= M) return;
    const float* x = X + (size_t)row * DD;
    const float* r = R ? R + (size_t)row * DD : nullptr;
    int t = threadIdx.x;
    float4 v = *reinterpret_cast<const float4*>(&x[t * 4]);
    if (r) {
        float4 rv = *reinterpret_cast<const float4*>(&r[t * 4]);
        v.x += rv.x; v.y += rv.y; v.z += rv.z; v.w += rv.w;
    }
    float s1 = v.x + v.y + v.z + v.w;
    float s2 = v.x * v.x + v.y * v.y + v.z * v.z + v.w * v.w;
#pragma unroll
    for (int o = 32; o > 0; o >>= 1) { s1 += __shfl_xor(s1, o, 64); s2 += __shfl_xor(s2, o, 64); }
    __shared__ float red[10];
    int wid = t >> 6, lane = t & 63;
    if (lane == 0) { red[wid] = s1; red[4 + wid] = s2; }
    __syncthreads();
    if (t == 0) {
        float a = red[0] + red[1] + red[2] + red[3];
        float q = red[4] + red[5] + red[6] + red[7];
        float mu = a * (1.f / DD);
        float var = q * (1.f / DD) - mu * mu;
        red[8] = mu; red[9] = rsqrtf(var + 1e-5f);
    }
    __syncthreads();
    float mu = red[8], rs = red[9];
    float4 gv = *reinterpret_cast<const float4*>(&g[t * 4]);
    float4 bv = *reinterpret_cast<const float4*>(&bta[t * 4]);
    ushort4 o4;
    o4.x = f2us((v.x - mu) * rs * gv.x + bv.x);
    o4.y = f2us((v.y - mu) * rs * gv.y + bv.y);
    o4.z = f2us((v.z - mu) * rs * gv.z + bv.z);
    o4.w = f2us((v.w - mu) * rs * gv.w + bv.w);
    *reinterpret_cast<ushort4*>(&out[(size_t)row * DD + t * 4]) = o4;
}

// ---------------- fused s-branch prep ----------------
__global__ __launch_bounds__(256)
void s_prep(const float* __restrict__ s, const float* __restrict__ te,
            const float* __restrict__ smlp_g, const float* __restrict__ smlp_b,
            const float* __restrict__ ln1_g, const float* __restrict__ ln1_b,
            const float* __restrict__ lnte_g, const float* __restrict__ lnte_b,
            const u16* __restrict__ w1b, const u16* __restrict__ w2b,
            u16* __restrict__ snte)
{
    const int blk = blockIdx.x, t = threadIdx.x;
    __shared__ float red[10];
    const int wid = t >> 6, lane = t & 63;

    if (blk == 64) {   // ln_te
        const int NE = TT * DD;
        float s1 = 0.f, s2 = 0.f;
        for (int i = t; i < NE; i += 256) { float v = te[i]; s1 += v; s2 += v * v; }
#pragma unroll
        for (int o = 32; o > 0; o >>= 1) { s1 += __shfl_xor(s1, o, 64); s2 += __shfl_xor(s2, o, 64); }
        if (lane == 0) { red[wid] = s1; red[4 + wid] = s2; }
        __syncthreads();
        if (t == 0) {
            float a = red[0] + red[1] + red[2] + red[3];
            float q = red[4] + red[5] + red[6] + red[7];
            float mu = a / (float)NE;
            float var = q / (float)NE - mu * mu;
            red[8] = mu; red[9] = rsqrtf(var + 1e-5f);
        }
        __syncthreads();
        float mu = red[8], rs = red[9];
        for (int i = t; i < NE; i += 256)
            snte[(size_t)64 * DD + i] = f2us((te[i] - mu) * rs * lnte_g[i] + lnte_b[i]);
        return;
    }

    __shared__ float xrow[1024];
    __shared__ float h1[128];
    const float* sr = s + (size_t)blk * DD;

    float v[4]; float s1 = 0.f, s2 = 0.f;
#pragma unroll
    for (int i = 0; i < 4; ++i) {
        float val = sr[t + 256 * i];
        v[i] = val; s1 += val; s2 += val * val;
    }
#pragma unroll
    for (int o = 32; o > 0; o >>= 1) { s1 += __shfl_xor(s1, o, 64); s2 += __shfl_xor(s2, o, 64); }
    if (lane == 0) { red[wid] = s1; red[4 + wid] = s2; }
    __syncthreads();
    if (t == 0) {
        float a = red[0] + red[1] + red[2] + red[3];
        float q = red[4] + red[5] + red[6] + red[7];
        float mu = a * (1.f / DD);
        float var = q * (1.f / DD) - mu * mu;
        red[8] = mu; red[9] = rsqrtf(var + 1e-5f);
    }
    __syncthreads();
    {
        float mu = red[8], rs = red[9];
#pragma unroll
        for (int i = 0; i < 4; ++i) {
            int c = t + 256 * i;
            xrow[c] = (v[i] - mu) * rs * smlp_g[c] + smlp_b[c];
        }
    }
    __syncthreads();
    if (t < 128) {
        const u16* wr_ = w1b + (size_t)t * DD;
        float a0 = 0.f, a1 = 0.f;
        for (int k = 0; k < DD; k += 8) {
            short4v wa = *reinterpret_cast<const short4v*>(&wr_[k]);
            short4v wb = *reinterpret_cast<const short4v*>(&wr_[k + 4]);
#pragma unroll
            for (int j = 0; j < 4; ++j) {
                a0 += xrow[k + j] * us2f((u16)wa[j]);
                a1 += xrow[k + 4 + j] * us2f((u16)wb[j]);
            }
        }
        h1[t] = a0 + a1;
    }
    __syncthreads();
    float w[4]; s1 = 0.f; s2 = 0.f;
#pragma unroll
    for (int i = 0; i < 4; ++i) {
        int d = t + 256 * i;
        const u16* w2r = w2b + (size_t)d * 128;
        float a = 0.f;
        for (int k = 0; k < 128; k += 4) {
            short4v wa = *reinterpret_cast<const short4v*>(&w2r[k]);
#pragma unroll
            for (int j = 0; j < 4; ++j) a += h1[k + j] * us2f((u16)wa[j]);
        }
        float val = sr[d] + a;
        w[i] = val; s1 += val; s2 += val * val;
    }
#pragma unroll
    for (int o = 32; o > 0; o >>= 1) { s1 += __shfl_xor(s1, o, 64); s2 += __shfl_xor(s2, o, 64); }
    __syncthreads();
    if (lane == 0) { red[wid] = s1; red[4 + wid] = s2; }
    __syncthreads();
    if (t == 0) {
        float a = red[0] + red[1] + red[2] + red[3];
        float q = red[4] + red[5] + red[6] + red[7];
        float mu = a * (1.f / DD);
        float var = q * (1.f / DD) - mu * mu;
        red[8] = mu; red[9] = rsqrtf(var + 1e-5f);
    }
    __syncthreads();
    {
        float mu = red[8], rs = red[9];
#pragma unroll
        for (int i = 0; i < 4; ++i) {
            int d = t + 256 * i;
            snte[(size_t)blk * DD + d] = f2us((w[i] - mu) * rs * ln1_g[d] + ln1_b[d]);
        }
    }
}

enum { EPI_BF16 = 0, EPI_GELU = 1, EPI_RES = 2, EPI_F32 = 3 };

// ---------------- 256x256 MFMA GEMM, 4-phase lockstep (frozen R10 config) ----------------
template<int EPI>
__global__ __launch_bounds__(512)
void gemm256(const u16* __restrict__ A, const u16* __restrict__ W,
             const float* __restrict__ bias, int M, int N, int K,
             u16* __restrict__ outB, float* __restrict__ outF,
             const float* __restrict__ res)
{
    __shared__ u16 lds[2][4][8192];       // [buf][half: Ak0,Bk0,Ak1,Bk1][16KB]
    const int tid = threadIdx.x;
    const int lane = tid & 63;
    const int wid = tid >> 6;
    const int wr = wid >> 2, wc = wid & 3;   // per-wave C: 128(m) x 64(n)

    const int gx = gridDim.x;
    const int nwg = gx * gridDim.y;
    int bid = blockIdx.y * gx + blockIdx.x;
    int qq = nwg >> 3, rr = nwg & 7;
    int xcd = bid & 7, idx = bid >> 3;
    int nb = (xcd < rr ? xcd * (qq + 1) : rr * (qq + 1) + (xcd - rr) * qq) + idx;
    const int m0 = (nb / gx) * 256, n0 = (nb % gx) * 256;

    int u0 = tid, u1 = tid + 512;
    int g0 = u0 >> 6, kb0 = (u0 >> 4) & 3, r0 = u0 & 15;
    int g1 = u1 >> 6, kb1 = (u1 >> 4) & 3, r1 = u1 & 15;
    int ar0 = m0 + g0 * 16 + r0; if (ar0 >= M) ar0 = M - 1;
    int ar1 = m0 + g1 * 16 + r1; if (ar1 >= M) ar1 = M - 1;
    int br0 = n0 + g0 * 16 + r0;
    int br1 = n0 + g1 * 16 + r1;
    const u16* pa0 = A + (size_t)ar0 * K + kb0 * 8;
    const u16* pa1 = A + (size_t)ar1 * K + kb1 * 8;
    const u16* pb0 = W + (size_t)br0 * K + kb0 * 8;
    const u16* pb1 = W + (size_t)br1 * K + kb1 * 8;

    f32x4 acc[8][4];
#pragma unroll
    for (int i = 0; i < 8; ++i)
#pragma unroll
        for (int j = 0; j < 4; ++j)
            acc[i][j] = (f32x4){0.f, 0.f, 0.f, 0.f};

    auto stageA = [&](int kt, int s, int bf) {
        int kc = kt * 64 + s * 32;
        gload_lds16(pa0 + kc, &lds[bf][s * 2][u0 * 8]);
        gload_lds16(pa1 + kc, &lds[bf][s * 2][u1 * 8]);
    };
    auto stageB = [&](int kt, int s, int bf) {
        int kc = kt * 64 + s * 32;
        gload_lds16(pb0 + kc, &lds[bf][s * 2 + 1][u0 * 8]);
        gload_lds16(pb1 + kc, &lds[bf][s * 2 + 1][u1 * 8]);
    };

    const int nk = K >> 6;   // >= 2
    stageA(0, 0, 0); stageB(0, 0, 0); stageA(0, 1, 0); stageB(0, 1, 0);
    asm volatile("s_waitcnt vmcnt(4)" ::: "memory");
    __builtin_amdgcn_s_barrier();
    __builtin_amdgcn_sched_barrier(0);

    for (int t = 0; t < nk; ++t) {
        const int bf = t & 1, bn = bf ^ 1;
        const bool st = (t + 1 < nk);
        short8 aq[4], bq[4];
        // ---------- P0 ----------
#pragma unroll
        for (int j = 0; j < 4; ++j)
            bq[j] = *reinterpret_cast<const short8*>(&lds[bf][1][(wc * 4 + j) * 512 + lane * 8]);
#pragma unroll
        for (int i = 0; i < 4; ++i)
            aq[i] = *reinterpret_cast<const short8*>(&lds[bf][0][(wr * 8 + i) * 512 + lane * 8]);
        if (st) stageA(t + 1, 0, bn);
        __builtin_amdgcn_s_barrier();
        __builtin_amdgcn_s_setprio(1);
#pragma unroll
        for (int i = 0; i < 4; ++i)
#pragma unroll
            for (int j = 0; j < 4; ++j)
                acc[i][j] = __builtin_amdgcn_mfma_f32_16x16x32_bf16(aq[i], bq[j], acc[i][j], 0, 0, 0);
        __builtin_amdgcn_s_setprio(0);
        __builtin_amdgcn_s_barrier();
        __builtin_amdgcn_sched_barrier(0);
        // ---------- P1 ----------
#pragma unroll
        for (int i = 0; i < 4; ++i)
            aq[i] = *reinterpret_cast<const short8*>(&lds[bf][0][(wr * 8 + 4 + i) * 512 + lane * 8]);
        if (st) stageB(t + 1, 0, bn);
        __builtin_amdgcn_s_barrier();
        __builtin_amdgcn_s_setprio(1);
#pragma unroll
        for (int i = 0; i < 4; ++i)
#pragma unroll
            for (int j = 0; j < 4; ++j)
                acc[4 + i][j] = __builtin_amdgcn_mfma_f32_16x16x32_bf16(aq[i], bq[j], acc[4 + i][j], 0, 0, 0);
        __builtin_amdgcn_s_setprio(0);
        if (st) asm volatile("s_waitcnt vmcnt(4)" ::: "memory");
        else    asm volatile("s_waitcnt vmcnt(0)" ::: "memory");
        __builtin_amdgcn_s_barrier();
        __builtin_amdgcn_sched_barrier(0);
        // ---------- P2 ----------
#pragma unroll
        for (int j = 0; j < 4; ++j)
            bq[j] = *reinterpret_cast<const short8*>(&lds[bf][3][(wc * 4 + j) * 512 + lane * 8]);
#pragma unroll
        for (int i = 0; i < 4; ++i)
            aq[i] = *reinterpret_cast<const short8*>(&lds[bf][2][(wr * 8 + i) * 512 + lane * 8]);
        if (st) stageA(t + 1, 1, bn);
        __builtin_amdgcn_s_barrier();
        __builtin_amdgcn_s_setprio(1);
#pragma unroll
        for (int i = 0; i < 4; ++i)
#pragma unroll
            for (int j = 0; j < 4; ++j)
                acc[i][j] = __builtin_amdgcn_mfma_f32_16x16x32_bf16(aq[i], bq[j], acc[i][j], 0, 0, 0);
        __builtin_amdgcn_s_setprio(0);
        __builtin_amdgcn_s_barrier();
        __builtin_amdgcn_sched_barrier(0);
        // ---------- P3 ----------
#pragma unroll
        for (int i = 0; i < 4; ++i)
            aq[i] = *reinterpret_cast<const short8*>(&lds[bf][2][(wr * 8 + 4 + i) * 512 + lane * 8]);
        if (st) stageB(t + 1, 1, bn);
        __builtin_amdgcn_s_barrier();
        __builtin_amdgcn_s_setprio(1);
#pragma unroll
        for (int i = 0; i < 4; ++i)
#pragma unroll
            for (int j = 0; j < 4; ++j)
                acc[4 + i][j] = __builtin_amdgcn_mfma_f32_16x16x32_bf16(aq[i], bq[j], acc[4 + i][j], 0, 0, 0);
        __builtin_amdgcn_s_setprio(0);
        if (st) asm volatile("s_waitcnt vmcnt(4)" ::: "memory");
        __builtin_amdgcn_s_barrier();
        __builtin_amdgcn_sched_barrier(0);
    }

    const int cn = lane & 15, cr = (lane >> 4) * 4;
#pragma unroll
    for (int i = 0; i < 8; ++i) {
#pragma unroll
        for (int r = 0; r < 4; ++r) {
            int m = m0 + wr * 128 + i * 16 + cr + r;
            if (m >= M) continue;
#pragma unroll
            for (int j = 0; j < 4; ++j) {
                int n = n0 + wc * 64 + j * 16 + cn;
                float c = acc[i][j][r];
                if (bias) c += bias[n];
                size_t o = (size_t)m * N + n;
                if (EPI == EPI_BF16) outB[o] = f2us(c);
                else if (EPI == EPI_GELU) { float gg = c / (1.f + __expf(-1.702f * c)); outB[o] = f2us(gg); }
                else if (EPI == EPI_RES) outF[o] = res[o] + c;
                else outF[o] = c;
            }
        }
    }
}

// ---------------- 128x128 MFMA GEMM (small-M / tail shapes): ring-3, counted vmcnt ----------------
template<int EPI>
__global__ __launch_bounds__(256)
void gemm_mfma(const u16* __restrict__ A, const u16* __restrict__ W,
               const float* __restrict__ bias, int M, int N, int K,
               u16* __restrict__ outB, float* __restrict__ outF,
               const float* __restrict__ res)
{
    __shared__ u16 Als[3][128 * 32];
    __shared__ u16 Bls[3][128 * 32];
    const int tid = threadIdx.x;
    const int lane = tid & 63;
    const int wid = tid >> 6;
    const int wm = (wid >> 1) * 64, wn = (wid & 1) * 64;

    const int gx = gridDim.x;
    const int nwg = gx * gridDim.y;
    int bid = blockIdx.y * gx + blockIdx.x;
    int qq = nwg >> 3, rr = nwg & 7;
    int xcd = bid & 7, idx = bid >> 3;
    int nb = (xcd < rr ? xcd * (qq + 1) : rr * (qq + 1) + (xcd - rr) * qq) + idx;
    const int m0 = (nb / gx) * 128, n0 = (nb % gx) * 128;

    int o0 = tid, o1 = tid + 256;
    int g0 = o0 >> 6, kb0 = (o0 >> 4) & 3, r0 = o0 & 15;
    int g1 = o1 >> 6, kb1 = (o1 >> 4) & 3, r1 = o1 & 15;
    int ar0 = m0 + g0 * 16 + r0; if (ar0 >= M) ar0 = M - 1;
    int ar1 = m0 + g1 * 16 + r1; if (ar1 >= M) ar1 = M - 1;
    int br0 = n0 + g0 * 16 + r0;
    int br1 = n0 + g1 * 16 + r1;
    const u16* a0 = A + (size_t)ar0 * K + kb0 * 8;
    const u16* a1 = A + (size_t)ar1 * K + kb1 * 8;
    const u16* b0 = W + (size_t)br0 * K + kb0 * 8;
    const u16* b1 = W + (size_t)br1 * K + kb1 * 8;

    f32x4 acc[4][4];
#pragma unroll
    for (int i = 0; i < 4; ++i)
#pragma unroll
        for (int j = 0; j < 4; ++j)
            acc[i][j] = (f32x4){0.f, 0.f, 0.f, 0.f};

    auto stage = [&](int kt, int sl) {
        int kk = kt << 5;
        gload_lds16(a0 + kk, &Als[sl][o0 * 8]);
        gload_lds16(a1 + kk, &Als[sl][o1 * 8]);
        gload_lds16(b0 + kk, &Bls[sl][o0 * 8]);
        gload_lds16(b1 + kk, &Bls[sl][o1 * 8]);
    };
    auto compute = [&](int sl) {
        short8 af[4], bfr[4];
#pragma unroll
        for (int i = 0; i < 4; ++i)
            af[i] = *reinterpret_cast<const short8*>(&Als[sl][((wm >> 4) + i) * 512 + lane * 8]);
#pragma unroll
        for (int j = 0; j < 4; ++j)
            bfr[j] = *reinterpret_cast<const short8*>(&Bls[sl][((wn >> 4) + j) * 512 + lane * 8]);
        __builtin_amdgcn_s_setprio(1);
#pragma unroll
        for (int i = 0; i < 4; ++i)
#pragma unroll
            for (int j = 0; j < 4; ++j)
                acc[i][j] = __builtin_amdgcn_mfma_f32_16x16x32_bf16(af[i], bfr[j], acc[i][j], 0, 0, 0);
        __builtin_amdgcn_s_setprio(0);
    };

    const int nk = K >> 5;   // >= 4
    stage(0, 0);
    stage(1, 1);
    asm volatile("s_waitcnt vmcnt(4)" ::: "memory");
    __builtin_amdgcn_s_barrier();
    __builtin_amdgcn_sched_barrier(0);

    int t = 0;
    for (; t < nk - 2; ++t) {
        stage(t + 2, (t + 2) % 3);
        compute(t % 3);
        asm volatile("s_waitcnt vmcnt(4)" ::: "memory");
        __builtin_amdgcn_s_barrier();
        __builtin_amdgcn_sched_barrier(0);
    }
    compute(t % 3);
    asm volatile("s_waitcnt vmcnt(0)" ::: "memory");
    __builtin_amdgcn_s_barrier();
    __builtin_amdgcn_sched_barrier(0);
    ++t;
    compute(t % 3);

    const int cn = lane & 15, cr = (lane >> 4) * 4;
#pragma unroll
    for (int i = 0; i < 4; ++i) {
#pragma unroll
        for (int r = 0; r < 4; ++r) {
            int m = m0 + wm + i * 16 + cr + r;
            if (m >= M) continue;
#pragma unroll
            for (int j = 0; j < 4; ++j) {
                int n = n0 + wn + j * 16 + cn;
                float c = acc[i][j][r];
                if (bias) c += bias[n];
                size_t o = (size_t)m * N + n;
                if (EPI == EPI_BF16) outB[o] = f2us(c);
                else if (EPI == EPI_GELU) { float gg = c / (1.f + __expf(-1.702f * c)); outB[o] = f2us(gg); }
                else if (EPI == EPI_RES) outF[o] = res[o] + c;
                else outF[o] = c;
            }
        }
    }
}

// ---------------- MFMA spatial attention: one block (4 waves) per (h, b*t) ----------------
#define VSTR 290
#define PSTR 40

__global__ __launch_bounds__(256)
void spatial_attn(const u16* __restrict__ qkv, u16* __restrict__ mix)
{
    const int h = blockIdx.x, bt = blockIdx.y;
    const int hoff = h * CC;
    const size_t base = (size_t)bt * LL * D3;
    __shared__ u16 Vt[64 * VSTR];
    __shared__ u16 Pb[4][16 * PSTR];
    const int tid = threadIdx.x, lane = tid & 63, w = tid >> 6;
    const int c15 = lane & 15, g = lane >> 4;

    for (int idx = tid; idx < 288 * 64; idx += 256) {
        int key = idx >> 6, c = idx & 63;
        u16 v = 0;
        if (key < 257) v = qkv[base + (size_t)key * D3 + 2 * DD + hoff + c];
        Vt[c * VSTR + key] = v;
    }
    __syncthreads();

    u16* pb = Pb[w];
    for (int qt = w; qt < 17; qt += 4) {
        int qrow = qt * 16 + c15; if (qrow > 256) qrow = 256;
        const u16* qp = &qkv[base + (size_t)qrow * D3 + hoff + g * 8];
        short8 a0 = *reinterpret_cast<const short8*>(qp);
        short8 a1 = *reinterpret_cast<const short8*>(qp + 32);

        f32x4 sc[17];
#pragma unroll
        for (int t = 0; t < 17; ++t) sc[t] = (f32x4){0.f, 0.f, 0.f, 0.f};
#pragma unroll
        for (int t = 0; t < 17; ++t) {
            int krow = t * 16 + c15; if (krow > 256) krow = 256;
            const u16* kp = &qkv[base + (size_t)krow * D3 + DD + hoff + g * 8];
            short8 b0 = *reinterpret_cast<const short8*>(kp);
            short8 b1 = *reinterpret_cast<const short8*>(kp + 32);
            sc[t] = __builtin_amdgcn_mfma_f32_16x16x32_bf16(a0, b0, sc[t], 0, 0, 0);
            sc[t] = __builtin_amdgcn_mfma_f32_16x16x32_bf16(a1, b1, sc[t], 0, 0, 0);
        }

        const bool lastv = (c15 == 0);
#pragma unroll
        for (int r = 0; r < 4; ++r) {
            float mx = -1e30f;
#pragma unroll
            for (int t = 0; t < 17; ++t) {
                float v = sc[t][r] * 0.125f;
                if (t == 16 && !lastv) v = -1e30f;
                sc[t][r] = v;
                mx = fmaxf(mx, v);
            }
            mx = fmaxf(mx, __shfl_xor(mx, 1, 64));
            mx = fmaxf(mx, __shfl_xor(mx, 2, 64));
            mx = fmaxf(mx, __shfl_xor(mx, 4, 64));
            mx = fmaxf(mx, __shfl_xor(mx, 8, 64));
            float sum = 0.f;
#pragma unroll
            for (int t = 0; t < 17; ++t) { float e = __expf(sc[t][r] - mx); sc[t][r] = e; sum += e; }
            sum += __shfl_xor(sum, 1, 64);
            sum += __shfl_xor(sum, 2, 64);
            sum += __shfl_xor(sum, 4, 64);
            sum += __shfl_xor(sum, 8, 64);
            float is = 1.f / sum;
#pragma unroll
            for (int t = 0; t < 17; ++t) sc[t][r] *= is;
        }

        f32x4 oacc[4];
#pragma unroll
        for (int ct = 0; ct < 4; ++ct) oacc[ct] = (f32x4){0.f, 0.f, 0.f, 0.f};
#pragma unroll
        for (int k0 = 0; k0 < 9; ++k0) {
            const int t0 = 2 * k0, t1 = 2 * k0 + 1;
#pragma unroll
            for (int r = 0; r < 4; ++r) {
                pb[(4 * g + r) * PSTR + c15]      = f2us(sc[t0][r]);
                pb[(4 * g + r) * PSTR + 16 + c15] = (t1 < 17) ? f2us(sc[t1][r]) : (u16)0;
            }
            short8 pa = *reinterpret_cast<const short8*>(&pb[c15 * PSTR + 8 * g]);
            __builtin_amdgcn_s_setprio(1);
#pragma unroll
            for (int ct = 0; ct < 4; ++ct) {
                short8 vb = *reinterpret_cast<const short8*>(&Vt[(16 * ct + c15) * VSTR + 32 * k0 + 8 * g]);
                oacc[ct] = __builtin_amdgcn_mfma_f32_16x16x32_bf16(pa, vb, oacc[ct], 0, 0, 0);
            }
            __builtin_amdgcn_s_setprio(0);
        }

#pragma unroll
        for (int r = 0; r < 4; ++r) {
            int q = qt * 16 + 4 * g + r;
            if (q >= LL) continue;
            size_t ob = ((size_t)bt * LL + q) * DD + hoff;
#pragma unroll
            for (int ct = 0; ct < 4; ++ct)
                mix[ob + 16 * ct + c15] = f2us(oacc[ct][r]);
        }
    }
}

// ---------------- syno-token attention: one block (4 waves) per (h, b*t) ----------------
#define SK 68

__global__ __launch_bounds__(256)
void s_attn(const u16* __restrict__ qkv, const u16* __restrict__ snqkv,
            const u16* __restrict__ teqkv, const float* __restrict__ pmask,
            float* __restrict__ smix)
{
    const int h = blockIdx.x, bt = blockIdx.y, b = bt >> 3, t = bt & 7;
    const int hoff = h * CC;
    const int tid = threadIdx.x, lane = tid & 63, w = tid >> 6;
    __shared__ u16 Kls[256 * SK];
    __shared__ u16 Vls[256 * SK];
    __shared__ float pls[4][256];
    const size_t base = (size_t)bt * LL * D3;

    const int c8 = (tid & 7) * 8;
    const u16* tekp = &teqkv[t * D3 + DD + hoff + c8];
    const u16* tevp = &teqkv[t * D3 + 2 * DD + hoff + c8];
    float tek[8], tev[8];
#pragma unroll
    for (int j = 0; j < 8; ++j) { tek[j] = us2f(tekp[j]); tev[j] = us2f(tevp[j]); }
#pragma unroll
    for (int pass = 0; pass < 8; ++pass) {
        int key = (tid >> 3) + 32 * pass;
        const u16* kp = &qkv[base + (size_t)(key + 1) * D3 + DD + hoff + c8];
        const u16* vp = &qkv[base + (size_t)(key + 1) * D3 + 2 * DD + hoff + c8];
        short4v k0 = *reinterpret_cast<const short4v*>(kp);
        short4v k1 = *reinterpret_cast<const short4v*>(kp + 4);
        short4v v0 = *reinterpret_cast<const short4v*>(vp);
        short4v v1 = *reinterpret_cast<const short4v*>(vp + 4);
        short4v ok0, ok1, ov0, ov1;
#pragma unroll
        for (int j = 0; j < 4; ++j) {
            ok0[j] = (short)f2us(us2f((u16)k0[j]) + tek[j]);
            ok1[j] = (short)f2us(us2f((u16)k1[j]) + tek[4 + j]);
            ov0[j] = (short)f2us(us2f((u16)v0[j]) + tev[j]);
            ov1[j] = (short)f2us(us2f((u16)v1[j]) + tev[4 + j]);
        }
        *reinterpret_cast<short4v*>(&Kls[key * SK + c8]) = ok0;
        *reinterpret_cast<short4v*>(&Kls[key * SK + c8 + 4]) = ok1;
        *reinterpret_cast<short4v*>(&Vls[key * SK + c8]) = ov0;
        *reinterpret_cast<short4v*>(&Vls[key * SK + c8 + 4]) = ov1;
    }
    __syncthreads();

    const float* pm = pmask + (size_t)bt * 256;
    for (int qi = w; qi < SS; qi += 4) {
        float qc = us2f(snqkv[(size_t)(b * SS + qi) * D3 + hoff + lane]) * 0.125f;
        float sc[4] = {0.f, 0.f, 0.f, 0.f};
        for (int c = 0; c < CC; ++c) {
            float qv = __shfl(qc, c, 64);
#pragma unroll
            for (int j = 0; j < 4; ++j)
                sc[j] += qv * us2f(Kls[(lane + 64 * j) * SK + c]);
        }
#pragma unroll
        for (int j = 0; j < 4; ++j) sc[j] += pm[lane + 64 * j];
        float mx = fmaxf(fmaxf(sc[0], sc[1]), fmaxf(sc[2], sc[3]));
#pragma unroll
        for (int o = 32; o > 0; o >>= 1) mx = fmaxf(mx, __shfl_xor(mx, o, 64));
        float sum = 0.f;
#pragma unroll
        for (int j = 0; j < 4; ++j) { sc[j] = __expf(sc[j] - mx); sum += sc[j]; }
#pragma unroll
        for (int o = 32; o > 0; o >>= 1) sum += __shfl_xor(sum, o, 64);
        float inv = 1.f / sum;
#pragma unroll
        for (int j = 0; j < 4; ++j) pls[w][lane + 64 * j] = sc[j] * inv;
        float acc = 0.f;
        for (int key = 0; key < 256; ++key)
            acc += pls[w][key] * us2f(Vls[key * SK + lane]);
        smix[(((size_t)bt * SS + qi) * HH + h) * CC + lane] = acc;
    }
}

// ---------------- depthwise temporal conv + residual + mean over T ----------------
__global__ __launch_bounds__(256)
void conv_mean(const float* __restrict__ smix, const float* __restrict__ cw,
               const float* __restrict__ cb, u16* __restrict__ out)
{
    int idx = blockIdx.x * 256 + threadIdx.x;
    int d = idx & 1023;
    int bs = idx >> 10;
    int b = bs >> 3, s_ = bs & 7;
    float z[TT];
#pragma unroll
    for (int t = 0; t < TT; ++t)
        z[t] = smix[((size_t)(b * TT + t) * SS + s_) * DD + d];
    float w0 = cw[d * 3], w1 = cw[d * 3 + 1], w2 = cw[d * 3 + 2];
    float acc = 0.f;
#pragma unroll
    for (int t = 0; t < TT; ++t) {
        float zc = w1 * z[t];
        if (t > 0)      zc += w0 * z[t - 1];
        if (t < TT - 1) zc += w2 * z[t + 1];
        acc += z[t] + zc;
    }
    out[(size_t)bs * DD + d] = f2us(acc * 0.125f + cb[d]);
}

// ---------------- host: launch sequence ----------------
extern "C" void kernel_launch(void* const* d_in, const int* in_sizes, int n_in,
                              void* d_out, int out_size, void* d_ws, size_t ws_size,
                              hipStream_t stream)
{
    const float* x      = (const float*)d_in[0];
    const float* s      = (const float*)d_in[1];
    const float* te     = (const float*)d_in[2];
    const float* pmask  = (const float*)d_in[3];
    const float* in_w   = (const float*)d_in[4];
    const float* in_b   = (const float*)d_in[5];
    const float* out_w  = (const float*)d_in[6];
    const float* out_b  = (const float*)d_in[7];
    const float* ln1_g  = (const float*)d_in[8];
    const float* ln1_b  = (const float*)d_in[9];
    const float* ln2_g  = (const float*)d_in[10];
    const float* ln2_b  = (const float*)d_in[11];
    const float* fc_w   = (const float*)d_in[12];
    const float* fc_b   = (const float*)d_in[13];
    const float* proj_w = (const float*)d_in[14];
    const float* proj_b = (const float*)d_in[15];
    const float* smlp_g = (const float*)d_in[16];
    const float* smlp_b = (const float*)d_in[17];
    const float* w1     = (const float*)d_in[18];
    const float* w2     = (const float*)d_in[19];
    const float* lnte_g = (const float*)d_in[20];
    const float* lnte_b = (const float*)d_in[21];
    const float* conv_w = (const float*)d_in[22];
    const float* conv_b = (const float*)d_in[23];

    float* outx = (float*)d_out;                     // [NTOK, 1024]
    float* outs = outx + (size_t)NTOK * DD;          // [64, 1024] (contiguous after outx)

    char* ws = (char*)d_ws;
    u16* qkv    = (u16*)ws;                                      // [NTOK,3072] bf16
    u16* mixb   = (u16*)(ws + (size_t)NTOK * D3 * 2);            // [NTOK,1024] bf16
    u16* hidden = qkv;                                           // [MMAIN,4096] overlay (main rows only)
    u16* xn     = (u16*)(ws + (size_t)NTOK * DFF * 2);           // [NTOK+64,1024] bf16
    char* sm    = ws + (size_t)NTOK * DFF * 2 + (size_t)(NTOK + 64) * DD * 2;
    u16*  snte    = (u16*)sm;  sm += (size_t)72 * DD * 2;        // [72,1024]
    u16*  sqkv72  = (u16*)sm;  sm += (size_t)72 * D3 * 2;        // [72,3072]
    float* smix  = (float*)sm; sm += (size_t)BB * TT * SS * DD * 4;
    u16*  smm    = (u16*)sm;   sm += 64 * DD * 2;
    u16*  hidtail = (u16*)sm;  sm += (size_t)128 * DFF * 2;      // dedicated tail hidden (no alias)
    // bf16 weights
    u16* in_wb   = (u16*)sm;  sm += (size_t)D3 * DD * 2;
    u16* out_wb  = (u16*)sm;  sm += (size_t)DD * DD * 2;
    u16* fc_wb   = (u16*)sm;  sm += (size_t)DFF * DD * 2;
    u16* proj_wb = (u16*)sm;  sm += (size_t)DD * DFF * 2;
    u16* w1b     = (u16*)sm;  sm += (size_t)128 * DD * 2;
    u16* w2b     = (u16*)sm;  sm += (size_t)DD * 128 * 2;

    const float* FNULL = nullptr;
    u16* UNULL = nullptr;

    // 0. weight conversions
    auto cvt = [&](const float* src, u16* dst, int n) {
        hipLaunchKernelGGL(cvt_w, dim3((n / 4 + 255) / 256), dim3(256), 0, stream, src, dst, n / 4);
    };
    cvt(in_w,   in_wb,   D3 * DD);
    cvt(out_w,  out_wb,  DD * DD);
    cvt(fc_w,   fc_wb,   DFF * DD);
    cvt(proj_w, proj_wb, DD * DFF);
    cvt(w1,     w1b,     128 * DD);
    cvt(w2,     w2b,     DD * 128);

    const int MT64 = MMAIN / 256;   // 64 m-tiles -> grid multiples of 256

    // 1. xn = LN1(x)
    hipLaunchKernelGGL(ln_rows, dim3(NTOK), dim3(256), 0, stream, x, FNULL, ln1_g, ln1_b, xn, NTOK);
    // 2. qkv = xn @ in_proj_w^T + b   (main + tail)
    hipLaunchKernelGGL((gemm256<EPI_BF16>), dim3(D3 / 256, MT64), dim3(512), 0, stream,
                       xn, in_wb, in_b, MMAIN, D3, DD, qkv, (float*)nullptr, FNULL);
    hipLaunchKernelGGL((gemm_mfma<EPI_BF16>), dim3(D3 / 128, 1), dim3(256), 0, stream,
                       xn + (size_t)MMAIN * DD, in_wb, in_b, MTAIL, D3, DD,
                       qkv + (size_t)MMAIN * D3, (float*)nullptr, FNULL);
    // 3. spatial attention -> mix
    hipLaunchKernelGGL(spatial_attn, dim3(HH, BB * TT), dim3(256), 0, stream, qkv, mixb);
    // 4. outx = x + mix @ out_w^T + out_b
    hipLaunchKernelGGL((gemm256<EPI_RES>), dim3(DD / 256, MT64), dim3(512), 0, stream,
                       mixb, out_wb, out_b, MMAIN, DD, DD, UNULL, outx, x);
    hipLaunchKernelGGL((gemm_mfma<EPI_RES>), dim3(DD / 128, 1), dim3(256), 0, stream,
                       mixb + (size_t)MMAIN * DD, out_wb, out_b, MTAIL, DD, DD,
                       UNULL, outx + (size_t)MMAIN * DD, x + (size_t)MMAIN * DD);
    // 5. syno-token branch
    hipLaunchKernelGGL(s_prep, dim3(65), dim3(256), 0, stream,
                       s, te, smlp_g, smlp_b, ln1_g, ln1_b, lnte_g, lnte_b, w1b, w2b, snte);
    hipLaunchKernelGGL((gemm_mfma<EPI_BF16>), dim3(D3 / 128, 1), dim3(256), 0, stream,
                       snte, in_wb, in_b, 72, D3, DD, sqkv72, (float*)nullptr, FNULL);
    hipLaunchKernelGGL(s_attn, dim3(HH, BB * TT), dim3(256), 0, stream,
                       qkv, sqkv72, sqkv72 + (size_t)64 * D3, pmask, smix);
    hipLaunchKernelGGL(conv_mean, dim3(256), dim3(256), 0, stream, smix, conv_w, conv_b, smm);
    hipLaunchKernelGGL((gemm_mfma<EPI_RES>), dim3(DD / 128, 1), dim3(256), 0, stream,
                       smm, out_wb, out_b, 64, DD, DD, UNULL, outs, s);
    // 6. MLP (x main + merged x-tail/s rows):
    hipLaunchKernelGGL(ln_rows, dim3(NTOK), dim3(256), 0, stream, outx, FNULL, ln2_g, ln2_b, xn, NTOK);
    hipLaunchKernelGGL(ln_rows, dim3(64), dim3(256), 0, stream, outs, FNULL, ln2_g, ln2_b,
                       xn + (size_t)NTOK * DD, 64);
    // fc: main (MMAIN rows) + merged tail (128 rows -> dedicated hidtail, no alias)
    hipLaunchKernelGGL((gemm256<EPI_GELU>), dim3(DFF / 256, MT64), dim3(512), 0, stream,
                       xn, fc_wb, fc_b, MMAIN, DFF, DD, hidden, (float*)nullptr, FNULL);
    hipLaunchKernelGGL((gemm_mfma<EPI_GELU>), dim3(DFF / 128, 1), dim3(256), 0, stream,
                       xn + (size_t)MMAIN * DD, fc_wb, fc_b, 128, DFF, DD,
                       hidtail, (float*)nullptr, FNULL);
    // proj: main + merged tail (outputs [outx_tail; outs] contiguous in d_out)
    hipLaunchKernelGGL((gemm256<EPI_RES>), dim3(DD / 256, MT64), dim3(512), 0, stream,
                       hidden, proj_wb, proj_b, MMAIN, DD, DFF, UNULL, outx, outx);
    hipLaunchKernelGGL((gemm_mfma<EPI_RES>), dim3(DD / 128, 1), dim3(256), 0, stream,
                       hidtail, proj_wb, proj_b, 128, DD, DFF,
                       UNULL, outx + (size_t)MMAIN * DD, outx + (size_t)MMAIN * DD);
}